// Round 14
// baseline (4646.948 us; speedup 1.0000x reference)
//
#include <hip/hip_runtime.h>
#include <stdint.h>

#define T_ 1024
#define H_ 256
#define G_ 768

typedef __attribute__((ext_vector_type(8))) short bf16x8;
typedef __attribute__((ext_vector_type(4))) float f32x4;

__device__ __forceinline__ unsigned short f2bf(float f) {
    union { float f; uint32_t u; } v; v.f = f;
    uint32_t u = v.u;
    return (unsigned short)((u + 0x7FFFu + ((u >> 16) & 1u)) >> 16);
}

// clamp-free, NaN-free activations (inf-safe limits)
__device__ __forceinline__ float sigm(float x) {
    return __builtin_amdgcn_rcpf(1.f + __expf(-x));
}
__device__ __forceinline__ float tanh_f(float x) {
    return __builtin_amdgcn_rcpf(1.f + __expf(-2.f * x)) * 2.f - 1.f;
}

// pack 4 f32 -> 4 bf16 in a u64, scalar-float inputs (K4/K10/K11-proven in recur ONLY;
// CONDEMNED on MFMA acc values in gemm — K5..K9 post-mortems, K10 A/B)
__device__ __forceinline__ unsigned long long pk4bf(float a, float b, float c, float d) {
    uint32_t lo, hi;
    asm("v_cvt_pk_bf16_f32 %0, %1, %2" : "=v"(lo) : "v"(a), "v"(b));
    asm("v_cvt_pk_bf16_f32 %0, %1, %2" : "=v"(hi) : "v"(c), "v"(d));
    return ((unsigned long long)hi << 32) | (unsigned long long)lo;
}

// pack 4 f32 -> u64 with NO inline asm (f2bf bit-twiddle; for gemm epilogue; K10-proven)
__device__ __forceinline__ unsigned long long pk4bf_sw(float a, float b, float c, float d) {
    return (unsigned long long)f2bf(a)
         | ((unsigned long long)f2bf(b) << 16)
         | ((unsigned long long)f2bf(c) << 32)
         | ((unsigned long long)f2bf(d) << 48);
}

// unpack 4 bf16 (bits [15:0],[31:16],[47:32],[63:48]) -> 4 f32, exact
__device__ __forceinline__ void unpk4(unsigned long long v, float* o) {
    uint32_t lo = (uint32_t)v, hi = (uint32_t)(v >> 32);
    union { uint32_t u; float f; } a, b, c, d;
    a.u = lo << 16; b.u = lo & 0xffff0000u;
    c.u = hi << 16; d.u = hi & 0xffff0000u;
    o[0] = a.f; o[1] = b.f; o[2] = c.f; o[3] = d.f;
}

__device__ __forceinline__ void gload_lds16(const void* g, void* l) {
    __builtin_amdgcn_global_load_lds((const __attribute__((address_space(1))) void*)g,
                                     (__attribute__((address_space(3))) void*)l,
                                     16, 0, 0);
}

// Pack W (f32 [layer][768][256]) into MFMA A-fragment order, 48 flat tiles/layer:
// flat = (((layer*48 + gt)*8 + kt)*64 + l)*8 + j
// tile gt: recur wave w = gt/3 owns hidden units [16w,16w+16), mt = gt%3 (r,z,n)
// gate = (gt%3)*256 + (gt/3)*16 + (l&15)
// k    = kt*32 + (j&3) + ((l>>4)<<2) + ((j>>2)<<4)
__global__ void pack_weights(const float* __restrict__ W_ih, const float* __restrict__ W_hh,
                             unsigned short* __restrict__ pIH, unsigned short* __restrict__ pHH)
{
    int idx = blockIdx.x * blockDim.x + threadIdx.x;
    if (idx >= 2 * 48 * 8 * 64 * 8) return;
    int j = idx & 7;
    int l = (idx >> 3) & 63;
    int kt = (idx >> 9) & 7;
    int gt = (idx >> 12) % 48;
    int layer = (idx >> 12) / 48;
    int gate = (gt % 3) * 256 + (gt / 3) * 16 + (l & 15);
    int k = kt * 32 + (j & 3) + ((l >> 4) << 2) + ((j >> 2) << 4);
    size_t src = (size_t)layer * G_ * H_ + (size_t)gate * H_ + k;
    pIH[idx] = f2bf(W_ih[src]);
    pHH[idx] = f2bf(W_hh[src]);
}

// xg GEMM with bias fold (r: gate<256 etc. — r/z get b_ih+b_hh, n gets b_ih),
// packed bf16 u64 output: xg_u64[(tloc*8+bblk)*3072 + gt*64 + l], gt = w*6+mt.
// No inline asm in this kernel.
template<bool SRC_BF16>
__global__ __launch_bounds__(512, 2)
void gemm_xg(const void* __restrict__ srcp, const unsigned short* __restrict__ wpack,
             const float* __restrict__ bih, const float* __restrict__ bhh,
             unsigned long long* __restrict__ xg, int t0)
{
    extern __shared__ char smem[];
    unsigned short* Bt = (unsigned short*)smem; // [8][4096] shorts = 64KB
    const int tid = threadIdx.x;
    const int w = tid >> 6, l = tid & 63;
    const int bblk = blockIdx.x & 7;
    const int tg = blockIdx.x >> 3;
    const int tbase = t0 + tg * 8;
    const int b = l & 15, g = l >> 4;

    bf16x8 af[6][8];
    {
        const bf16x8* wp = (const bf16x8*)wpack;
        #pragma unroll
        for (int mt = 0; mt < 6; ++mt)
            #pragma unroll
            for (int kt = 0; kt < 8; ++kt)
                af[mt][kt] = wp[((w * 6 + mt) * 8 + kt) * 64 + l];
    }

    // folded biases for this wave's 6 tiles: C row = g*4+q
    float bsum[6][4];
    #pragma unroll
    for (int mt = 0; mt < 6; ++mt) {
        int gt = w * 6 + mt;
        int gbase = (gt % 3) * 256 + (gt / 3) * 16;
        #pragma unroll
        for (int q = 0; q < 4; ++q) {
            int gate = gbase + g * 4 + q;
            bsum[mt][q] = (gate < 512) ? (bih[gate] + bhh[gate]) : bih[gate];
        }
    }

    if (!SRC_BF16) {
        const float* x = (const float*)srcp;
        const int t_i = w;
        const int sb = (l >> 2) & 15;
        const int f0 = (l & 3) * 64;
        const float* row = x + ((size_t)(bblk * 16 + sb) * T_ + (tbase + t_i)) * H_ + f0;
        unsigned short* bt = Bt + t_i * 4096;
        #pragma unroll
        for (int i = 0; i < 64; i += 4) {
            f32x4 v = *(const f32x4*)(row + i);
            int f = f0 + i;
            bt[(f + 0) * 16 + sb] = f2bf(v[0]);
            bt[(f + 1) * 16 + sb] = f2bf(v[1]);
            bt[(f + 2) * 16 + sb] = f2bf(v[2]);
            bt[(f + 3) * 16 + sb] = f2bf(v[3]);
        }
    } else {
        const unsigned short* hs = (const unsigned short*)srcp;
        #pragma unroll
        for (int t_i = 0; t_i < 8; ++t_i) {
            const unsigned short* src = hs + ((size_t)bblk * T_ + (tbase + t_i)) * 4096
                                           + (size_t)(w * 64 + l) * 8;
            gload_lds16(src, Bt + t_i * 4096 + w * 512);
        }
    }
    __syncthreads();

    #pragma unroll 1
    for (int t_i = 0; t_i < 8; ++t_i) {
        const unsigned short* bt = Bt + t_i * 4096;
        f32x4 acc[6];
        #pragma unroll
        for (int mt = 0; mt < 6; ++mt) acc[mt] = (f32x4){0.f, 0.f, 0.f, 0.f};
        #pragma unroll
        for (int kt = 0; kt < 8; ++kt) {
            bf16x8 bf;
            if (SRC_BF16) {
                bf = *(const bf16x8*)(bt + kt * 512 + l * 8);
            } else {
                #pragma unroll
                for (int j = 0; j < 8; ++j) {
                    int k = kt * 32 + (j & 3) + (g << 2) + ((j >> 2) << 4);
                    bf[j] = (short)bt[k * 16 + b];
                }
            }
            #pragma unroll
            for (int mt = 0; mt < 6; ++mt)
                acc[mt] = __builtin_amdgcn_mfma_f32_16x16x32_bf16(af[mt][kt], bf, acc[mt], 0, 0, 0);
        }
        unsigned long long* dst = xg + ((size_t)(tg * 8 + t_i) * 8 + bblk) * 3072 + (size_t)w * 384;
        #pragma unroll
        for (int mt = 0; mt < 6; ++mt)
            dst[mt * 64 + l] = pk4bf_sw(acc[mt][0] + bsum[mt][0], acc[mt][1] + bsum[mt][1],
                                        acc[mt][2] + bsum[mt][2], acc[mt][3] + bsum[mt][3]);
    }
}

// Zero-communication recurrence, 16 waves/block (1024 threads):
// 8 blocks x 16 batch rows. Wave w owns hidden units [16w,16w+16): 3 gate-tiles
// (r,z,n) x 8 kt = 24 A-fragments = 96 VGPRs -> fully register-resident under the
// 128-VGPR wall (K10/K11/K13 all overflowed it and re-streamed weights from L2).
// h exchange through LDS hfrag (16 KB, 2 parities); lgkm-only barrier per step.
template<int LAYER>
__global__ __launch_bounds__(1024, 4)
void recur(const unsigned long long* __restrict__ xg, const unsigned short* __restrict__ wpack,
           const float* __restrict__ bhh,
           unsigned short* __restrict__ hseq, float* __restrict__ hstate,
           float* __restrict__ h2last, int t0, int nsteps, int first)
{
    __shared__ unsigned short hfrag[2][8][512];   // 16 KB
    const int tid = threadIdx.x;
    const int w = tid >> 6, l = tid & 63;
    const int bblk = blockIdx.x;
    const int g = l >> 4, b = l & 15;

    // this wave's 24 A-fragments, register-resident (96 VGPRs)
    bf16x8 af[3][8];
    {
        const bf16x8* wp = (const bf16x8*)wpack;
        #pragma unroll
        for (int mt = 0; mt < 3; ++mt)
            #pragma unroll
            for (int kt = 0; kt < 8; ++kt)
                af[mt][kt] = wp[((size_t)(w * 3 + mt) * 8 + kt) * 64 + l];
    }

    // n-gate hidden bias (the only bias recur needs; rest folded into xg)
    const int hid0 = w * 16 + g * 4;
    float nbh[4];
    #pragma unroll
    for (int q = 0; q < 4; ++q) nbh[q] = bhh[512 + hid0 + q];

    float hreg[4];
    #pragma unroll
    for (int q = 0; q < 4; ++q)
        hreg[q] = first ? 0.f : hstate[(size_t)(bblk * 16 + b) * H_ + hid0 + q];

    // publish position: fragment kt = w>>1, u64 at byte-short offset l*8 + 4*(w&1)
    const int ktw = w >> 1;
    const int jo = (w & 1) * 4;
    // init hfrag parity 0 (16 waves fill 8 fragments exactly)
    *(unsigned long long*)(&hfrag[0][ktw][l * 8 + jo]) =
        pk4bf(hreg[0], hreg[1], hreg[2], hreg[3]);
    __syncthreads();

    #pragma unroll 1
    for (int it = 0; it < nsteps; ++it) {
        const int pr = it & 1;
        // 1) xg for THIS step -> registers (issued first, consumed after MFMAs)
        unsigned long long xgc[3];
        {
            const unsigned long long* xv = xg + ((size_t)it * 8 + bblk) * 3072 + (size_t)(w * 3) * 64;
            #pragma unroll
            for (int mt = 0; mt < 3; ++mt) xgc[mt] = xv[mt * 64 + l];
        }
        // 2) h fragments (paired reads) + 24 MFMAs, weights all in VGPRs
        const unsigned short* hb = &hfrag[pr][0][0];
        f32x4 acc[3];
        #pragma unroll
        for (int mt = 0; mt < 3; ++mt) acc[mt] = (f32x4){0.f, 0.f, 0.f, 0.f};
        #pragma unroll
        for (int kp = 0; kp < 4; ++kp) {
            bf16x8 h0 = *(const bf16x8*)(hb + (2 * kp) * 512 + l * 8);
            bf16x8 h1 = *(const bf16x8*)(hb + (2 * kp + 1) * 512 + l * 8);
            #pragma unroll
            for (int mt = 0; mt < 3; ++mt)
                acc[mt] = __builtin_amdgcn_mfma_f32_16x16x32_bf16(af[mt][2 * kp], h0, acc[mt], 0, 0, 0);
            #pragma unroll
            for (int mt = 0; mt < 3; ++mt)
                acc[mt] = __builtin_amdgcn_mfma_f32_16x16x32_bf16(af[mt][2 * kp + 1], h1, acc[mt], 0, 0, 0);
        }
        // 3) gates (biases except bhh_n pre-folded into xg)
        float cx0[4], cx1[4], cx2[4];
        unpk4(xgc[0], cx0);
        unpk4(xgc[1], cx1);
        unpk4(xgc[2], cx2);
        float hn4[4];
        #pragma unroll
        for (int q = 0; q < 4; ++q) {
            float r = sigm(cx0[q] + acc[0][q]);
            float z = sigm(cx1[q] + acc[1][q]);
            float n = tanh_f(cx2[q] + r * (acc[2][q] + nbh[q]));
            float hn = n + z * (hreg[q] - n);
            hreg[q] = hn;
            hn4[q] = hn;
        }
        unsigned long long packed = pk4bf(hn4[0], hn4[1], hn4[2], hn4[3]);
        // 4) publish h: LDS (next parity) + hseq (LAYER 0)
        *(unsigned long long*)(&hfrag[pr ^ 1][ktw][l * 8 + jo]) = packed;
        if (LAYER == 0)
            *(unsigned long long*)(hseq + ((size_t)bblk * T_ + (t0 + it)) * 4096
                                   + (size_t)ktw * 512 + l * 8 + jo) = packed;
        // 5) lgkm-only barrier: hfrag ordered; hseq stores drain at dispatch end
        asm volatile("s_waitcnt lgkmcnt(0)\n\ts_barrier" ::: "memory");
    }

    #pragma unroll
    for (int q = 0; q < 4; ++q)
        hstate[(size_t)(bblk * 16 + b) * H_ + hid0 + q] = hreg[q];
    if (LAYER == 1 && t0 + nsteps == T_) {
        #pragma unroll
        for (int q = 0; q < 4; ++q)
            h2last[(size_t)(bblk * 16 + b) * H_ + hid0 + q] = hreg[q];
    }
}

__global__ void fc_out(const float* __restrict__ h2, const float* __restrict__ W_fc,
                       const float* __restrict__ b_fc, float* __restrict__ out)
{
    __shared__ float hrow[256];
    const int bb = blockIdx.x, i = threadIdx.x;
    hrow[i] = h2[(size_t)bb * 256 + i];
    __syncthreads();
    float acc = b_fc[i];
    const float* wr = W_fc + (size_t)i * 256;
    #pragma unroll 8
    for (int k = 0; k < 256; ++k) acc += hrow[k] * wr[k];
    out[(size_t)bb * 256 + i] = sigm(acc);
}

extern "C" void kernel_launch(void* const* d_in, const int* in_sizes, int n_in,
                              void* d_out, int out_size, void* d_ws, size_t ws_size,
                              hipStream_t stream)
{
    const float* x    = (const float*)d_in[0];
    const float* W_ih = (const float*)d_in[1];
    const float* W_hh = (const float*)d_in[2];
    const float* b_ih = (const float*)d_in[3];
    const float* b_hh = (const float*)d_in[4];
    const float* W_fc = (const float*)d_in[5];
    const float* b_fc = (const float*)d_in[6];
    float* out = (float*)d_out;

    const size_t HSEQ_B = (size_t)8 * T_ * 4096 * 2;   // 64 MB
    const size_t PACK_B = 393216ull * 2;               // 768 KB each
    const size_t HST_B = 131072, H2_B = 131072;
    size_t fixed = HSEQ_B + 2 * PACK_B + HST_B + H2_B;
    // xg: per chunk-t, 8 bblk x 3072 u64 x 8 B = 196608 BYTES
    int chunk = 1024;
    while (chunk > 64 && fixed + (size_t)chunk * 196608 > ws_size) chunk >>= 1;

    char* ws = (char*)d_ws;
    unsigned long long* xg = (unsigned long long*)ws;  // chunk * 24576 u64
    size_t off = (size_t)chunk * 196608;
    unsigned short* hseq = (unsigned short*)(ws + off); off += HSEQ_B;
    unsigned short* pIH  = (unsigned short*)(ws + off); off += PACK_B;
    unsigned short* pHH  = (unsigned short*)(ws + off); off += PACK_B;
    float* hstate = (float*)(ws + off); off += HST_B;
    float* h2     = (float*)(ws + off);

    pack_weights<<<1536, 256, 0, stream>>>(W_ih, W_hh, pIH, pHH);

    for (int layer = 0; layer < 2; ++layer) {
        const unsigned short* wIH = pIH + (size_t)layer * 196608;
        const unsigned short* wHH = pHH + (size_t)layer * 196608;
        const float* bi = b_ih + layer * G_;
        const float* bh = b_hh + layer * G_;
        for (int c = 0; c * chunk < T_; ++c) {
            int t0 = c * chunk;
            if (layer == 0) {
                gemm_xg<false><<<chunk, 512, 65536, stream>>>(x, wIH, bi, bh, xg, t0);
                recur<0><<<8, 1024, 0, stream>>>(xg, wHH, bh, hseq, hstate, h2,
                                                 t0, chunk, c == 0);
            } else {
                gemm_xg<true><<<chunk, 512, 65536, stream>>>(hseq, wIH, bi, bh, xg, t0);
                recur<1><<<8, 1024, 0, stream>>>(xg, wHH, bh, hseq, hstate, h2,
                                                 t0, chunk, c == 0);
            }
        }
    }
    fc_out<<<128, 256, 0, stream>>>(h2, W_fc, b_fc, out);
}

// Round 15
// 4518.561 us; speedup vs baseline: 1.0284x; 1.0284x over previous
//
#include <hip/hip_runtime.h>
#include <stdint.h>

#define T_ 1024
#define H_ 256
#define G_ 768

typedef __attribute__((ext_vector_type(8))) short bf16x8;
typedef __attribute__((ext_vector_type(4))) float f32x4;

__device__ __forceinline__ unsigned short f2bf(float f) {
    union { float f; uint32_t u; } v; v.f = f;
    uint32_t u = v.u;
    return (unsigned short)((u + 0x7FFFu + ((u >> 16) & 1u)) >> 16);
}

// clamp-free, NaN-free activations (inf-safe limits)
__device__ __forceinline__ float sigm(float x) {
    return __builtin_amdgcn_rcpf(1.f + __expf(-x));
}
__device__ __forceinline__ float tanh_f(float x) {
    return __builtin_amdgcn_rcpf(1.f + __expf(-2.f * x)) * 2.f - 1.f;
}

// pack 4 f32 -> 4 bf16 in a u64, scalar-float inputs (K4/K10/K11/K14-proven in recur ONLY;
// CONDEMNED on MFMA acc values in gemm — K5..K9 post-mortems, K10 A/B)
__device__ __forceinline__ unsigned long long pk4bf(float a, float b, float c, float d) {
    uint32_t lo, hi;
    asm("v_cvt_pk_bf16_f32 %0, %1, %2" : "=v"(lo) : "v"(a), "v"(b));
    asm("v_cvt_pk_bf16_f32 %0, %1, %2" : "=v"(hi) : "v"(c), "v"(d));
    return ((unsigned long long)hi << 32) | (unsigned long long)lo;
}

// pack 4 f32 -> u64 with NO inline asm (f2bf bit-twiddle; for gemm epilogue; K10-proven)
__device__ __forceinline__ unsigned long long pk4bf_sw(float a, float b, float c, float d) {
    return (unsigned long long)f2bf(a)
         | ((unsigned long long)f2bf(b) << 16)
         | ((unsigned long long)f2bf(c) << 32)
         | ((unsigned long long)f2bf(d) << 48);
}

// unpack 4 bf16 (bits [15:0],[31:16],[47:32],[63:48]) -> 4 f32, exact
__device__ __forceinline__ void unpk4(unsigned long long v, float* o) {
    uint32_t lo = (uint32_t)v, hi = (uint32_t)(v >> 32);
    union { uint32_t u; float f; } a, b, c, d;
    a.u = lo << 16; b.u = lo & 0xffff0000u;
    c.u = hi << 16; d.u = hi & 0xffff0000u;
    o[0] = a.f; o[1] = b.f; o[2] = c.f; o[3] = d.f;
}

__device__ __forceinline__ void gload_lds16(const void* g, void* l) {
    __builtin_amdgcn_global_load_lds((const __attribute__((address_space(1))) void*)g,
                                     (__attribute__((address_space(3))) void*)l,
                                     16, 0, 0);
}

// Pack W (f32 [layer][768][256]) into MFMA A-fragment order, 48 flat tiles/layer:
// flat = (((layer*48 + gt)*8 + kt)*64 + l)*8 + j
// tile gt: recur wave w = gt/3 owns hidden units [16w,16w+16), mt = gt%3 (r,z,n)
// gate = (gt%3)*256 + (gt/3)*16 + (l&15)
// k    = kt*32 + (j&3) + ((l>>4)<<2) + ((j>>2)<<4)
__global__ void pack_weights(const float* __restrict__ W_ih, const float* __restrict__ W_hh,
                             unsigned short* __restrict__ pIH, unsigned short* __restrict__ pHH)
{
    int idx = blockIdx.x * blockDim.x + threadIdx.x;
    if (idx >= 2 * 48 * 8 * 64 * 8) return;
    int j = idx & 7;
    int l = (idx >> 3) & 63;
    int kt = (idx >> 9) & 7;
    int gt = (idx >> 12) % 48;
    int layer = (idx >> 12) / 48;
    int gate = (gt % 3) * 256 + (gt / 3) * 16 + (l & 15);
    int k = kt * 32 + (j & 3) + ((l >> 4) << 2) + ((j >> 2) << 4);
    size_t src = (size_t)layer * G_ * H_ + (size_t)gate * H_ + k;
    pIH[idx] = f2bf(W_ih[src]);
    pHH[idx] = f2bf(W_hh[src]);
}

// xg GEMM with bias fold (r/z get b_ih+b_hh, n gets b_ih), packed bf16 u64 output:
// xg_u64[(tloc*8+bblk)*3072 + gt*64 + l], gt = w*6+mt.  No inline asm in this kernel.
template<bool SRC_BF16>
__global__ __launch_bounds__(512, 2)
void gemm_xg(const void* __restrict__ srcp, const unsigned short* __restrict__ wpack,
             const float* __restrict__ bih, const float* __restrict__ bhh,
             unsigned long long* __restrict__ xg, int t0)
{
    extern __shared__ char smem[];
    unsigned short* Bt = (unsigned short*)smem; // [8][4096] shorts = 64KB
    const int tid = threadIdx.x;
    const int w = tid >> 6, l = tid & 63;
    const int bblk = blockIdx.x & 7;
    const int tg = blockIdx.x >> 3;
    const int tbase = t0 + tg * 8;
    const int b = l & 15, g = l >> 4;

    bf16x8 af[6][8];
    {
        const bf16x8* wp = (const bf16x8*)wpack;
        #pragma unroll
        for (int mt = 0; mt < 6; ++mt)
            #pragma unroll
            for (int kt = 0; kt < 8; ++kt)
                af[mt][kt] = wp[((w * 6 + mt) * 8 + kt) * 64 + l];
    }

    // folded biases for this wave's 6 tiles: C row = g*4+q
    float bsum[6][4];
    #pragma unroll
    for (int mt = 0; mt < 6; ++mt) {
        int gt = w * 6 + mt;
        int gbase = (gt % 3) * 256 + (gt / 3) * 16;
        #pragma unroll
        for (int q = 0; q < 4; ++q) {
            int gate = gbase + g * 4 + q;
            bsum[mt][q] = (gate < 512) ? (bih[gate] + bhh[gate]) : bih[gate];
        }
    }

    if (!SRC_BF16) {
        const float* x = (const float*)srcp;
        const int t_i = w;
        const int sb = (l >> 2) & 15;
        const int f0 = (l & 3) * 64;
        const float* row = x + ((size_t)(bblk * 16 + sb) * T_ + (tbase + t_i)) * H_ + f0;
        unsigned short* bt = Bt + t_i * 4096;
        #pragma unroll
        for (int i = 0; i < 64; i += 4) {
            f32x4 v = *(const f32x4*)(row + i);
            int f = f0 + i;
            bt[(f + 0) * 16 + sb] = f2bf(v[0]);
            bt[(f + 1) * 16 + sb] = f2bf(v[1]);
            bt[(f + 2) * 16 + sb] = f2bf(v[2]);
            bt[(f + 3) * 16 + sb] = f2bf(v[3]);
        }
    } else {
        const unsigned short* hs = (const unsigned short*)srcp;
        #pragma unroll
        for (int t_i = 0; t_i < 8; ++t_i) {
            const unsigned short* src = hs + ((size_t)bblk * T_ + (tbase + t_i)) * 4096
                                           + (size_t)(w * 64 + l) * 8;
            gload_lds16(src, Bt + t_i * 4096 + w * 512);
        }
    }
    __syncthreads();

    #pragma unroll 1
    for (int t_i = 0; t_i < 8; ++t_i) {
        const unsigned short* bt = Bt + t_i * 4096;
        f32x4 acc[6];
        #pragma unroll
        for (int mt = 0; mt < 6; ++mt) acc[mt] = (f32x4){0.f, 0.f, 0.f, 0.f};
        #pragma unroll
        for (int kt = 0; kt < 8; ++kt) {
            bf16x8 bf;
            if (SRC_BF16) {
                bf = *(const bf16x8*)(bt + kt * 512 + l * 8);
            } else {
                #pragma unroll
                for (int j = 0; j < 8; ++j) {
                    int k = kt * 32 + (j & 3) + (g << 2) + ((j >> 2) << 4);
                    bf[j] = (short)bt[k * 16 + b];
                }
            }
            #pragma unroll
            for (int mt = 0; mt < 6; ++mt)
                acc[mt] = __builtin_amdgcn_mfma_f32_16x16x32_bf16(af[mt][kt], bf, acc[mt], 0, 0, 0);
        }
        unsigned long long* dst = xg + ((size_t)(tg * 8 + t_i) * 8 + bblk) * 3072 + (size_t)w * 384;
        #pragma unroll
        for (int mt = 0; mt < 6; ++mt)
            dst[mt * 64 + l] = pk4bf_sw(acc[mt][0] + bsum[mt][0], acc[mt][1] + bsum[mt][1],
                                        acc[mt][2] + bsum[mt][2], acc[mt][3] + bsum[mt][3]);
    }
}

// Zero-communication recurrence, 16 waves/block (1024 threads):
// 8 blocks x 16 batch rows. Wave w owns hidden units [16w,16w+16): 24 A-fragments
// = 96 VGPRs. amdgpu_waves_per_eu(4,4) pins EXACTLY 4 waves/SIMD -> 128-reg budget
// (K14's launch_bounds(1024,4) let the allocator target 8 waves/EU -> 64 regs and
// re-stream weights from L2). xg double-buffered one step ahead (K4-proven):
// loads ride across the lgkm-only barrier, consumed next step.
template<int LAYER>
__global__
__attribute__((amdgpu_flat_work_group_size(1024, 1024), amdgpu_waves_per_eu(4, 4)))
void recur(const unsigned long long* __restrict__ xg, const unsigned short* __restrict__ wpack,
           const float* __restrict__ bhh,
           unsigned short* __restrict__ hseq, float* __restrict__ hstate,
           float* __restrict__ h2last, int t0, int nsteps, int first)
{
    __shared__ unsigned short hfrag[2][8][512];   // 16 KB
    const int tid = threadIdx.x;
    const int w = tid >> 6, l = tid & 63;
    const int bblk = blockIdx.x;
    const int g = l >> 4, b = l & 15;

    // this wave's 24 A-fragments, register-resident (96 VGPRs)
    bf16x8 af[3][8];
    {
        const bf16x8* wp = (const bf16x8*)wpack;
        #pragma unroll
        for (int mt = 0; mt < 3; ++mt)
            #pragma unroll
            for (int kt = 0; kt < 8; ++kt)
                af[mt][kt] = wp[((size_t)(w * 3 + mt) * 8 + kt) * 64 + l];
    }

    // n-gate hidden bias (the only bias recur needs; rest folded into xg)
    const int hid0 = w * 16 + g * 4;
    float nbh[4];
    #pragma unroll
    for (int q = 0; q < 4; ++q) nbh[q] = bhh[512 + hid0 + q];

    float hreg[4];
    #pragma unroll
    for (int q = 0; q < 4; ++q)
        hreg[q] = first ? 0.f : hstate[(size_t)(bblk * 16 + b) * H_ + hid0 + q];

    // publish position: fragment kt = w>>1, u64 at short offset l*8 + 4*(w&1)
    const int ktw = w >> 1;
    const int jo = (w & 1) * 4;
    *(unsigned long long*)(&hfrag[0][ktw][l * 8 + jo]) =
        pk4bf(hreg[0], hreg[1], hreg[2], hreg[3]);
    __syncthreads();

    // xg prologue for it=0
    unsigned long long xgA[3], xgB[3];
    {
        const unsigned long long* xv = xg + (size_t)bblk * 3072 + (size_t)(w * 3) * 64;
        #pragma unroll
        for (int mt = 0; mt < 3; ++mt) xgA[mt] = xv[mt * 64 + l];
    }

    auto step = [&](int it, unsigned long long (&cur)[3], unsigned long long (&nxt)[3]) {
        const int pr = it & 1;
        // h fragments (paired reads) + 24 MFMAs, weights in VGPRs
        const unsigned short* hb = &hfrag[pr][0][0];
        f32x4 acc[3];
        #pragma unroll
        for (int mt = 0; mt < 3; ++mt) acc[mt] = (f32x4){0.f, 0.f, 0.f, 0.f};
        #pragma unroll
        for (int kp = 0; kp < 4; ++kp) {
            bf16x8 h0 = *(const bf16x8*)(hb + (2 * kp) * 512 + l * 8);
            bf16x8 h1 = *(const bf16x8*)(hb + (2 * kp + 1) * 512 + l * 8);
            #pragma unroll
            for (int mt = 0; mt < 3; ++mt)
                acc[mt] = __builtin_amdgcn_mfma_f32_16x16x32_bf16(af[mt][2 * kp], h0, acc[mt], 0, 0, 0);
            #pragma unroll
            for (int mt = 0; mt < 3; ++mt)
                acc[mt] = __builtin_amdgcn_mfma_f32_16x16x32_bf16(af[mt][2 * kp + 1], h1, acc[mt], 0, 0, 0);
        }
        // gates (cur = packed-bf16 xg with biases folded, loaded one step ago)
        float cx0[4], cx1[4], cx2[4];
        unpk4(cur[0], cx0);
        unpk4(cur[1], cx1);
        unpk4(cur[2], cx2);
        float hn4[4];
        #pragma unroll
        for (int q = 0; q < 4; ++q) {
            float r = sigm(cx0[q] + acc[0][q]);
            float z = sigm(cx1[q] + acc[1][q]);
            float n = tanh_f(cx2[q] + r * (acc[2][q] + nbh[q]));
            float hn = n + z * (hreg[q] - n);
            hreg[q] = hn;
            hn4[q] = hn;
        }
        unsigned long long packed = pk4bf(hn4[0], hn4[1], hn4[2], hn4[3]);
        // publish h: LDS (next parity) + hseq (LAYER 0)
        *(unsigned long long*)(&hfrag[pr ^ 1][ktw][l * 8 + jo]) = packed;
        if (LAYER == 0)
            *(unsigned long long*)(hseq + ((size_t)bblk * T_ + (t0 + it)) * 4096
                                   + (size_t)ktw * 512 + l * 8 + jo) = packed;
        // prefetch next-step xg into the other buffer (rides across the barrier)
        {
            int itn = (it + 1 < nsteps) ? (it + 1) : it;
            const unsigned long long* xv = xg + ((size_t)itn * 8 + bblk) * 3072 + (size_t)(w * 3) * 64;
            #pragma unroll
            for (int mt = 0; mt < 3; ++mt) nxt[mt] = xv[mt * 64 + l];
        }
        // lgkm-only barrier: hfrag ordered; vmem (hseq store + xg loads) stays in flight
        asm volatile("s_waitcnt lgkmcnt(0)\n\ts_barrier" ::: "memory");
    };

    #pragma unroll 1
    for (int it2 = 0; it2 < nsteps; it2 += 2) {
        step(it2,     xgA, xgB);
        step(it2 + 1, xgB, xgA);
    }

    #pragma unroll
    for (int q = 0; q < 4; ++q)
        hstate[(size_t)(bblk * 16 + b) * H_ + hid0 + q] = hreg[q];
    if (LAYER == 1 && t0 + nsteps == T_) {
        #pragma unroll
        for (int q = 0; q < 4; ++q)
            h2last[(size_t)(bblk * 16 + b) * H_ + hid0 + q] = hreg[q];
    }
}

__global__ void fc_out(const float* __restrict__ h2, const float* __restrict__ W_fc,
                       const float* __restrict__ b_fc, float* __restrict__ out)
{
    __shared__ float hrow[256];
    const int bb = blockIdx.x, i = threadIdx.x;
    hrow[i] = h2[(size_t)bb * 256 + i];
    __syncthreads();
    float acc = b_fc[i];
    const float* wr = W_fc + (size_t)i * 256;
    #pragma unroll 8
    for (int k = 0; k < 256; ++k) acc += hrow[k] * wr[k];
    out[(size_t)bb * 256 + i] = sigm(acc);
}

extern "C" void kernel_launch(void* const* d_in, const int* in_sizes, int n_in,
                              void* d_out, int out_size, void* d_ws, size_t ws_size,
                              hipStream_t stream)
{
    const float* x    = (const float*)d_in[0];
    const float* W_ih = (const float*)d_in[1];
    const float* W_hh = (const float*)d_in[2];
    const float* b_ih = (const float*)d_in[3];
    const float* b_hh = (const float*)d_in[4];
    const float* W_fc = (const float*)d_in[5];
    const float* b_fc = (const float*)d_in[6];
    float* out = (float*)d_out;

    const size_t HSEQ_B = (size_t)8 * T_ * 4096 * 2;   // 64 MB
    const size_t PACK_B = 393216ull * 2;               // 768 KB each
    const size_t HST_B = 131072, H2_B = 131072;
    size_t fixed = HSEQ_B + 2 * PACK_B + HST_B + H2_B;
    // xg: per chunk-t, 8 bblk x 3072 u64 x 8 B = 196608 BYTES
    int chunk = 1024;
    while (chunk > 64 && fixed + (size_t)chunk * 196608 > ws_size) chunk >>= 1;

    char* ws = (char*)d_ws;
    unsigned long long* xg = (unsigned long long*)ws;  // chunk * 24576 u64
    size_t off = (size_t)chunk * 196608;
    unsigned short* hseq = (unsigned short*)(ws + off); off += HSEQ_B;
    unsigned short* pIH  = (unsigned short*)(ws + off); off += PACK_B;
    unsigned short* pHH  = (unsigned short*)(ws + off); off += PACK_B;
    float* hstate = (float*)(ws + off); off += HST_B;
    float* h2     = (float*)(ws + off);

    pack_weights<<<1536, 256, 0, stream>>>(W_ih, W_hh, pIH, pHH);

    for (int layer = 0; layer < 2; ++layer) {
        const unsigned short* wIH = pIH + (size_t)layer * 196608;
        const unsigned short* wHH = pHH + (size_t)layer * 196608;
        const float* bi = b_ih + layer * G_;
        const float* bh = b_hh + layer * G_;
        for (int c = 0; c * chunk < T_; ++c) {
            int t0 = c * chunk;
            if (layer == 0) {
                gemm_xg<false><<<chunk, 512, 65536, stream>>>(x, wIH, bi, bh, xg, t0);
                recur<0><<<8, 1024, 0, stream>>>(xg, wHH, bh, hseq, hstate, h2,
                                                 t0, chunk, c == 0);
            } else {
                gemm_xg<true><<<chunk, 512, 65536, stream>>>(hseq, wIH, bi, bh, xg, t0);
                recur<1><<<8, 1024, 0, stream>>>(xg, wHH, bh, hseq, hstate, h2,
                                                 t0, chunk, c == 0);
            }
        }
    }
    fc_out<<<128, 256, 0, stream>>>(h2, W_fc, b_fc, out);
}

// Round 16
// 4397.123 us; speedup vs baseline: 1.0568x; 1.0276x over previous
//
#include <hip/hip_runtime.h>
#include <stdint.h>

#define T_ 1024
#define H_ 256
#define G_ 768

typedef __attribute__((ext_vector_type(8))) short bf16x8;
typedef __attribute__((ext_vector_type(4))) float f32x4;

__device__ __forceinline__ unsigned short f2bf(float f) {
    union { float f; uint32_t u; } v; v.f = f;
    uint32_t u = v.u;
    return (unsigned short)((u + 0x7FFFu + ((u >> 16) & 1u)) >> 16);
}

// clamp-free, NaN-free activations (inf-safe limits)
__device__ __forceinline__ float sigm(float x) {
    return __builtin_amdgcn_rcpf(1.f + __expf(-x));
}
__device__ __forceinline__ float tanh_f(float x) {
    return __builtin_amdgcn_rcpf(1.f + __expf(-2.f * x)) * 2.f - 1.f;
}

// pack 4 f32 -> 4 bf16 in a u64, scalar-float inputs (K4/K10/K11-proven in recur ONLY;
// CONDEMNED on MFMA acc values in gemm — K5..K9 post-mortems, K10 A/B)
__device__ __forceinline__ unsigned long long pk4bf(float a, float b, float c, float d) {
    uint32_t lo, hi;
    asm("v_cvt_pk_bf16_f32 %0, %1, %2" : "=v"(lo) : "v"(a), "v"(b));
    asm("v_cvt_pk_bf16_f32 %0, %1, %2" : "=v"(hi) : "v"(c), "v"(d));
    return ((unsigned long long)hi << 32) | (unsigned long long)lo;
}

// pack 4 f32 -> u64 with NO inline asm (f2bf bit-twiddle; for gemm epilogue; K10-proven)
__device__ __forceinline__ unsigned long long pk4bf_sw(float a, float b, float c, float d) {
    return (unsigned long long)f2bf(a)
         | ((unsigned long long)f2bf(b) << 16)
         | ((unsigned long long)f2bf(c) << 32)
         | ((unsigned long long)f2bf(d) << 48);
}

// unpack 4 bf16 (bits [15:0],[31:16],[47:32],[63:48]) -> 4 f32, exact
__device__ __forceinline__ void unpk4(unsigned long long v, float* o) {
    uint32_t lo = (uint32_t)v, hi = (uint32_t)(v >> 32);
    union { uint32_t u; float f; } a, b, c, d;
    a.u = lo << 16; b.u = lo & 0xffff0000u;
    c.u = hi << 16; d.u = hi & 0xffff0000u;
    o[0] = a.f; o[1] = b.f; o[2] = c.f; o[3] = d.f;
}

__device__ __forceinline__ void gload_lds16(const void* g, void* l) {
    __builtin_amdgcn_global_load_lds((const __attribute__((address_space(1))) void*)g,
                                     (__attribute__((address_space(3))) void*)l,
                                     16, 0, 0);
}

// Pack W (f32 [layer][768][256]) into per-wave MFMA A-fragment order (K2-proven):
// flat = ((((layer*8 + w)*6 + mt)*8 + kt)*64 + l)*8 + j
// gate = (mt>>1)*256 + w*32 + (mt&1)*16 + (l&15)
// k    = kt*32 + (j&3) + ((l>>4)<<2) + ((j>>2)<<4)
__global__ void pack_weights(const float* __restrict__ W_ih, const float* __restrict__ W_hh,
                             unsigned short* __restrict__ pIH, unsigned short* __restrict__ pHH)
{
    int idx = blockIdx.x * blockDim.x + threadIdx.x;
    if (idx >= 2 * 8 * 6 * 8 * 64 * 8) return;
    int pos = idx;
    int j = pos & 7;  pos >>= 3;
    int l = pos & 63; pos >>= 6;
    int kt = pos & 7; pos >>= 3;
    int mt = pos % 6; pos /= 6;
    int w = pos & 7;  pos >>= 3;
    int layer = pos;
    int gate = (mt >> 1) * 256 + w * 32 + (mt & 1) * 16 + (l & 15);
    int k = kt * 32 + (j & 3) + ((l >> 4) << 2) + ((j >> 2) << 4);
    size_t src = (size_t)layer * G_ * H_ + (size_t)gate * H_ + k;
    pIH[idx] = f2bf(W_ih[src]);
    pHH[idx] = f2bf(W_hh[src]);
}

// xg GEMM with bias fold (r/z: b_ih+b_hh; n: b_ih), packed bf16 u64 output:
// xg_u64[(tloc*8+bblk)*3072 + w*384 + mt*64 + l].  No inline asm in this kernel.
template<bool SRC_BF16>
__global__ __launch_bounds__(512, 2)
void gemm_xg(const void* __restrict__ srcp, const unsigned short* __restrict__ wpack,
             const float* __restrict__ bih, const float* __restrict__ bhh,
             unsigned long long* __restrict__ xg, int t0)
{
    extern __shared__ char smem[];
    unsigned short* Bt = (unsigned short*)smem; // [8][4096] shorts = 64KB
    const int tid = threadIdx.x;
    const int w = tid >> 6, l = tid & 63;
    const int bblk = blockIdx.x & 7;
    const int tg = blockIdx.x >> 3;
    const int tbase = t0 + tg * 8;
    const int b = l & 15, g = l >> 4;

    bf16x8 af[6][8];
    {
        const bf16x8* wp = (const bf16x8*)wpack;
        #pragma unroll
        for (int mt = 0; mt < 6; ++mt)
            #pragma unroll
            for (int kt = 0; kt < 8; ++kt)
                af[mt][kt] = wp[((w * 6 + mt) * 8 + kt) * 64 + l];
    }

    // folded biases for this wave's 6 tiles: C row = g*4+q
    float bsum[6][4];
    #pragma unroll
    for (int mt = 0; mt < 6; ++mt)
        #pragma unroll
        for (int q = 0; q < 4; ++q) {
            int gate = (mt >> 1) * 256 + w * 32 + (mt & 1) * 16 + g * 4 + q;
            bsum[mt][q] = (gate < 512) ? (bih[gate] + bhh[gate]) : bih[gate];
        }

    if (!SRC_BF16) {
        const float* x = (const float*)srcp;
        const int t_i = w;
        const int sb = (l >> 2) & 15;
        const int f0 = (l & 3) * 64;
        const float* row = x + ((size_t)(bblk * 16 + sb) * T_ + (tbase + t_i)) * H_ + f0;
        unsigned short* bt = Bt + t_i * 4096;
        #pragma unroll
        for (int i = 0; i < 64; i += 4) {
            f32x4 v = *(const f32x4*)(row + i);
            int f = f0 + i;
            bt[(f + 0) * 16 + sb] = f2bf(v[0]);
            bt[(f + 1) * 16 + sb] = f2bf(v[1]);
            bt[(f + 2) * 16 + sb] = f2bf(v[2]);
            bt[(f + 3) * 16 + sb] = f2bf(v[3]);
        }
    } else {
        const unsigned short* hs = (const unsigned short*)srcp;
        #pragma unroll
        for (int t_i = 0; t_i < 8; ++t_i) {
            const unsigned short* src = hs + ((size_t)bblk * T_ + (tbase + t_i)) * 4096
                                           + (size_t)(w * 64 + l) * 8;
            gload_lds16(src, Bt + t_i * 4096 + w * 512);
        }
    }
    __syncthreads();

    #pragma unroll 1
    for (int t_i = 0; t_i < 8; ++t_i) {
        const unsigned short* bt = Bt + t_i * 4096;
        f32x4 acc[6];
        #pragma unroll
        for (int mt = 0; mt < 6; ++mt) acc[mt] = (f32x4){0.f, 0.f, 0.f, 0.f};
        #pragma unroll
        for (int kt = 0; kt < 8; ++kt) {
            bf16x8 bf;
            if (SRC_BF16) {
                bf = *(const bf16x8*)(bt + kt * 512 + l * 8);
            } else {
                #pragma unroll
                for (int j = 0; j < 8; ++j) {
                    int k = kt * 32 + (j & 3) + (g << 2) + ((j >> 2) << 4);
                    bf[j] = (short)bt[k * 16 + b];
                }
            }
            #pragma unroll
            for (int mt = 0; mt < 6; ++mt)
                acc[mt] = __builtin_amdgcn_mfma_f32_16x16x32_bf16(af[mt][kt], bf, acc[mt], 0, 0, 0);
        }
        unsigned long long* dst = xg + ((size_t)(tg * 8 + t_i) * 8 + bblk) * 3072 + (size_t)w * 384;
        #pragma unroll
        for (int mt = 0; mt < 6; ++mt)
            dst[mt * 64 + l] = pk4bf_sw(acc[mt][0] + bsum[mt][0], acc[mt][1] + bsum[mt][1],
                                        acc[mt][2] + bsum[mt][2], acc[mt][3] + bsum[mt][3]);
    }
}

// Zero-communication recurrence (K11 base), with intra-wave pipe overlap:
// per step, Phase A = 24 MFMAs for s=0 tiles (acc 0,2,4), then gates(s=0) VALU +
// early h-publish — source-placed BEFORE Phase B's independent 24 MFMAs (acc 1,3,5)
// so the scheduler can issue gate VALU into matrix-pipe stall cycles. xg is
// double-buffered one step ahead (loads ride across the lgkm-only barrier).
// W_hh: kt0..6 in regs (af[6][7]), kt7 in LDS. Biases folded into xg at gemm.
template<int LAYER>
__global__ __launch_bounds__(512, 2)
void recur(const unsigned long long* __restrict__ xg, const unsigned short* __restrict__ wpack,
           const float* __restrict__ bhh,
           unsigned short* __restrict__ hseq, float* __restrict__ hstate,
           float* __restrict__ h2last, int t0, int nsteps, int first)
{
    extern __shared__ char smem[];
    unsigned short* wlds  = (unsigned short*)smem;             // [8][6][512] u16 = 48KB (kt7)
    unsigned short* hfrag = (unsigned short*)(smem + 49152);   // [2][8][512] u16 = 16KB
    const int tid = threadIdx.x;
    const int w = tid >> 6, l = tid & 63;
    const int bblk = blockIdx.x;
    const int g = l >> 4, b = l & 15;

    // reg-resident A-fragments: kt 0..6
    bf16x8 af[6][7];
    {
        const bf16x8* wp = (const bf16x8*)wpack;
        #pragma unroll
        for (int mt = 0; mt < 6; ++mt)
            #pragma unroll
            for (int kt = 0; kt < 7; ++kt)
                af[mt][kt] = wp[((w * 6 + mt) * 8 + kt) * 64 + l];
    }
    // LDS-resident A-fragments: kt 7 only
    #pragma unroll
    for (int mt = 0; mt < 6; ++mt)
        gload_lds16(wpack + ((((size_t)(w * 6 + mt)) * 8 + 7) * 64 + l) * 8,
                    wlds + (w * 6 + mt) * 512);

    // n-gate hidden bias in registers (the only bias recur needs)
    float nbh[2][4];
    #pragma unroll
    for (int s = 0; s < 2; ++s)
        #pragma unroll
        for (int q = 0; q < 4; ++q)
            nbh[s][q] = bhh[512 + w * 32 + s * 16 + g * 4 + q];

    float hreg[2][4];
    #pragma unroll
    for (int s = 0; s < 2; ++s)
        #pragma unroll
        for (int q = 0; q < 4; ++q) {
            int hid = w * 32 + s * 16 + g * 4 + q;
            hreg[s][q] = first ? 0.f : hstate[(size_t)(bblk * 16 + b) * H_ + hid];
        }
    // init hfrag parity 0: wave w owns kt=w; two u64 quads (s=0, s=1)
    {
        unsigned long long p0 = pk4bf(hreg[0][0], hreg[0][1], hreg[0][2], hreg[0][3]);
        unsigned long long p1 = pk4bf(hreg[1][0], hreg[1][1], hreg[1][2], hreg[1][3]);
        *(unsigned long long*)(&hfrag[(size_t)w * 512 + l * 8])     = p0;
        *(unsigned long long*)(&hfrag[(size_t)w * 512 + l * 8 + 4]) = p1;
    }
    __syncthreads();   // drains weight gload_lds + hfrag writes (once)

    // strength-reduced pointers (advance per step)
    const unsigned long long* xp = xg + (size_t)bblk * 3072 + (size_t)w * 384 + l;
    unsigned short* hq = hseq + ((size_t)bblk * T_ + t0) * 4096 + (size_t)w * 512 + l * 8;

    // xg prologue for it=0
    unsigned long long xgA[6], xgB[6];
    #pragma unroll
    for (int mt = 0; mt < 6; ++mt) xgA[mt] = xp[mt * 64];
    xp += 24576;

    auto step = [&](int it, unsigned long long (&cur)[6], unsigned long long (&nxt)[6]) {
        const int pr = it & 1;
        const unsigned short* hb = hfrag + (size_t)pr * 4096;

        // ---- Phase A: s=0 tiles (acc mt 0,2,4) ----
        f32x4 accA[3];
        #pragma unroll
        for (int i = 0; i < 3; ++i) accA[i] = (f32x4){0.f, 0.f, 0.f, 0.f};
        #pragma unroll
        for (int kp = 0; kp < 3; ++kp) {
            bf16x8 h0 = *(const bf16x8*)(hb + (2 * kp) * 512 + l * 8);
            bf16x8 h1 = *(const bf16x8*)(hb + (2 * kp + 1) * 512 + l * 8);
            #pragma unroll
            for (int i = 0; i < 3; ++i)
                accA[i] = __builtin_amdgcn_mfma_f32_16x16x32_bf16(af[2 * i][2 * kp], h0, accA[i], 0, 0, 0);
            #pragma unroll
            for (int i = 0; i < 3; ++i)
                accA[i] = __builtin_amdgcn_mfma_f32_16x16x32_bf16(af[2 * i][2 * kp + 1], h1, accA[i], 0, 0, 0);
        }
        {
            bf16x8 h6 = *(const bf16x8*)(hb + 6 * 512 + l * 8);
            #pragma unroll
            for (int i = 0; i < 3; ++i)
                accA[i] = __builtin_amdgcn_mfma_f32_16x16x32_bf16(af[2 * i][6], h6, accA[i], 0, 0, 0);
            bf16x8 h7 = *(const bf16x8*)(hb + 7 * 512 + l * 8);
            #pragma unroll
            for (int i = 0; i < 3; ++i) {
                bf16x8 a = *(const bf16x8*)(wlds + (w * 6 + 2 * i) * 512 + l * 8);
                accA[i] = __builtin_amdgcn_mfma_f32_16x16x32_bf16(a, h7, accA[i], 0, 0, 0);
            }
        }
        // ---- gates s=0 + early publish (independent of Phase B MFMAs) ----
        {
            float cx0[4], cx1[4], cx2[4];
            unpk4(cur[0], cx0);
            unpk4(cur[2], cx1);
            unpk4(cur[4], cx2);
            float hn4[4];
            #pragma unroll
            for (int q = 0; q < 4; ++q) {
                float r = sigm(cx0[q] + accA[0][q]);
                float z = sigm(cx1[q] + accA[1][q]);
                float n = tanh_f(cx2[q] + r * (accA[2][q] + nbh[0][q]));
                float hn = n + z * (hreg[0][q] - n);
                hreg[0][q] = hn;
                hn4[q] = hn;
            }
            unsigned long long pk0 = pk4bf(hn4[0], hn4[1], hn4[2], hn4[3]);
            *(unsigned long long*)(&hfrag[(size_t)(pr ^ 1) * 4096 + w * 512 + l * 8]) = pk0;
            if (LAYER == 0) *(unsigned long long*)hq = pk0;
        }
        // ---- Phase B: s=1 tiles (acc mt 1,3,5) ----
        f32x4 accB[3];
        #pragma unroll
        for (int i = 0; i < 3; ++i) accB[i] = (f32x4){0.f, 0.f, 0.f, 0.f};
        #pragma unroll
        for (int kp = 0; kp < 3; ++kp) {
            bf16x8 h0 = *(const bf16x8*)(hb + (2 * kp) * 512 + l * 8);
            bf16x8 h1 = *(const bf16x8*)(hb + (2 * kp + 1) * 512 + l * 8);
            #pragma unroll
            for (int i = 0; i < 3; ++i)
                accB[i] = __builtin_amdgcn_mfma_f32_16x16x32_bf16(af[2 * i + 1][2 * kp], h0, accB[i], 0, 0, 0);
            #pragma unroll
            for (int i = 0; i < 3; ++i)
                accB[i] = __builtin_amdgcn_mfma_f32_16x16x32_bf16(af[2 * i + 1][2 * kp + 1], h1, accB[i], 0, 0, 0);
        }
        {
            bf16x8 h6 = *(const bf16x8*)(hb + 6 * 512 + l * 8);
            #pragma unroll
            for (int i = 0; i < 3; ++i)
                accB[i] = __builtin_amdgcn_mfma_f32_16x16x32_bf16(af[2 * i + 1][6], h6, accB[i], 0, 0, 0);
            bf16x8 h7 = *(const bf16x8*)(hb + 7 * 512 + l * 8);
            #pragma unroll
            for (int i = 0; i < 3; ++i) {
                bf16x8 a = *(const bf16x8*)(wlds + (w * 6 + 2 * i + 1) * 512 + l * 8);
                accB[i] = __builtin_amdgcn_mfma_f32_16x16x32_bf16(a, h7, accB[i], 0, 0, 0);
            }
        }
        // ---- gates s=1 + publish ----
        {
            float cx0[4], cx1[4], cx2[4];
            unpk4(cur[1], cx0);
            unpk4(cur[3], cx1);
            unpk4(cur[5], cx2);
            float hn4[4];
            #pragma unroll
            for (int q = 0; q < 4; ++q) {
                float r = sigm(cx0[q] + accB[0][q]);
                float z = sigm(cx1[q] + accB[1][q]);
                float n = tanh_f(cx2[q] + r * (accB[2][q] + nbh[1][q]));
                float hn = n + z * (hreg[1][q] - n);
                hreg[1][q] = hn;
                hn4[q] = hn;
            }
            unsigned long long pk1 = pk4bf(hn4[0], hn4[1], hn4[2], hn4[3]);
            *(unsigned long long*)(&hfrag[(size_t)(pr ^ 1) * 4096 + w * 512 + l * 8 + 4]) = pk1;
            if (LAYER == 0) *(unsigned long long*)(hq + 4) = pk1;
        }
        hq += 4096;
        // prefetch next-step xg into the other buffer (rides across the barrier)
        if (it + 1 < nsteps) {
            #pragma unroll
            for (int mt = 0; mt < 6; ++mt) nxt[mt] = xp[mt * 64];
        }
        xp += 24576;
        // lgkm-only barrier: hfrag ordered; vmem (hseq store + xg loads) in flight
        asm volatile("s_waitcnt lgkmcnt(0)\n\ts_barrier" ::: "memory");
    };

    #pragma unroll 1
    for (int it2 = 0; it2 < nsteps; it2 += 2) {
        step(it2,     xgA, xgB);
        step(it2 + 1, xgB, xgA);
    }

    #pragma unroll
    for (int s = 0; s < 2; ++s)
        #pragma unroll
        for (int q = 0; q < 4; ++q) {
            int hid = w * 32 + s * 16 + g * 4 + q;
            hstate[(size_t)(bblk * 16 + b) * H_ + hid] = hreg[s][q];
        }
    if (LAYER == 1 && t0 + nsteps == T_) {
        #pragma unroll
        for (int s = 0; s < 2; ++s)
            #pragma unroll
            for (int q = 0; q < 4; ++q) {
                int hid = w * 32 + s * 16 + g * 4 + q;
                h2last[(size_t)(bblk * 16 + b) * H_ + hid] = hreg[s][q];
            }
    }
}

__global__ void fc_out(const float* __restrict__ h2, const float* __restrict__ W_fc,
                       const float* __restrict__ b_fc, float* __restrict__ out)
{
    __shared__ float hrow[256];
    const int bb = blockIdx.x, i = threadIdx.x;
    hrow[i] = h2[(size_t)bb * 256 + i];
    __syncthreads();
    float acc = b_fc[i];
    const float* wr = W_fc + (size_t)i * 256;
    #pragma unroll 8
    for (int k = 0; k < 256; ++k) acc += hrow[k] * wr[k];
    out[(size_t)bb * 256 + i] = sigm(acc);
}

extern "C" void kernel_launch(void* const* d_in, const int* in_sizes, int n_in,
                              void* d_out, int out_size, void* d_ws, size_t ws_size,
                              hipStream_t stream)
{
    const float* x    = (const float*)d_in[0];
    const float* W_ih = (const float*)d_in[1];
    const float* W_hh = (const float*)d_in[2];
    const float* b_ih = (const float*)d_in[3];
    const float* b_hh = (const float*)d_in[4];
    const float* W_fc = (const float*)d_in[5];
    const float* b_fc = (const float*)d_in[6];
    float* out = (float*)d_out;

    const size_t HSEQ_B = (size_t)8 * T_ * 4096 * 2;   // 64 MB
    const size_t PACK_B = 393216ull * 2;               // 768 KB each
    const size_t HST_B = 131072, H2_B = 131072;
    size_t fixed = HSEQ_B + 2 * PACK_B + HST_B + H2_B;
    // xg: per chunk-t, 8 bblk x 3072 u64 x 8 B = 196608 BYTES
    int chunk = 1024;
    while (chunk > 64 && fixed + (size_t)chunk * 196608 > ws_size) chunk >>= 1;

    char* ws = (char*)d_ws;
    unsigned long long* xg = (unsigned long long*)ws;  // chunk * 24576 u64
    size_t off = (size_t)chunk * 196608;
    unsigned short* hseq = (unsigned short*)(ws + off); off += HSEQ_B;
    unsigned short* pIH  = (unsigned short*)(ws + off); off += PACK_B;
    unsigned short* pHH  = (unsigned short*)(ws + off); off += PACK_B;
    float* hstate = (float*)(ws + off); off += HST_B;
    float* h2     = (float*)(ws + off);

    pack_weights<<<1536, 256, 0, stream>>>(W_ih, W_hh, pIH, pHH);

    const int RLDS = 49152 + 16384;   // wlds(kt7) + hfrag
    for (int layer = 0; layer < 2; ++layer) {
        const unsigned short* wIH = pIH + (size_t)layer * 196608;
        const unsigned short* wHH = pHH + (size_t)layer * 196608;
        const float* bi = b_ih + layer * G_;
        const float* bh = b_hh + layer * G_;
        for (int c = 0; c * chunk < T_; ++c) {
            int t0 = c * chunk;
            if (layer == 0) {
                gemm_xg<false><<<chunk, 512, 65536, stream>>>(x, wIH, bi, bh, xg, t0);
                recur<0><<<8, 512, RLDS, stream>>>(xg, wHH, bh, hseq, hstate, h2,
                                                   t0, chunk, c == 0);
            } else {
                gemm_xg<true><<<chunk, 512, 65536, stream>>>(hseq, wIH, bi, bh, xg, t0);
                recur<1><<<8, 512, RLDS, stream>>>(xg, wHH, bh, hseq, hstate, h2,
                                                   t0, chunk, c == 0);
            }
        }
    }
    fc_out<<<128, 256, 0, stream>>>(h2, W_fc, b_fc, out);
}

// Round 17
// 3425.410 us; speedup vs baseline: 1.3566x; 1.2837x over previous
//
#include <hip/hip_runtime.h>
#include <stdint.h>

#define T_ 1024
#define H_ 256
#define G_ 768

typedef __attribute__((ext_vector_type(8))) short bf16x8;
typedef __attribute__((ext_vector_type(4))) float f32x4;

__device__ __forceinline__ unsigned short f2bf(float f) {
    union { float f; uint32_t u; } v; v.f = f;
    uint32_t u = v.u;
    return (unsigned short)((u + 0x7FFFu + ((u >> 16) & 1u)) >> 16);
}

// clamp-free, NaN-free activations (inf-safe limits)
__device__ __forceinline__ float sigm(float x) {
    return __builtin_amdgcn_rcpf(1.f + __expf(-x));
}
__device__ __forceinline__ float tanh_f(float x) {
    return __builtin_amdgcn_rcpf(1.f + __expf(-2.f * x)) * 2.f - 1.f;
}

// pack 4 f32 -> 4 bf16 in a u64, scalar-float inputs (K4/K10/K11-proven in recur ONLY;
// CONDEMNED on MFMA acc values in gemm — K5..K9 post-mortems, K10 A/B)
__device__ __forceinline__ unsigned long long pk4bf(float a, float b, float c, float d) {
    uint32_t lo, hi;
    asm("v_cvt_pk_bf16_f32 %0, %1, %2" : "=v"(lo) : "v"(a), "v"(b));
    asm("v_cvt_pk_bf16_f32 %0, %1, %2" : "=v"(hi) : "v"(c), "v"(d));
    return ((unsigned long long)hi << 32) | (unsigned long long)lo;
}

// pack 4 f32 -> u64 with NO inline asm (f2bf bit-twiddle; for gemm epilogue; K10-proven)
__device__ __forceinline__ unsigned long long pk4bf_sw(float a, float b, float c, float d) {
    return (unsigned long long)f2bf(a)
         | ((unsigned long long)f2bf(b) << 16)
         | ((unsigned long long)f2bf(c) << 32)
         | ((unsigned long long)f2bf(d) << 48);
}

// unpack 4 bf16 (bits [15:0],[31:16],[47:32],[63:48]) -> 4 f32, exact
__device__ __forceinline__ void unpk4(unsigned long long v, float* o) {
    uint32_t lo = (uint32_t)v, hi = (uint32_t)(v >> 32);
    union { uint32_t u; float f; } a, b, c, d;
    a.u = lo << 16; b.u = lo & 0xffff0000u;
    c.u = hi << 16; d.u = hi & 0xffff0000u;
    o[0] = a.f; o[1] = b.f; o[2] = c.f; o[3] = d.f;
}

__device__ __forceinline__ void gload_lds16(const void* g, void* l) {
    __builtin_amdgcn_global_load_lds((const __attribute__((address_space(1))) void*)g,
                                     (__attribute__((address_space(3))) void*)l,
                                     16, 0, 0);
}

// Pack W (f32 [layer][768][256]) into per-wave MFMA A-fragment order (K2-proven):
// flat = ((((layer*8 + w)*6 + mt)*8 + kt)*64 + l)*8 + j
// gate = (mt>>1)*256 + w*32 + (mt&1)*16 + (l&15)
// k    = kt*32 + (j&3) + ((l>>4)<<2) + ((j>>2)<<4)
__global__ void pack_weights(const float* __restrict__ W_ih, const float* __restrict__ W_hh,
                             unsigned short* __restrict__ pIH, unsigned short* __restrict__ pHH)
{
    int idx = blockIdx.x * blockDim.x + threadIdx.x;
    if (idx >= 2 * 8 * 6 * 8 * 64 * 8) return;
    int pos = idx;
    int j = pos & 7;  pos >>= 3;
    int l = pos & 63; pos >>= 6;
    int kt = pos & 7; pos >>= 3;
    int mt = pos % 6; pos /= 6;
    int w = pos & 7;  pos >>= 3;
    int layer = pos;
    int gate = (mt >> 1) * 256 + w * 32 + (mt & 1) * 16 + (l & 15);
    int k = kt * 32 + (j & 3) + ((l >> 4) << 2) + ((j >> 2) << 4);
    size_t src = (size_t)layer * G_ * H_ + (size_t)gate * H_ + k;
    pIH[idx] = f2bf(W_ih[src]);
    pHH[idx] = f2bf(W_hh[src]);
}

// xg GEMM with bias fold (r/z: b_ih+b_hh; n: b_ih), packed bf16 u64 output:
// xg_u64[(tloc*8+bblk)*3072 + w*384 + mt*64 + l].  No inline asm in this kernel.
template<bool SRC_BF16>
__global__ __launch_bounds__(512, 2)
void gemm_xg(const void* __restrict__ srcp, const unsigned short* __restrict__ wpack,
             const float* __restrict__ bih, const float* __restrict__ bhh,
             unsigned long long* __restrict__ xg, int t0)
{
    extern __shared__ char smem[];
    unsigned short* Bt = (unsigned short*)smem; // [8][4096] shorts = 64KB
    const int tid = threadIdx.x;
    const int w = tid >> 6, l = tid & 63;
    const int bblk = blockIdx.x & 7;
    const int tg = blockIdx.x >> 3;
    const int tbase = t0 + tg * 8;
    const int b = l & 15, g = l >> 4;

    bf16x8 af[6][8];
    {
        const bf16x8* wp = (const bf16x8*)wpack;
        #pragma unroll
        for (int mt = 0; mt < 6; ++mt)
            #pragma unroll
            for (int kt = 0; kt < 8; ++kt)
                af[mt][kt] = wp[((w * 6 + mt) * 8 + kt) * 64 + l];
    }

    // folded biases for this wave's 6 tiles: C row = g*4+q
    float bsum[6][4];
    #pragma unroll
    for (int mt = 0; mt < 6; ++mt)
        #pragma unroll
        for (int q = 0; q < 4; ++q) {
            int gate = (mt >> 1) * 256 + w * 32 + (mt & 1) * 16 + g * 4 + q;
            bsum[mt][q] = (gate < 512) ? (bih[gate] + bhh[gate]) : bih[gate];
        }

    if (!SRC_BF16) {
        const float* x = (const float*)srcp;
        const int t_i = w;
        const int sb = (l >> 2) & 15;
        const int f0 = (l & 3) * 64;
        const float* row = x + ((size_t)(bblk * 16 + sb) * T_ + (tbase + t_i)) * H_ + f0;
        unsigned short* bt = Bt + t_i * 4096;
        #pragma unroll
        for (int i = 0; i < 64; i += 4) {
            f32x4 v = *(const f32x4*)(row + i);
            int f = f0 + i;
            bt[(f + 0) * 16 + sb] = f2bf(v[0]);
            bt[(f + 1) * 16 + sb] = f2bf(v[1]);
            bt[(f + 2) * 16 + sb] = f2bf(v[2]);
            bt[(f + 3) * 16 + sb] = f2bf(v[3]);
        }
    } else {
        const unsigned short* hs = (const unsigned short*)srcp;
        #pragma unroll
        for (int t_i = 0; t_i < 8; ++t_i) {
            const unsigned short* src = hs + ((size_t)bblk * T_ + (tbase + t_i)) * 4096
                                           + (size_t)(w * 64 + l) * 8;
            gload_lds16(src, Bt + t_i * 4096 + w * 512);
        }
    }
    __syncthreads();

    #pragma unroll 1
    for (int t_i = 0; t_i < 8; ++t_i) {
        const unsigned short* bt = Bt + t_i * 4096;
        f32x4 acc[6];
        #pragma unroll
        for (int mt = 0; mt < 6; ++mt) acc[mt] = (f32x4){0.f, 0.f, 0.f, 0.f};
        #pragma unroll
        for (int kt = 0; kt < 8; ++kt) {
            bf16x8 bf;
            if (SRC_BF16) {
                bf = *(const bf16x8*)(bt + kt * 512 + l * 8);
            } else {
                #pragma unroll
                for (int j = 0; j < 8; ++j) {
                    int k = kt * 32 + (j & 3) + (g << 2) + ((j >> 2) << 4);
                    bf[j] = (short)bt[k * 16 + b];
                }
            }
            #pragma unroll
            for (int mt = 0; mt < 6; ++mt)
                acc[mt] = __builtin_amdgcn_mfma_f32_16x16x32_bf16(af[mt][kt], bf, acc[mt], 0, 0, 0);
        }
        unsigned long long* dst = xg + ((size_t)(tg * 8 + t_i) * 8 + bblk) * 3072 + (size_t)w * 384;
        #pragma unroll
        for (int mt = 0; mt < 6; ++mt)
            dst[mt * 64 + l] = pk4bf_sw(acc[mt][0] + bsum[mt][0], acc[mt][1] + bsum[mt][1],
                                        acc[mt][2] + bsum[mt][2], acc[mt][3] + bsum[mt][3]);
    }
}

// Zero-communication recurrence (EXACT K11 structure) + REGISTER PINNING:
// K11 demanded 168 weight VGPRs but VGPR_Count=128 — the allocator rematerializes
// const-pointer loads (re-streams weights from L2 every step) instead of keeping
// them live (proven across K13 budget-256->used-128, K14 budget-128->used-64).
// The identity asm "+v" makes each fragment asm-defined: it CANNOT be
// rematerialized, forcing true register residency. Zero runtime cost.
template<int LAYER>
__global__ __launch_bounds__(512, 2)
void recur(const unsigned long long* __restrict__ xg, const unsigned short* __restrict__ wpack,
           const float* __restrict__ bhh,
           unsigned short* __restrict__ hseq, float* __restrict__ hstate,
           float* __restrict__ h2last, int t0, int nsteps, int first)
{
    extern __shared__ char smem[];
    unsigned short* wlds  = (unsigned short*)smem;             // [8][6][512] u16 = 48KB (kt7)
    unsigned short* hfrag = (unsigned short*)(smem + 49152);   // [2][8][512] u16 = 16KB
    const int tid = threadIdx.x;
    const int w = tid >> 6, l = tid & 63;
    const int bblk = blockIdx.x;
    const int g = l >> 4, b = l & 15;

    // reg-resident A-fragments: kt 0..6, PINNED in VGPRs via identity asm
    bf16x8 af[6][7];
    {
        const bf16x8* wp = (const bf16x8*)wpack;
        #pragma unroll
        for (int mt = 0; mt < 6; ++mt)
            #pragma unroll
            for (int kt = 0; kt < 7; ++kt) {
                af[mt][kt] = wp[((w * 6 + mt) * 8 + kt) * 64 + l];
                asm volatile("" : "+v"(af[mt][kt]));   // pin: not rematerializable
            }
    }
    // LDS-resident A-fragments: kt 7 only
    #pragma unroll
    for (int mt = 0; mt < 6; ++mt)
        gload_lds16(wpack + ((((size_t)(w * 6 + mt)) * 8 + 7) * 64 + l) * 8,
                    wlds + (w * 6 + mt) * 512);

    // n-gate hidden bias in registers (the only bias recur needs)
    float nbh[2][4];
    #pragma unroll
    for (int s = 0; s < 2; ++s)
        #pragma unroll
        for (int q = 0; q < 4; ++q)
            nbh[s][q] = bhh[512 + w * 32 + s * 16 + g * 4 + q];

    float hreg[2][4];
    #pragma unroll
    for (int s = 0; s < 2; ++s)
        #pragma unroll
        for (int q = 0; q < 4; ++q) {
            int hid = w * 32 + s * 16 + g * 4 + q;
            hreg[s][q] = first ? 0.f : hstate[(size_t)(bblk * 16 + b) * H_ + hid];
        }
    // init hfrag parity 0: wave w owns kt=w; two u64 quads (s=0, s=1)
    {
        unsigned long long p0 = pk4bf(hreg[0][0], hreg[0][1], hreg[0][2], hreg[0][3]);
        unsigned long long p1 = pk4bf(hreg[1][0], hreg[1][1], hreg[1][2], hreg[1][3]);
        *(unsigned long long*)(&hfrag[(size_t)w * 512 + l * 8])     = p0;
        *(unsigned long long*)(&hfrag[(size_t)w * 512 + l * 8 + 4]) = p1;
    }
    __syncthreads();   // drains weight gload_lds + hfrag writes (once)

    #pragma unroll 1
    for (int it = 0; it < nsteps; ++it) {
        const int pr = it & 1;
        // 1) xg for THIS step -> registers (issued first, consumed after MFMAs)
        unsigned long long xgc[6];
        {
            const unsigned long long* xv = xg + ((size_t)it * 8 + bblk) * 3072 + (size_t)w * 384;
            #pragma unroll
            for (int mt = 0; mt < 6; ++mt) xgc[mt] = xv[mt * 64 + l];
        }
        // 2) h fragments (paired reads) + MFMAs — weights pinned in VGPRs
        const unsigned short* hb = hfrag + (size_t)pr * 4096;
        f32x4 acc[6];
        #pragma unroll
        for (int mt = 0; mt < 6; ++mt) acc[mt] = (f32x4){0.f, 0.f, 0.f, 0.f};
        #pragma unroll
        for (int kp = 0; kp < 3; ++kp) {
            bf16x8 h0 = *(const bf16x8*)(hb + (2 * kp) * 512 + l * 8);
            bf16x8 h1 = *(const bf16x8*)(hb + (2 * kp + 1) * 512 + l * 8);
            #pragma unroll
            for (int mt = 0; mt < 6; ++mt)
                acc[mt] = __builtin_amdgcn_mfma_f32_16x16x32_bf16(af[mt][2 * kp], h0, acc[mt], 0, 0, 0);
            #pragma unroll
            for (int mt = 0; mt < 6; ++mt)
                acc[mt] = __builtin_amdgcn_mfma_f32_16x16x32_bf16(af[mt][2 * kp + 1], h1, acc[mt], 0, 0, 0);
        }
        {
            bf16x8 h0 = *(const bf16x8*)(hb + 6 * 512 + l * 8);
            bf16x8 h1 = *(const bf16x8*)(hb + 7 * 512 + l * 8);
            #pragma unroll
            for (int mt = 0; mt < 6; ++mt)
                acc[mt] = __builtin_amdgcn_mfma_f32_16x16x32_bf16(af[mt][6], h0, acc[mt], 0, 0, 0);
            #pragma unroll
            for (int mt = 0; mt < 6; ++mt) {
                bf16x8 a = *(const bf16x8*)(wlds + (w * 6 + mt) * 512 + l * 8);
                acc[mt] = __builtin_amdgcn_mfma_f32_16x16x32_bf16(a, h1, acc[mt], 0, 0, 0);
            }
        }
        // 3) gates (all biases except bhh_n pre-folded into xg)
        unsigned long long pks[2];
        #pragma unroll
        for (int s = 0; s < 2; ++s) {
            float cx0[4], cx1[4], cx2[4];
            unpk4(xgc[0 + s], cx0);
            unpk4(xgc[2 + s], cx1);
            unpk4(xgc[4 + s], cx2);
            float hn4[4];
            #pragma unroll
            for (int q = 0; q < 4; ++q) {
                float r = sigm(cx0[q] + acc[0 + s][q]);
                float z = sigm(cx1[q] + acc[2 + s][q]);
                float n = tanh_f(cx2[q] + r * (acc[4 + s][q] + nbh[s][q]));
                float hn = n + z * (hreg[s][q] - n);
                hreg[s][q] = hn;
                hn4[q] = hn;
            }
            pks[s] = pk4bf(hn4[0], hn4[1], hn4[2], hn4[3]);
        }
        // 4) publish h: LDS (next parity) + hseq (LAYER 0)
        *(unsigned long long*)(&hfrag[(size_t)(pr ^ 1) * 4096 + w * 512 + l * 8])     = pks[0];
        *(unsigned long long*)(&hfrag[(size_t)(pr ^ 1) * 4096 + w * 512 + l * 8 + 4]) = pks[1];
        if (LAYER == 0) {
            unsigned long long* dv = (unsigned long long*)(hseq
                + ((size_t)bblk * T_ + (t0 + it)) * 4096 + (size_t)w * 512 + l * 8);
            dv[0] = pks[0];
            dv[1] = pks[1];
        }
        // 5) lgkm-only barrier: hfrag ordered; hseq stores drain at dispatch end
        asm volatile("s_waitcnt lgkmcnt(0)\n\ts_barrier" ::: "memory");
    }

    #pragma unroll
    for (int s = 0; s < 2; ++s)
        #pragma unroll
        for (int q = 0; q < 4; ++q) {
            int hid = w * 32 + s * 16 + g * 4 + q;
            hstate[(size_t)(bblk * 16 + b) * H_ + hid] = hreg[s][q];
        }
    if (LAYER == 1 && t0 + nsteps == T_) {
        #pragma unroll
        for (int s = 0; s < 2; ++s)
            #pragma unroll
            for (int q = 0; q < 4; ++q) {
                int hid = w * 32 + s * 16 + g * 4 + q;
                h2last[(size_t)(bblk * 16 + b) * H_ + hid] = hreg[s][q];
            }
    }
}

__global__ void fc_out(const float* __restrict__ h2, const float* __restrict__ W_fc,
                       const float* __restrict__ b_fc, float* __restrict__ out)
{
    __shared__ float hrow[256];
    const int bb = blockIdx.x, i = threadIdx.x;
    hrow[i] = h2[(size_t)bb * 256 + i];
    __syncthreads();
    float acc = b_fc[i];
    const float* wr = W_fc + (size_t)i * 256;
    #pragma unroll 8
    for (int k = 0; k < 256; ++k) acc += hrow[k] * wr[k];
    out[(size_t)bb * 256 + i] = sigm(acc);
}

extern "C" void kernel_launch(void* const* d_in, const int* in_sizes, int n_in,
                              void* d_out, int out_size, void* d_ws, size_t ws_size,
                              hipStream_t stream)
{
    const float* x    = (const float*)d_in[0];
    const float* W_ih = (const float*)d_in[1];
    const float* W_hh = (const float*)d_in[2];
    const float* b_ih = (const float*)d_in[3];
    const float* b_hh = (const float*)d_in[4];
    const float* W_fc = (const float*)d_in[5];
    const float* b_fc = (const float*)d_in[6];
    float* out = (float*)d_out;

    const size_t HSEQ_B = (size_t)8 * T_ * 4096 * 2;   // 64 MB
    const size_t PACK_B = 393216ull * 2;               // 768 KB each
    const size_t HST_B = 131072, H2_B = 131072;
    size_t fixed = HSEQ_B + 2 * PACK_B + HST_B + H2_B;
    // xg: per chunk-t, 8 bblk x 3072 u64 x 8 B = 196608 BYTES
    int chunk = 1024;
    while (chunk > 64 && fixed + (size_t)chunk * 196608 > ws_size) chunk >>= 1;

    char* ws = (char*)d_ws;
    unsigned long long* xg = (unsigned long long*)ws;  // chunk * 24576 u64
    size_t off = (size_t)chunk * 196608;
    unsigned short* hseq = (unsigned short*)(ws + off); off += HSEQ_B;
    unsigned short* pIH  = (unsigned short*)(ws + off); off += PACK_B;
    unsigned short* pHH  = (unsigned short*)(ws + off); off += PACK_B;
    float* hstate = (float*)(ws + off); off += HST_B;
    float* h2     = (float*)(ws + off);

    pack_weights<<<1536, 256, 0, stream>>>(W_ih, W_hh, pIH, pHH);

    const int RLDS = 49152 + 16384;   // wlds(kt7) + hfrag
    for (int layer = 0; layer < 2; ++layer) {
        const unsigned short* wIH = pIH + (size_t)layer * 196608;
        const unsigned short* wHH = pHH + (size_t)layer * 196608;
        const float* bi = b_ih + layer * G_;
        const float* bh = b_hh + layer * G_;
        for (int c = 0; c * chunk < T_; ++c) {
            int t0 = c * chunk;
            if (layer == 0) {
                gemm_xg<false><<<chunk, 512, 65536, stream>>>(x, wIH, bi, bh, xg, t0);
                recur<0><<<8, 512, RLDS, stream>>>(xg, wHH, bh, hseq, hstate, h2,
                                                   t0, chunk, c == 0);
            } else {
                gemm_xg<true><<<chunk, 512, 65536, stream>>>(hseq, wIH, bi, bh, xg, t0);
                recur<1><<<8, 512, RLDS, stream>>>(xg, wHH, bh, hseq, hstate, h2,
                                                   t0, chunk, c == 0);
            }
        }
    }
    fc_out<<<128, 256, 0, stream>>>(h2, W_fc, b_fc, out);
}

// Round 18
// 2278.242 us; speedup vs baseline: 2.0397x; 1.5035x over previous
//
#include <hip/hip_runtime.h>
#include <stdint.h>

#define T_ 1024
#define H_ 256
#define G_ 768

typedef __attribute__((ext_vector_type(8))) short bf16x8;
typedef __attribute__((ext_vector_type(4))) float f32x4;

__device__ __forceinline__ unsigned short f2bf(float f) {
    union { float f; uint32_t u; } v; v.f = f;
    uint32_t u = v.u;
    return (unsigned short)((u + 0x7FFFu + ((u >> 16) & 1u)) >> 16);
}

__device__ __forceinline__ float sigm(float x) {
    return __builtin_amdgcn_rcpf(1.f + __expf(-x));
}
__device__ __forceinline__ float tanh_f(float x) {
    return __builtin_amdgcn_rcpf(1.f + __expf(-2.f * x)) * 2.f - 1.f;
}

// asm cvt_pk: recur-only (scalar float inputs) — CONDEMNED on gemm MFMA accs (K5..K10)
__device__ __forceinline__ unsigned long long pk4bf(float a, float b, float c, float d) {
    uint32_t lo, hi;
    asm("v_cvt_pk_bf16_f32 %0, %1, %2" : "=v"(lo) : "v"(a), "v"(b));
    asm("v_cvt_pk_bf16_f32 %0, %1, %2" : "=v"(hi) : "v"(c), "v"(d));
    return ((unsigned long long)hi << 32) | (unsigned long long)lo;
}

__device__ __forceinline__ unsigned long long pk4bf_sw(float a, float b, float c, float d) {
    return (unsigned long long)f2bf(a)
         | ((unsigned long long)f2bf(b) << 16)
         | ((unsigned long long)f2bf(c) << 32)
         | ((unsigned long long)f2bf(d) << 48);
}

__device__ __forceinline__ void unpk4(unsigned long long v, float* o) {
    uint32_t lo = (uint32_t)v, hi = (uint32_t)(v >> 32);
    union { uint32_t u; float f; } a, b, c, d;
    a.u = lo << 16; b.u = lo & 0xffff0000u;
    c.u = hi << 16; d.u = hi & 0xffff0000u;
    o[0] = a.f; o[1] = b.f; o[2] = c.f; o[3] = d.f;
}

__device__ __forceinline__ void gload_lds16(const void* g, void* l) {
    __builtin_amdgcn_global_load_lds((const __attribute__((address_space(1))) void*)g,
                                     (__attribute__((address_space(3))) void*)l,
                                     16, 0, 0);
}

// Pack W (f32 [layer][768][256]) into per-wave MFMA A-fragment order (K2-proven):
// flat = ((((layer*8 + w)*6 + mt)*8 + kt)*64 + l)*8 + j
// gate = (mt>>1)*256 + w*32 + (mt&1)*16 + (l&15)
// k    = kt*32 + (j&3) + ((l>>4)<<2) + ((j>>2)<<4)
__global__ void pack_weights(const float* __restrict__ W_ih, const float* __restrict__ W_hh,
                             unsigned short* __restrict__ pIH, unsigned short* __restrict__ pHH)
{
    int idx = blockIdx.x * blockDim.x + threadIdx.x;
    if (idx >= 2 * 8 * 6 * 8 * 64 * 8) return;
    int pos = idx;
    int j = pos & 7;  pos >>= 3;
    int l = pos & 63; pos >>= 6;
    int kt = pos & 7; pos >>= 3;
    int mt = pos % 6; pos /= 6;
    int w = pos & 7;  pos >>= 3;
    int layer = pos;
    int gate = (mt >> 1) * 256 + w * 32 + (mt & 1) * 16 + (l & 15);
    int k = kt * 32 + (j & 3) + ((l >> 4) << 2) + ((j >> 2) << 4);
    size_t src = (size_t)layer * G_ * H_ + (size_t)gate * H_ + k;
    pIH[idx] = f2bf(W_ih[src]);
    pHH[idx] = f2bf(W_hh[src]);
}

// ---- gemm role body (K17-proven): bias fold + pk4bf_sw packed bf16 xg ----
template<bool SRC_BF16>
__device__ void gemm_body(char* smem, int gb, const void* __restrict__ srcp,
                          const unsigned short* __restrict__ wpack,
                          const float* __restrict__ bih, const float* __restrict__ bhh,
                          unsigned long long* __restrict__ xg, int t0)
{
    unsigned short* Bt = (unsigned short*)smem; // [8][4096] shorts = 64KB
    const int tid = threadIdx.x;
    const int w = tid >> 6, l = tid & 63;
    const int bblk = gb & 7;
    const int tg = gb >> 3;
    const int tbase = t0 + tg * 8;
    const int b = l & 15, g = l >> 4;

    bf16x8 af[6][8];
    {
        const bf16x8* wp = (const bf16x8*)wpack;
        #pragma unroll
        for (int mt = 0; mt < 6; ++mt)
            #pragma unroll
            for (int kt = 0; kt < 8; ++kt)
                af[mt][kt] = wp[((w * 6 + mt) * 8 + kt) * 64 + l];
    }

    float bsum[6][4];
    #pragma unroll
    for (int mt = 0; mt < 6; ++mt)
        #pragma unroll
        for (int q = 0; q < 4; ++q) {
            int gate = (mt >> 1) * 256 + w * 32 + (mt & 1) * 16 + g * 4 + q;
            bsum[mt][q] = (gate < 512) ? (bih[gate] + bhh[gate]) : bih[gate];
        }

    if (!SRC_BF16) {
        const float* x = (const float*)srcp;
        const int t_i = w;
        const int sb = (l >> 2) & 15;
        const int f0 = (l & 3) * 64;
        const float* row = x + ((size_t)(bblk * 16 + sb) * T_ + (tbase + t_i)) * H_ + f0;
        unsigned short* bt = Bt + t_i * 4096;
        #pragma unroll
        for (int i = 0; i < 64; i += 4) {
            f32x4 v = *(const f32x4*)(row + i);
            int f = f0 + i;
            bt[(f + 0) * 16 + sb] = f2bf(v[0]);
            bt[(f + 1) * 16 + sb] = f2bf(v[1]);
            bt[(f + 2) * 16 + sb] = f2bf(v[2]);
            bt[(f + 3) * 16 + sb] = f2bf(v[3]);
        }
    } else {
        const unsigned short* hs = (const unsigned short*)srcp;
        #pragma unroll
        for (int t_i = 0; t_i < 8; ++t_i) {
            const unsigned short* src = hs + ((size_t)bblk * T_ + (tbase + t_i)) * 4096
                                           + (size_t)(w * 64 + l) * 8;
            gload_lds16(src, Bt + t_i * 4096 + w * 512);
        }
    }
    __syncthreads();

    #pragma unroll 1
    for (int t_i = 0; t_i < 8; ++t_i) {
        const unsigned short* bt = Bt + t_i * 4096;
        f32x4 acc[6];
        #pragma unroll
        for (int mt = 0; mt < 6; ++mt) acc[mt] = (f32x4){0.f, 0.f, 0.f, 0.f};
        #pragma unroll
        for (int kt = 0; kt < 8; ++kt) {
            bf16x8 bf;
            if (SRC_BF16) {
                bf = *(const bf16x8*)(bt + kt * 512 + l * 8);
            } else {
                #pragma unroll
                for (int j = 0; j < 8; ++j) {
                    int k = kt * 32 + (j & 3) + (g << 2) + ((j >> 2) << 4);
                    bf[j] = (short)bt[k * 16 + b];
                }
            }
            #pragma unroll
            for (int mt = 0; mt < 6; ++mt)
                acc[mt] = __builtin_amdgcn_mfma_f32_16x16x32_bf16(af[mt][kt], bf, acc[mt], 0, 0, 0);
        }
        unsigned long long* dst = xg + ((size_t)(tg * 8 + t_i) * 8 + bblk) * 3072 + (size_t)w * 384;
        #pragma unroll
        for (int mt = 0; mt < 6; ++mt)
            dst[mt * 64 + l] = pk4bf_sw(acc[mt][0] + bsum[mt][0], acc[mt][1] + bsum[mt][1],
                                        acc[mt][2] + bsum[mt][2], acc[mt][3] + bsum[mt][3]);
    }
}

// ---- recur role body (EXACT K17 structure, runtime layer flag) ----
__device__ void recur_body(char* smem, int layer, int bblk,
                           const unsigned long long* __restrict__ xg,
                           const unsigned short* __restrict__ wpack,
                           const float* __restrict__ bhh,
                           unsigned short* __restrict__ hseq, float* __restrict__ hstate,
                           float* __restrict__ h2last, int t0, int nsteps, int first)
{
    unsigned short* wlds  = (unsigned short*)smem;             // [8][6][512] u16 = 48KB (kt7)
    unsigned short* hfrag = (unsigned short*)(smem + 49152);   // [2][8][512] u16 = 16KB
    const int tid = threadIdx.x;
    const int w = tid >> 6, l = tid & 63;
    const int g = l >> 4, b = l & 15;

    bf16x8 af[6][7];
    {
        const bf16x8* wp = (const bf16x8*)wpack;
        #pragma unroll
        for (int mt = 0; mt < 6; ++mt)
            #pragma unroll
            for (int kt = 0; kt < 7; ++kt) {
                af[mt][kt] = wp[((w * 6 + mt) * 8 + kt) * 64 + l];
                asm volatile("" : "+v"(af[mt][kt]));
            }
    }
    #pragma unroll
    for (int mt = 0; mt < 6; ++mt)
        gload_lds16(wpack + ((((size_t)(w * 6 + mt)) * 8 + 7) * 64 + l) * 8,
                    wlds + (w * 6 + mt) * 512);

    float nbh[2][4];
    #pragma unroll
    for (int s = 0; s < 2; ++s)
        #pragma unroll
        for (int q = 0; q < 4; ++q)
            nbh[s][q] = bhh[512 + w * 32 + s * 16 + g * 4 + q];

    float hreg[2][4];
    #pragma unroll
    for (int s = 0; s < 2; ++s)
        #pragma unroll
        for (int q = 0; q < 4; ++q) {
            int hid = w * 32 + s * 16 + g * 4 + q;
            hreg[s][q] = first ? 0.f : hstate[(size_t)(bblk * 16 + b) * H_ + hid];
        }
    {
        unsigned long long p0 = pk4bf(hreg[0][0], hreg[0][1], hreg[0][2], hreg[0][3]);
        unsigned long long p1 = pk4bf(hreg[1][0], hreg[1][1], hreg[1][2], hreg[1][3]);
        *(unsigned long long*)(&hfrag[(size_t)w * 512 + l * 8])     = p0;
        *(unsigned long long*)(&hfrag[(size_t)w * 512 + l * 8 + 4]) = p1;
    }
    __syncthreads();

    #pragma unroll 1
    for (int it = 0; it < nsteps; ++it) {
        const int pr = it & 1;
        unsigned long long xgc[6];
        {
            const unsigned long long* xv = xg + ((size_t)it * 8 + bblk) * 3072 + (size_t)w * 384;
            #pragma unroll
            for (int mt = 0; mt < 6; ++mt) xgc[mt] = xv[mt * 64 + l];
        }
        const unsigned short* hb = hfrag + (size_t)pr * 4096;
        f32x4 acc[6];
        #pragma unroll
        for (int mt = 0; mt < 6; ++mt) acc[mt] = (f32x4){0.f, 0.f, 0.f, 0.f};
        #pragma unroll
        for (int kp = 0; kp < 3; ++kp) {
            bf16x8 h0 = *(const bf16x8*)(hb + (2 * kp) * 512 + l * 8);
            bf16x8 h1 = *(const bf16x8*)(hb + (2 * kp + 1) * 512 + l * 8);
            #pragma unroll
            for (int mt = 0; mt < 6; ++mt)
                acc[mt] = __builtin_amdgcn_mfma_f32_16x16x32_bf16(af[mt][2 * kp], h0, acc[mt], 0, 0, 0);
            #pragma unroll
            for (int mt = 0; mt < 6; ++mt)
                acc[mt] = __builtin_amdgcn_mfma_f32_16x16x32_bf16(af[mt][2 * kp + 1], h1, acc[mt], 0, 0, 0);
        }
        {
            bf16x8 h0 = *(const bf16x8*)(hb + 6 * 512 + l * 8);
            bf16x8 h1 = *(const bf16x8*)(hb + 7 * 512 + l * 8);
            #pragma unroll
            for (int mt = 0; mt < 6; ++mt)
                acc[mt] = __builtin_amdgcn_mfma_f32_16x16x32_bf16(af[mt][6], h0, acc[mt], 0, 0, 0);
            #pragma unroll
            for (int mt = 0; mt < 6; ++mt) {
                bf16x8 a = *(const bf16x8*)(wlds + (w * 6 + mt) * 512 + l * 8);
                acc[mt] = __builtin_amdgcn_mfma_f32_16x16x32_bf16(a, h1, acc[mt], 0, 0, 0);
            }
        }
        unsigned long long pks[2];
        #pragma unroll
        for (int s = 0; s < 2; ++s) {
            float cx0[4], cx1[4], cx2[4];
            unpk4(xgc[0 + s], cx0);
            unpk4(xgc[2 + s], cx1);
            unpk4(xgc[4 + s], cx2);
            float hn4[4];
            #pragma unroll
            for (int q = 0; q < 4; ++q) {
                float r = sigm(cx0[q] + acc[0 + s][q]);
                float z = sigm(cx1[q] + acc[2 + s][q]);
                float n = tanh_f(cx2[q] + r * (acc[4 + s][q] + nbh[s][q]));
                float hn = n + z * (hreg[s][q] - n);
                hreg[s][q] = hn;
                hn4[q] = hn;
            }
            pks[s] = pk4bf(hn4[0], hn4[1], hn4[2], hn4[3]);
        }
        *(unsigned long long*)(&hfrag[(size_t)(pr ^ 1) * 4096 + w * 512 + l * 8])     = pks[0];
        *(unsigned long long*)(&hfrag[(size_t)(pr ^ 1) * 4096 + w * 512 + l * 8 + 4]) = pks[1];
        if (layer == 0) {
            unsigned long long* dv = (unsigned long long*)(hseq
                + ((size_t)bblk * T_ + (t0 + it)) * 4096 + (size_t)w * 512 + l * 8);
            dv[0] = pks[0];
            dv[1] = pks[1];
        }
        asm volatile("s_waitcnt lgkmcnt(0)\n\ts_barrier" ::: "memory");
    }

    #pragma unroll
    for (int s = 0; s < 2; ++s)
        #pragma unroll
        for (int q = 0; q < 4; ++q) {
            int hid = w * 32 + s * 16 + g * 4 + q;
            hstate[(size_t)(bblk * 16 + b) * H_ + hid] = hreg[s][q];
        }
    if (layer == 1 && t0 + nsteps == T_) {
        #pragma unroll
        for (int s = 0; s < 2; ++s)
            #pragma unroll
            for (int q = 0; q < 4; ++q) {
                int hid = w * 32 + s * 16 + g * 4 + q;
                h2last[(size_t)(bblk * 16 + b) * H_ + hid] = hreg[s][q];
            }
    }
}

// Fused pipeline launch c (stream order supplies all cross-role dependencies):
//  blocks [0,8):            L0 recur chunk c-1   (reads xg0 slot (c-1)&1)
//  blocks [8,16):           L1 recur chunk c-3   (reads xg1 slot (c-3)&1)
//  blocks [16,16+CH):       L1 gemm  chunk c-2   (reads hseq, writes xg1 slot (c-2)&1)
//  blocks [16+CH,16+2CH):   L0 gemm  chunk c     (reads x,    writes xg0 slot c&1)
__global__ __launch_bounds__(512, 2)
void fused(int c, int nc, int chunk,
           const float* __restrict__ x,
           const unsigned short* __restrict__ pIH0, const unsigned short* __restrict__ pIH1,
           const unsigned short* __restrict__ pHH0, const unsigned short* __restrict__ pHH1,
           const float* __restrict__ bih0, const float* __restrict__ bhh0,
           const float* __restrict__ bih1, const float* __restrict__ bhh1,
           unsigned long long* __restrict__ xg0, unsigned long long* __restrict__ xg1,
           unsigned short* __restrict__ hseq, float* __restrict__ hstate0,
           float* __restrict__ hstate1, float* __restrict__ h2last)
{
    extern __shared__ char smem[];
    const size_t slotU = (size_t)chunk * 24576;   // u64 per ring slot
    const int bid = blockIdx.x;
    if (bid < 8) {
        if (c >= 1 && c <= nc)
            recur_body(smem, 0, bid, xg0 + (size_t)((c - 1) & 1) * slotU, pHH0, bhh0,
                       hseq, hstate0, nullptr, (c - 1) * chunk, chunk, c == 1);
    } else if (bid < 16) {
        if (c >= 3 && c <= nc + 2)
            recur_body(smem, 1, bid - 8, xg1 + (size_t)((c - 3) & 1) * slotU, pHH1, bhh1,
                       nullptr, hstate1, h2last, (c - 3) * chunk, chunk, c == 3);
    } else if (bid < 16 + chunk) {
        if (c >= 2 && c <= nc + 1)
            gemm_body<true>(smem, bid - 16, hseq, pIH1, bih1, bhh1,
                            xg1 + (size_t)((c - 2) & 1) * slotU, (c - 2) * chunk);
    } else {
        if (c < nc)
            gemm_body<false>(smem, bid - 16 - chunk, x, pIH0, bih0, bhh0,
                             xg0 + (size_t)(c & 1) * slotU, c * chunk);
    }
}

__global__ void fc_out(const float* __restrict__ h2, const float* __restrict__ W_fc,
                       const float* __restrict__ b_fc, float* __restrict__ out)
{
    __shared__ float hrow[256];
    const int bb = blockIdx.x, i = threadIdx.x;
    hrow[i] = h2[(size_t)bb * 256 + i];
    __syncthreads();
    float acc = b_fc[i];
    const float* wr = W_fc + (size_t)i * 256;
    #pragma unroll 8
    for (int k = 0; k < 256; ++k) acc += hrow[k] * wr[k];
    out[(size_t)bb * 256 + i] = sigm(acc);
}

extern "C" void kernel_launch(void* const* d_in, const int* in_sizes, int n_in,
                              void* d_out, int out_size, void* d_ws, size_t ws_size,
                              hipStream_t stream)
{
    const float* x    = (const float*)d_in[0];
    const float* W_ih = (const float*)d_in[1];
    const float* W_hh = (const float*)d_in[2];
    const float* b_ih = (const float*)d_in[3];
    const float* b_hh = (const float*)d_in[4];
    const float* W_fc = (const float*)d_in[5];
    const float* b_fc = (const float*)d_in[6];
    float* out = (float*)d_out;

    const size_t HSEQ_B = (size_t)8 * T_ * 4096 * 2;   // 64 MB
    const size_t PACK_B = 393216ull * 2;               // 768 KB each
    const size_t HST_B = 131072, H2_B = 131072;
    size_t fixed = HSEQ_B + 2 * PACK_B + 2 * HST_B + H2_B;
    // rings: 2 layers x 2 slots x chunk*196608 B
    int chunk = 128;
    while (chunk > 16 && fixed + (size_t)chunk * 196608 * 4 > ws_size) chunk >>= 1;
    const size_t slotB = (size_t)chunk * 196608;

    char* ws = (char*)d_ws;
    unsigned long long* xg0 = (unsigned long long*)ws;
    unsigned long long* xg1 = (unsigned long long*)(ws + 2 * slotB);
    size_t off = 4 * slotB;
    unsigned short* hseq = (unsigned short*)(ws + off); off += HSEQ_B;
    unsigned short* pIH  = (unsigned short*)(ws + off); off += PACK_B;
    unsigned short* pHH  = (unsigned short*)(ws + off); off += PACK_B;
    float* hstate0 = (float*)(ws + off); off += HST_B;
    float* hstate1 = (float*)(ws + off); off += HST_B;
    float* h2      = (float*)(ws + off);

    pack_weights<<<1536, 256, 0, stream>>>(W_ih, W_hh, pIH, pHH);

    const unsigned short* pIH0 = pIH;
    const unsigned short* pIH1 = pIH + 196608;
    const unsigned short* pHH0 = pHH;
    const unsigned short* pHH1 = pHH + 196608;
    const float* bih0 = b_ih;
    const float* bih1 = b_ih + G_;
    const float* bhh0 = b_hh;
    const float* bhh1 = b_hh + G_;

    const int nc = T_ / chunk;
    const int grid = 16 + 2 * chunk;
    for (int c = 0; c <= nc + 2; ++c) {
        fused<<<grid, 512, 65536, stream>>>(c, nc, chunk, x,
                                            pIH0, pIH1, pHH0, pHH1,
                                            bih0, bhh0, bih1, bhh1,
                                            xg0, xg1, hseq, hstate0, hstate1, h2);
    }
    fc_out<<<128, 256, 0, stream>>>(h2, W_fc, b_fc, out);
}

// Round 19
// 2111.843 us; speedup vs baseline: 2.2004x; 1.0788x over previous
//
#include <hip/hip_runtime.h>
#include <hip/hip_cooperative_groups.h>
#include <stdint.h>

namespace cg = cooperative_groups;

#define T_ 1024
#define H_ 256
#define G_ 768

typedef __attribute__((ext_vector_type(8))) short bf16x8;
typedef __attribute__((ext_vector_type(4))) float f32x4;

__device__ __forceinline__ unsigned short f2bf(float f) {
    union { float f; uint32_t u; } v; v.f = f;
    uint32_t u = v.u;
    return (unsigned short)((u + 0x7FFFu + ((u >> 16) & 1u)) >> 16);
}

__device__ __forceinline__ float sigm(float x) {
    return __builtin_amdgcn_rcpf(1.f + __expf(-x));
}
__device__ __forceinline__ float tanh_f(float x) {
    return __builtin_amdgcn_rcpf(1.f + __expf(-2.f * x)) * 2.f - 1.f;
}

// asm cvt_pk: recur-only (scalar float inputs) — CONDEMNED on gemm MFMA accs (K5..K10)
__device__ __forceinline__ unsigned long long pk4bf(float a, float b, float c, float d) {
    uint32_t lo, hi;
    asm("v_cvt_pk_bf16_f32 %0, %1, %2" : "=v"(lo) : "v"(a), "v"(b));
    asm("v_cvt_pk_bf16_f32 %0, %1, %2" : "=v"(hi) : "v"(c), "v"(d));
    return ((unsigned long long)hi << 32) | (unsigned long long)lo;
}

__device__ __forceinline__ unsigned long long pk4bf_sw(float a, float b, float c, float d) {
    return (unsigned long long)f2bf(a)
         | ((unsigned long long)f2bf(b) << 16)
         | ((unsigned long long)f2bf(c) << 32)
         | ((unsigned long long)f2bf(d) << 48);
}

__device__ __forceinline__ void unpk4(unsigned long long v, float* o) {
    uint32_t lo = (uint32_t)v, hi = (uint32_t)(v >> 32);
    union { uint32_t u; float f; } a, b, c, d;
    a.u = lo << 16; b.u = lo & 0xffff0000u;
    c.u = hi << 16; d.u = hi & 0xffff0000u;
    o[0] = a.f; o[1] = b.f; o[2] = c.f; o[3] = d.f;
}

__device__ __forceinline__ void gload_lds16(const void* g, void* l) {
    __builtin_amdgcn_global_load_lds((const __attribute__((address_space(1))) void*)g,
                                     (__attribute__((address_space(3))) void*)l,
                                     16, 0, 0);
}

// Pack W (f32 [layer][768][256]) into per-wave MFMA A-fragment order (K2-proven):
// flat = ((((layer*8 + w)*6 + mt)*8 + kt)*64 + l)*8 + j
// gate = (mt>>1)*256 + w*32 + (mt&1)*16 + (l&15)
// k    = kt*32 + (j&3) + ((l>>4)<<2) + ((j>>2)<<4)
__global__ void pack_weights(const float* __restrict__ W_ih, const float* __restrict__ W_hh,
                             unsigned short* __restrict__ pIH, unsigned short* __restrict__ pHH)
{
    int idx = blockIdx.x * blockDim.x + threadIdx.x;
    if (idx >= 2 * 8 * 6 * 8 * 64 * 8) return;
    int pos = idx;
    int j = pos & 7;  pos >>= 3;
    int l = pos & 63; pos >>= 6;
    int kt = pos & 7; pos >>= 3;
    int mt = pos % 6; pos /= 6;
    int w = pos & 7;  pos >>= 3;
    int layer = pos;
    int gate = (mt >> 1) * 256 + w * 32 + (mt & 1) * 16 + (l & 15);
    int k = kt * 32 + (j & 3) + ((l >> 4) << 2) + ((j >> 2) << 4);
    size_t src = (size_t)layer * G_ * H_ + (size_t)gate * H_ + k;
    pIH[idx] = f2bf(W_ih[src]);
    pHH[idx] = f2bf(W_hh[src]);
}

// ---- persistent gemm role: weights loaded once, one chunk of xg per stage ----
template<bool SRC_BF16>
__device__ void gemm_persist(char* smem, cg::grid_group grid, int gb,
                             const void* __restrict__ srcp,
                             const unsigned short* __restrict__ wpack,
                             const float* __restrict__ bih, const float* __restrict__ bhh,
                             unsigned long long* __restrict__ xgring, size_t slotU,
                             int off, int nc, int chunk)
{
    unsigned short* Bt = (unsigned short*)smem; // [8][4096] shorts = 64KB
    const int tid = threadIdx.x;
    const int w = tid >> 6, l = tid & 63;
    const int bblk = gb & 7;
    const int tg = gb >> 3;
    const int b = l & 15, g = l >> 4;

    bf16x8 af[6][8];
    {
        const bf16x8* wp = (const bf16x8*)wpack;
        #pragma unroll
        for (int mt = 0; mt < 6; ++mt)
            #pragma unroll
            for (int kt = 0; kt < 8; ++kt)
                af[mt][kt] = wp[((w * 6 + mt) * 8 + kt) * 64 + l];
    }
    float bsum[6][4];
    #pragma unroll
    for (int mt = 0; mt < 6; ++mt)
        #pragma unroll
        for (int q = 0; q < 4; ++q) {
            int gate = (mt >> 1) * 256 + w * 32 + (mt & 1) * 16 + g * 4 + q;
            bsum[mt][q] = (gate < 512) ? (bih[gate] + bhh[gate]) : bih[gate];
        }

    const int nst = nc + 3;
    for (int s = 0; s < nst; ++s) {
        int cc = s - off;
        if (cc >= 0 && cc < nc) {
            unsigned long long* xg = xgring + (size_t)(cc & 1) * slotU;
            const int tbase = cc * chunk + tg * 8;

            if (!SRC_BF16) {
                const float* x = (const float*)srcp;
                const int t_i = w;
                const int sb = (l >> 2) & 15;
                const int f0 = (l & 3) * 64;
                const float* row = x + ((size_t)(bblk * 16 + sb) * T_ + (tbase + t_i)) * H_ + f0;
                unsigned short* bt = Bt + t_i * 4096;
                #pragma unroll
                for (int i = 0; i < 64; i += 4) {
                    f32x4 v = *(const f32x4*)(row + i);
                    int f = f0 + i;
                    bt[(f + 0) * 16 + sb] = f2bf(v[0]);
                    bt[(f + 1) * 16 + sb] = f2bf(v[1]);
                    bt[(f + 2) * 16 + sb] = f2bf(v[2]);
                    bt[(f + 3) * 16 + sb] = f2bf(v[3]);
                }
            } else {
                const unsigned short* hs = (const unsigned short*)srcp;
                #pragma unroll
                for (int t_i = 0; t_i < 8; ++t_i) {
                    const unsigned short* src = hs + ((size_t)bblk * T_ + (tbase + t_i)) * 4096
                                                   + (size_t)(w * 64 + l) * 8;
                    gload_lds16(src, Bt + t_i * 4096 + w * 512);
                }
            }
            __syncthreads();

            #pragma unroll 1
            for (int t_i = 0; t_i < 8; ++t_i) {
                const unsigned short* bt = Bt + t_i * 4096;
                f32x4 acc[6];
                #pragma unroll
                for (int mt = 0; mt < 6; ++mt) acc[mt] = (f32x4){0.f, 0.f, 0.f, 0.f};
                #pragma unroll
                for (int kt = 0; kt < 8; ++kt) {
                    bf16x8 bf;
                    if (SRC_BF16) {
                        bf = *(const bf16x8*)(bt + kt * 512 + l * 8);
                    } else {
                        #pragma unroll
                        for (int j = 0; j < 8; ++j) {
                            int k = kt * 32 + (j & 3) + (g << 2) + ((j >> 2) << 4);
                            bf[j] = (short)bt[k * 16 + b];
                        }
                    }
                    #pragma unroll
                    for (int mt = 0; mt < 6; ++mt)
                        acc[mt] = __builtin_amdgcn_mfma_f32_16x16x32_bf16(af[mt][kt], bf, acc[mt], 0, 0, 0);
                }
                unsigned long long* dst = xg + ((size_t)(tg * 8 + t_i) * 8 + bblk) * 3072 + (size_t)w * 384;
                #pragma unroll
                for (int mt = 0; mt < 6; ++mt)
                    dst[mt * 64 + l] = pk4bf_sw(acc[mt][0] + bsum[mt][0], acc[mt][1] + bsum[mt][1],
                                                acc[mt][2] + bsum[mt][2], acc[mt][3] + bsum[mt][3]);
            }
        }
        grid.sync();
    }
}

// ---- persistent recur role: weights + h state live for the whole run ----
__device__ void recur_persist(char* smem, cg::grid_group grid, int layer, int bblk,
                              const unsigned long long* __restrict__ xgring, size_t slotU,
                              const unsigned short* __restrict__ wpack,
                              const float* __restrict__ bhh,
                              unsigned short* __restrict__ hseq, float* __restrict__ h2last,
                              int off, int nc, int chunk)
{
    unsigned short* wlds  = (unsigned short*)smem;             // [8][6][512] u16 = 48KB (kt7)
    unsigned short* hfrag = (unsigned short*)(smem + 49152);   // [2][8][512] u16 = 16KB
    const int tid = threadIdx.x;
    const int w = tid >> 6, l = tid & 63;
    const int g = l >> 4, b = l & 15;

    bf16x8 af[6][7];
    {
        const bf16x8* wp = (const bf16x8*)wpack;
        #pragma unroll
        for (int mt = 0; mt < 6; ++mt)
            #pragma unroll
            for (int kt = 0; kt < 7; ++kt) {
                af[mt][kt] = wp[((w * 6 + mt) * 8 + kt) * 64 + l];
                asm volatile("" : "+v"(af[mt][kt]));
            }
    }
    #pragma unroll
    for (int mt = 0; mt < 6; ++mt)
        gload_lds16(wpack + ((((size_t)(w * 6 + mt)) * 8 + 7) * 64 + l) * 8,
                    wlds + (w * 6 + mt) * 512);

    float nbh[2][4];
    #pragma unroll
    for (int s = 0; s < 2; ++s)
        #pragma unroll
        for (int q = 0; q < 4; ++q)
            nbh[s][q] = bhh[512 + w * 32 + s * 16 + g * 4 + q];

    float hreg[2][4];
    #pragma unroll
    for (int s = 0; s < 2; ++s)
        #pragma unroll
        for (int q = 0; q < 4; ++q) hreg[s][q] = 0.f;
    // init hfrag parity 0 with zeros (h0 = 0)
    *(unsigned long long*)(&hfrag[(size_t)w * 512 + l * 8])     = 0ull;
    *(unsigned long long*)(&hfrag[(size_t)w * 512 + l * 8 + 4]) = 0ull;
    __syncthreads();   // drains weight gload_lds + hfrag writes (once)

    const int nst = nc + 3;
    for (int s = 0; s < nst; ++s) {
        int cc = s - off;
        if (cc >= 0 && cc < nc) {
            const unsigned long long* xg = xgring + (size_t)(cc & 1) * slotU;
            const int t0 = cc * chunk;
            #pragma unroll 1
            for (int it = 0; it < chunk; ++it) {
                const int pr = it & 1;   // chunk even -> parity continuous across stages
                unsigned long long xgc[6];
                {
                    const unsigned long long* xv = xg + ((size_t)it * 8 + bblk) * 3072 + (size_t)w * 384;
                    #pragma unroll
                    for (int mt = 0; mt < 6; ++mt) xgc[mt] = xv[mt * 64 + l];
                }
                const unsigned short* hb = hfrag + (size_t)pr * 4096;
                f32x4 acc[6];
                #pragma unroll
                for (int mt = 0; mt < 6; ++mt) acc[mt] = (f32x4){0.f, 0.f, 0.f, 0.f};
                #pragma unroll
                for (int kp = 0; kp < 3; ++kp) {
                    bf16x8 h0 = *(const bf16x8*)(hb + (2 * kp) * 512 + l * 8);
                    bf16x8 h1 = *(const bf16x8*)(hb + (2 * kp + 1) * 512 + l * 8);
                    #pragma unroll
                    for (int mt = 0; mt < 6; ++mt)
                        acc[mt] = __builtin_amdgcn_mfma_f32_16x16x32_bf16(af[mt][2 * kp], h0, acc[mt], 0, 0, 0);
                    #pragma unroll
                    for (int mt = 0; mt < 6; ++mt)
                        acc[mt] = __builtin_amdgcn_mfma_f32_16x16x32_bf16(af[mt][2 * kp + 1], h1, acc[mt], 0, 0, 0);
                }
                {
                    bf16x8 h0 = *(const bf16x8*)(hb + 6 * 512 + l * 8);
                    bf16x8 h1 = *(const bf16x8*)(hb + 7 * 512 + l * 8);
                    #pragma unroll
                    for (int mt = 0; mt < 6; ++mt)
                        acc[mt] = __builtin_amdgcn_mfma_f32_16x16x32_bf16(af[mt][6], h0, acc[mt], 0, 0, 0);
                    #pragma unroll
                    for (int mt = 0; mt < 6; ++mt) {
                        bf16x8 a = *(const bf16x8*)(wlds + (w * 6 + mt) * 512 + l * 8);
                        acc[mt] = __builtin_amdgcn_mfma_f32_16x16x32_bf16(a, h1, acc[mt], 0, 0, 0);
                    }
                }
                unsigned long long pks[2];
                #pragma unroll
                for (int ss = 0; ss < 2; ++ss) {
                    float cx0[4], cx1[4], cx2[4];
                    unpk4(xgc[0 + ss], cx0);
                    unpk4(xgc[2 + ss], cx1);
                    unpk4(xgc[4 + ss], cx2);
                    float hn4[4];
                    #pragma unroll
                    for (int q = 0; q < 4; ++q) {
                        float r = sigm(cx0[q] + acc[0 + ss][q]);
                        float z = sigm(cx1[q] + acc[2 + ss][q]);
                        float n = tanh_f(cx2[q] + r * (acc[4 + ss][q] + nbh[ss][q]));
                        float hn = n + z * (hreg[ss][q] - n);
                        hreg[ss][q] = hn;
                        hn4[q] = hn;
                    }
                    pks[ss] = pk4bf(hn4[0], hn4[1], hn4[2], hn4[3]);
                }
                *(unsigned long long*)(&hfrag[(size_t)(pr ^ 1) * 4096 + w * 512 + l * 8])     = pks[0];
                *(unsigned long long*)(&hfrag[(size_t)(pr ^ 1) * 4096 + w * 512 + l * 8 + 4]) = pks[1];
                if (layer == 0) {
                    unsigned long long* dv = (unsigned long long*)(hseq
                        + ((size_t)bblk * T_ + (t0 + it)) * 4096 + (size_t)w * 512 + l * 8);
                    dv[0] = pks[0];
                    dv[1] = pks[1];
                }
                asm volatile("s_waitcnt lgkmcnt(0)\n\ts_barrier" ::: "memory");
            }
        }
        grid.sync();
    }

    if (layer == 1) {
        #pragma unroll
        for (int s = 0; s < 2; ++s)
            #pragma unroll
            for (int q = 0; q < 4; ++q) {
                int hid = w * 32 + s * 16 + g * 4 + q;
                h2last[(size_t)(bblk * 16 + b) * H_ + hid] = hreg[s][q];
            }
    }
}

// One persistent cooperative launch; stream of stages with grid.sync() between.
// Stage s roles: L0g(chunk s), L0r(s-1), L1g(s-2), L1r(s-3).
__global__ __launch_bounds__(512, 2)
void pipeline(int nc, int chunk,
              const float* __restrict__ x,
              const unsigned short* __restrict__ pIH0, const unsigned short* __restrict__ pIH1,
              const unsigned short* __restrict__ pHH0, const unsigned short* __restrict__ pHH1,
              const float* __restrict__ bih0, const float* __restrict__ bhh0,
              const float* __restrict__ bih1, const float* __restrict__ bhh1,
              unsigned long long* __restrict__ xg0, unsigned long long* __restrict__ xg1,
              unsigned short* __restrict__ hseq, float* __restrict__ h2last)
{
    extern __shared__ char smem[];
    cg::grid_group grid = cg::this_grid();
    const size_t slotU = (size_t)chunk * 24576;
    const int bid = blockIdx.x;
    if (bid < 8) {
        recur_persist(smem, grid, 0, bid, xg0, slotU, pHH0, bhh0, hseq, nullptr, 1, nc, chunk);
    } else if (bid < 16) {
        recur_persist(smem, grid, 1, bid - 8, xg1, slotU, pHH1, bhh1, nullptr, h2last, 3, nc, chunk);
    } else if (bid < 16 + chunk) {
        gemm_persist<true>(smem, grid, bid - 16, hseq, pIH1, bih1, bhh1, xg1, slotU, 2, nc, chunk);
    } else {
        gemm_persist<false>(smem, grid, bid - 16 - chunk, x, pIH0, bih0, bhh0, xg0, slotU, 0, nc, chunk);
    }
}

__global__ void fc_out(const float* __restrict__ h2, const float* __restrict__ W_fc,
                       const float* __restrict__ b_fc, float* __restrict__ out)
{
    __shared__ float hrow[256];
    const int bb = blockIdx.x, i = threadIdx.x;
    hrow[i] = h2[(size_t)bb * 256 + i];
    __syncthreads();
    float acc = b_fc[i];
    const float* wr = W_fc + (size_t)i * 256;
    #pragma unroll 8
    for (int k = 0; k < 256; ++k) acc += hrow[k] * wr[k];
    out[(size_t)bb * 256 + i] = sigm(acc);
}

extern "C" void kernel_launch(void* const* d_in, const int* in_sizes, int n_in,
                              void* d_out, int out_size, void* d_ws, size_t ws_size,
                              hipStream_t stream)
{
    const float* x    = (const float*)d_in[0];
    const float* W_ih = (const float*)d_in[1];
    const float* W_hh = (const float*)d_in[2];
    const float* b_ih = (const float*)d_in[3];
    const float* b_hh = (const float*)d_in[4];
    const float* W_fc = (const float*)d_in[5];
    const float* b_fc = (const float*)d_in[6];
    float* out = (float*)d_out;

    const size_t HSEQ_B = (size_t)8 * T_ * 4096 * 2;   // 64 MB
    const size_t PACK_B = 393216ull * 2;               // 768 KB each
    const size_t H2_B = 131072;
    size_t fixed = HSEQ_B + 2 * PACK_B + H2_B;
    // rings: 2 layers x 2 slots x chunk*196608 B
    int chunk = 32;
    while (chunk > 8 && fixed + (size_t)chunk * 196608 * 4 > ws_size) chunk >>= 1;
    const size_t slotB = (size_t)chunk * 196608;

    char* ws = (char*)d_ws;
    unsigned long long* xg0 = (unsigned long long*)ws;
    unsigned long long* xg1 = (unsigned long long*)(ws + 2 * slotB);
    size_t off = 4 * slotB;
    unsigned short* hseq = (unsigned short*)(ws + off); off += HSEQ_B;
    unsigned short* pIH  = (unsigned short*)(ws + off); off += PACK_B;
    unsigned short* pHH  = (unsigned short*)(ws + off); off += PACK_B;
    float* h2      = (float*)(ws + off);

    pack_weights<<<1536, 256, 0, stream>>>(W_ih, W_hh, pIH, pHH);

    const unsigned short* pIH0 = pIH;
    const unsigned short* pIH1 = pIH + 196608;
    const unsigned short* pHH0 = pHH;
    const unsigned short* pHH1 = pHH + 196608;
    const float* bih0 = b_ih;
    const float* bih1 = b_ih + G_;
    const float* bhh0 = b_hh;
    const float* bhh1 = b_hh + G_;

    int nc = T_ / chunk;
    int grid = 16 + 2 * chunk;
    void* args[] = {
        (void*)&nc, (void*)&chunk, (void*)&x,
        (void*)&pIH0, (void*)&pIH1, (void*)&pHH0, (void*)&pHH1,
        (void*)&bih0, (void*)&bhh0, (void*)&bih1, (void*)&bhh1,
        (void*)&xg0, (void*)&xg1, (void*)&hseq, (void*)&h2
    };
    hipLaunchCooperativeKernel((const void*)pipeline, dim3(grid), dim3(512),
                               args, 65536, stream);

    fc_out<<<128, 256, 0, stream>>>(h2, W_fc, b_fc, out);
}

// Round 20
// 2093.139 us; speedup vs baseline: 2.2201x; 1.0089x over previous
//
#include <hip/hip_runtime.h>
#include <hip/hip_cooperative_groups.h>
#include <stdint.h>

namespace cg = cooperative_groups;

#define T_ 1024
#define H_ 256
#define G_ 768

typedef __attribute__((ext_vector_type(8))) short bf16x8;
typedef __attribute__((ext_vector_type(4))) float f32x4;

__device__ __forceinline__ unsigned short f2bf(float f) {
    union { float f; uint32_t u; } v; v.f = f;
    uint32_t u = v.u;
    return (unsigned short)((u + 0x7FFFu + ((u >> 16) & 1u)) >> 16);
}

__device__ __forceinline__ float sigm(float x) {
    return __builtin_amdgcn_rcpf(1.f + __expf(-x));
}
__device__ __forceinline__ float tanh_f(float x) {
    return __builtin_amdgcn_rcpf(1.f + __expf(-2.f * x)) * 2.f - 1.f;
}

// asm cvt_pk: recur-only (scalar float inputs) — CONDEMNED on gemm MFMA accs (K5..K10)
__device__ __forceinline__ unsigned long long pk4bf(float a, float b, float c, float d) {
    uint32_t lo, hi;
    asm("v_cvt_pk_bf16_f32 %0, %1, %2" : "=v"(lo) : "v"(a), "v"(b));
    asm("v_cvt_pk_bf16_f32 %0, %1, %2" : "=v"(hi) : "v"(c), "v"(d));
    return ((unsigned long long)hi << 32) | (unsigned long long)lo;
}

__device__ __forceinline__ unsigned long long pk4bf_sw(float a, float b, float c, float d) {
    return (unsigned long long)f2bf(a)
         | ((unsigned long long)f2bf(b) << 16)
         | ((unsigned long long)f2bf(c) << 32)
         | ((unsigned long long)f2bf(d) << 48);
}

__device__ __forceinline__ void unpk4(unsigned long long v, float* o) {
    uint32_t lo = (uint32_t)v, hi = (uint32_t)(v >> 32);
    union { uint32_t u; float f; } a, b, c, d;
    a.u = lo << 16; b.u = lo & 0xffff0000u;
    c.u = hi << 16; d.u = hi & 0xffff0000u;
    o[0] = a.f; o[1] = b.f; o[2] = c.f; o[3] = d.f;
}

__device__ __forceinline__ void gload_lds16(const void* g, void* l) {
    __builtin_amdgcn_global_load_lds((const __attribute__((address_space(1))) void*)g,
                                     (__attribute__((address_space(3))) void*)l,
                                     16, 0, 0);
}

// Pack W (f32 [layer][768][256]) into per-wave MFMA A-fragment order (K2-proven):
// flat = ((((layer*8 + w)*6 + mt)*8 + kt)*64 + l)*8 + j
// gate = (mt>>1)*256 + w*32 + (mt&1)*16 + (l&15)
// k    = kt*32 + (j&3) + ((l>>4)<<2) + ((j>>2)<<4)
__global__ void pack_weights(const float* __restrict__ W_ih, const float* __restrict__ W_hh,
                             unsigned short* __restrict__ pIH, unsigned short* __restrict__ pHH)
{
    int idx = blockIdx.x * blockDim.x + threadIdx.x;
    if (idx >= 2 * 8 * 6 * 8 * 64 * 8) return;
    int pos = idx;
    int j = pos & 7;  pos >>= 3;
    int l = pos & 63; pos >>= 6;
    int kt = pos & 7; pos >>= 3;
    int mt = pos % 6; pos /= 6;
    int w = pos & 7;  pos >>= 3;
    int layer = pos;
    int gate = (mt >> 1) * 256 + w * 32 + (mt & 1) * 16 + (l & 15);
    int k = kt * 32 + (j & 3) + ((l >> 4) << 2) + ((j >> 2) << 4);
    size_t src = (size_t)layer * G_ * H_ + (size_t)gate * H_ + k;
    pIH[idx] = f2bf(W_ih[src]);
    pHH[idx] = f2bf(W_hh[src]);
}

// ---- persistent gemm role: weights loaded once, one chunk of xg per stage ----
template<bool SRC_BF16>
__device__ void gemm_persist(char* smem, cg::grid_group grid, int gb,
                             const void* __restrict__ srcp,
                             const unsigned short* __restrict__ wpack,
                             const float* __restrict__ bih, const float* __restrict__ bhh,
                             unsigned long long* __restrict__ xgring, size_t slotU,
                             int off, int nc, int chunk)
{
    unsigned short* Bt = (unsigned short*)smem; // [8][4096] shorts = 64KB
    const int tid = threadIdx.x;
    const int w = tid >> 6, l = tid & 63;
    const int bblk = gb & 7;
    const int tg = gb >> 3;
    const int b = l & 15, g = l >> 4;

    bf16x8 af[6][8];
    {
        const bf16x8* wp = (const bf16x8*)wpack;
        #pragma unroll
        for (int mt = 0; mt < 6; ++mt)
            #pragma unroll
            for (int kt = 0; kt < 8; ++kt)
                af[mt][kt] = wp[((w * 6 + mt) * 8 + kt) * 64 + l];
    }
    float bsum[6][4];
    #pragma unroll
    for (int mt = 0; mt < 6; ++mt)
        #pragma unroll
        for (int q = 0; q < 4; ++q) {
            int gate = (mt >> 1) * 256 + w * 32 + (mt & 1) * 16 + g * 4 + q;
            bsum[mt][q] = (gate < 512) ? (bih[gate] + bhh[gate]) : bih[gate];
        }

    const int nst = nc + 3;
    for (int s = 0; s < nst; ++s) {
        int cc = s - off;
        if (cc >= 0 && cc < nc) {
            unsigned long long* xg = xgring + (size_t)(cc & 1) * slotU;
            const int tbase = cc * chunk + tg * 8;

            if (!SRC_BF16) {
                const float* x = (const float*)srcp;
                const int t_i = w;
                const int sb = (l >> 2) & 15;
                const int f0 = (l & 3) * 64;
                const float* row = x + ((size_t)(bblk * 16 + sb) * T_ + (tbase + t_i)) * H_ + f0;
                unsigned short* bt = Bt + t_i * 4096;
                #pragma unroll
                for (int i = 0; i < 64; i += 4) {
                    f32x4 v = *(const f32x4*)(row + i);
                    int f = f0 + i;
                    bt[(f + 0) * 16 + sb] = f2bf(v[0]);
                    bt[(f + 1) * 16 + sb] = f2bf(v[1]);
                    bt[(f + 2) * 16 + sb] = f2bf(v[2]);
                    bt[(f + 3) * 16 + sb] = f2bf(v[3]);
                }
            } else {
                const unsigned short* hs = (const unsigned short*)srcp;
                #pragma unroll
                for (int t_i = 0; t_i < 8; ++t_i) {
                    const unsigned short* src = hs + ((size_t)bblk * T_ + (tbase + t_i)) * 4096
                                                   + (size_t)(w * 64 + l) * 8;
                    gload_lds16(src, Bt + t_i * 4096 + w * 512);
                }
            }
            __syncthreads();

            #pragma unroll 1
            for (int t_i = 0; t_i < 8; ++t_i) {
                const unsigned short* bt = Bt + t_i * 4096;
                f32x4 acc[6];
                #pragma unroll
                for (int mt = 0; mt < 6; ++mt) acc[mt] = (f32x4){0.f, 0.f, 0.f, 0.f};
                #pragma unroll
                for (int kt = 0; kt < 8; ++kt) {
                    bf16x8 bf;
                    if (SRC_BF16) {
                        bf = *(const bf16x8*)(bt + kt * 512 + l * 8);
                    } else {
                        #pragma unroll
                        for (int j = 0; j < 8; ++j) {
                            int k = kt * 32 + (j & 3) + (g << 2) + ((j >> 2) << 4);
                            bf[j] = (short)bt[k * 16 + b];
                        }
                    }
                    #pragma unroll
                    for (int mt = 0; mt < 6; ++mt)
                        acc[mt] = __builtin_amdgcn_mfma_f32_16x16x32_bf16(af[mt][kt], bf, acc[mt], 0, 0, 0);
                }
                unsigned long long* dst = xg + ((size_t)(tg * 8 + t_i) * 8 + bblk) * 3072 + (size_t)w * 384;
                #pragma unroll
                for (int mt = 0; mt < 6; ++mt)
                    dst[mt * 64 + l] = pk4bf_sw(acc[mt][0] + bsum[mt][0], acc[mt][1] + bsum[mt][1],
                                                acc[mt][2] + bsum[mt][2], acc[mt][3] + bsum[mt][3]);
            }
        }
        grid.sync();
    }
}

// ---- persistent recur role: weights + h state live for the whole run.
// Per-stage chunk loop ping-pongs xg registers: next-step loads issued after the
// gates, riding across the lgkm-only barrier (~4000-cy window covers L3 latency).
__device__ void recur_persist(char* smem, cg::grid_group grid, int layer, int bblk,
                              const unsigned long long* __restrict__ xgring, size_t slotU,
                              const unsigned short* __restrict__ wpack,
                              const float* __restrict__ bhh,
                              unsigned short* __restrict__ hseq, float* __restrict__ h2last,
                              int off, int nc, int chunk)
{
    unsigned short* wlds  = (unsigned short*)smem;             // [8][6][512] u16 = 48KB (kt7)
    unsigned short* hfrag = (unsigned short*)(smem + 49152);   // [2][8][512] u16 = 16KB
    const int tid = threadIdx.x;
    const int w = tid >> 6, l = tid & 63;
    const int g = l >> 4, b = l & 15;

    bf16x8 af[6][7];
    {
        const bf16x8* wp = (const bf16x8*)wpack;
        #pragma unroll
        for (int mt = 0; mt < 6; ++mt)
            #pragma unroll
            for (int kt = 0; kt < 7; ++kt) {
                af[mt][kt] = wp[((w * 6 + mt) * 8 + kt) * 64 + l];
                asm volatile("" : "+v"(af[mt][kt]));
            }
    }
    #pragma unroll
    for (int mt = 0; mt < 6; ++mt)
        gload_lds16(wpack + ((((size_t)(w * 6 + mt)) * 8 + 7) * 64 + l) * 8,
                    wlds + (w * 6 + mt) * 512);

    float nbh[2][4];
    #pragma unroll
    for (int s = 0; s < 2; ++s)
        #pragma unroll
        for (int q = 0; q < 4; ++q)
            nbh[s][q] = bhh[512 + w * 32 + s * 16 + g * 4 + q];

    float hreg[2][4];
    #pragma unroll
    for (int s = 0; s < 2; ++s)
        #pragma unroll
        for (int q = 0; q < 4; ++q) hreg[s][q] = 0.f;
    *(unsigned long long*)(&hfrag[(size_t)w * 512 + l * 8])     = 0ull;
    *(unsigned long long*)(&hfrag[(size_t)w * 512 + l * 8 + 4]) = 0ull;
    __syncthreads();   // drains weight gload_lds + hfrag writes (once)

    const int nst = nc + 3;
    for (int s = 0; s < nst; ++s) {
        int cc = s - off;
        if (cc >= 0 && cc < nc) {
            const unsigned long long* xg = xgring + (size_t)(cc & 1) * slotU;
            const int t0 = cc * chunk;

            // prologue: xg for it=0
            unsigned long long xgA[6], xgB[6];
            {
                const unsigned long long* xv = xg + (size_t)bblk * 3072 + (size_t)w * 384;
                #pragma unroll
                for (int mt = 0; mt < 6; ++mt) xgA[mt] = xv[mt * 64 + l];
            }

            auto rstep = [&](int it, unsigned long long (&cur)[6], unsigned long long (&nxt)[6]) {
                const int pr = it & 1;   // chunk even -> parity continuous across stages
                const unsigned short* hb = hfrag + (size_t)pr * 4096;
                f32x4 acc[6];
                #pragma unroll
                for (int mt = 0; mt < 6; ++mt) acc[mt] = (f32x4){0.f, 0.f, 0.f, 0.f};
                #pragma unroll
                for (int kp = 0; kp < 3; ++kp) {
                    bf16x8 h0 = *(const bf16x8*)(hb + (2 * kp) * 512 + l * 8);
                    bf16x8 h1 = *(const bf16x8*)(hb + (2 * kp + 1) * 512 + l * 8);
                    #pragma unroll
                    for (int mt = 0; mt < 6; ++mt)
                        acc[mt] = __builtin_amdgcn_mfma_f32_16x16x32_bf16(af[mt][2 * kp], h0, acc[mt], 0, 0, 0);
                    #pragma unroll
                    for (int mt = 0; mt < 6; ++mt)
                        acc[mt] = __builtin_amdgcn_mfma_f32_16x16x32_bf16(af[mt][2 * kp + 1], h1, acc[mt], 0, 0, 0);
                }
                {
                    bf16x8 h0 = *(const bf16x8*)(hb + 6 * 512 + l * 8);
                    bf16x8 h1 = *(const bf16x8*)(hb + 7 * 512 + l * 8);
                    #pragma unroll
                    for (int mt = 0; mt < 6; ++mt)
                        acc[mt] = __builtin_amdgcn_mfma_f32_16x16x32_bf16(af[mt][6], h0, acc[mt], 0, 0, 0);
                    #pragma unroll
                    for (int mt = 0; mt < 6; ++mt) {
                        bf16x8 a = *(const bf16x8*)(wlds + (w * 6 + mt) * 512 + l * 8);
                        acc[mt] = __builtin_amdgcn_mfma_f32_16x16x32_bf16(a, h1, acc[mt], 0, 0, 0);
                    }
                }
                unsigned long long pks[2];
                #pragma unroll
                for (int ss = 0; ss < 2; ++ss) {
                    float cx0[4], cx1[4], cx2[4];
                    unpk4(cur[0 + ss], cx0);
                    unpk4(cur[2 + ss], cx1);
                    unpk4(cur[4 + ss], cx2);
                    float hn4[4];
                    #pragma unroll
                    for (int q = 0; q < 4; ++q) {
                        float r = sigm(cx0[q] + acc[0 + ss][q]);
                        float z = sigm(cx1[q] + acc[2 + ss][q]);
                        float n = tanh_f(cx2[q] + r * (acc[4 + ss][q] + nbh[ss][q]));
                        float hn = n + z * (hreg[ss][q] - n);
                        hreg[ss][q] = hn;
                        hn4[q] = hn;
                    }
                    pks[ss] = pk4bf(hn4[0], hn4[1], hn4[2], hn4[3]);
                }
                *(unsigned long long*)(&hfrag[(size_t)(pr ^ 1) * 4096 + w * 512 + l * 8])     = pks[0];
                *(unsigned long long*)(&hfrag[(size_t)(pr ^ 1) * 4096 + w * 512 + l * 8 + 4]) = pks[1];
                if (layer == 0) {
                    unsigned long long* dv = (unsigned long long*)(hseq
                        + ((size_t)bblk * T_ + (t0 + it)) * 4096 + (size_t)w * 512 + l * 8);
                    dv[0] = pks[0];
                    dv[1] = pks[1];
                }
                // prefetch next-step xg (within chunk); rides across the barrier
                {
                    int itn = (it + 1 < chunk) ? (it + 1) : it;
                    const unsigned long long* xv = xg + ((size_t)itn * 8 + bblk) * 3072 + (size_t)w * 384;
                    #pragma unroll
                    for (int mt = 0; mt < 6; ++mt) nxt[mt] = xv[mt * 64 + l];
                }
                asm volatile("s_waitcnt lgkmcnt(0)\n\ts_barrier" ::: "memory");
            };

            #pragma unroll 1
            for (int it2 = 0; it2 < chunk; it2 += 2) {
                rstep(it2,     xgA, xgB);
                rstep(it2 + 1, xgB, xgA);
            }
        }
        grid.sync();
    }

    if (layer == 1) {
        #pragma unroll
        for (int s = 0; s < 2; ++s)
            #pragma unroll
            for (int q = 0; q < 4; ++q) {
                int hid = w * 32 + s * 16 + g * 4 + q;
                h2last[(size_t)(bblk * 16 + b) * H_ + hid] = hreg[s][q];
            }
    }
}

// One persistent cooperative launch; stream of stages with grid.sync() between.
// Stage s roles: L0g(chunk s), L0r(s-1), L1g(s-2), L1r(s-3).
__global__ __launch_bounds__(512, 2)
void pipeline(int nc, int chunk,
              const float* __restrict__ x,
              const unsigned short* __restrict__ pIH0, const unsigned short* __restrict__ pIH1,
              const unsigned short* __restrict__ pHH0, const unsigned short* __restrict__ pHH1,
              const float* __restrict__ bih0, const float* __restrict__ bhh0,
              const float* __restrict__ bih1, const float* __restrict__ bhh1,
              unsigned long long* __restrict__ xg0, unsigned long long* __restrict__ xg1,
              unsigned short* __restrict__ hseq, float* __restrict__ h2last)
{
    extern __shared__ char smem[];
    cg::grid_group grid = cg::this_grid();
    const size_t slotU = (size_t)chunk * 24576;
    const int bid = blockIdx.x;
    if (bid < 8) {
        recur_persist(smem, grid, 0, bid, xg0, slotU, pHH0, bhh0, hseq, nullptr, 1, nc, chunk);
    } else if (bid < 16) {
        recur_persist(smem, grid, 1, bid - 8, xg1, slotU, pHH1, bhh1, nullptr, h2last, 3, nc, chunk);
    } else if (bid < 16 + chunk) {
        gemm_persist<true>(smem, grid, bid - 16, hseq, pIH1, bih1, bhh1, xg1, slotU, 2, nc, chunk);
    } else {
        gemm_persist<false>(smem, grid, bid - 16 - chunk, x, pIH0, bih0, bhh0, xg0, slotU, 0, nc, chunk);
    }
}

__global__ void fc_out(const float* __restrict__ h2, const float* __restrict__ W_fc,
                       const float* __restrict__ b_fc, float* __restrict__ out)
{
    __shared__ float hrow[256];
    const int bb = blockIdx.x, i = threadIdx.x;
    hrow[i] = h2[(size_t)bb * 256 + i];
    __syncthreads();
    float acc = b_fc[i];
    const float* wr = W_fc + (size_t)i * 256;
    #pragma unroll 8
    for (int k = 0; k < 256; ++k) acc += hrow[k] * wr[k];
    out[(size_t)bb * 256 + i] = sigm(acc);
}

extern "C" void kernel_launch(void* const* d_in, const int* in_sizes, int n_in,
                              void* d_out, int out_size, void* d_ws, size_t ws_size,
                              hipStream_t stream)
{
    const float* x    = (const float*)d_in[0];
    const float* W_ih = (const float*)d_in[1];
    const float* W_hh = (const float*)d_in[2];
    const float* b_ih = (const float*)d_in[3];
    const float* b_hh = (const float*)d_in[4];
    const float* W_fc = (const float*)d_in[5];
    const float* b_fc = (const float*)d_in[6];
    float* out = (float*)d_out;

    const size_t HSEQ_B = (size_t)8 * T_ * 4096 * 2;   // 64 MB
    const size_t PACK_B = 393216ull * 2;               // 768 KB each
    const size_t H2_B = 131072;
    size_t fixed = HSEQ_B + 2 * PACK_B + H2_B;
    // rings: 2 layers x 2 slots x chunk*196608 B
    int chunk = 32;
    while (chunk > 8 && fixed + (size_t)chunk * 196608 * 4 > ws_size) chunk >>= 1;
    const size_t slotB = (size_t)chunk * 196608;

    char* ws = (char*)d_ws;
    unsigned long long* xg0 = (unsigned long long*)ws;
    unsigned long long* xg1 = (unsigned long long*)(ws + 2 * slotB);
    size_t off = 4 * slotB;
    unsigned short* hseq = (unsigned short*)(ws + off); off += HSEQ_B;
    unsigned short* pIH  = (unsigned short*)(ws + off); off += PACK_B;
    unsigned short* pHH  = (unsigned short*)(ws + off); off += PACK_B;
    float* h2      = (float*)(ws + off);

    pack_weights<<<1536, 256, 0, stream>>>(W_ih, W_hh, pIH, pHH);

    const unsigned short* pIH0 = pIH;
    const unsigned short* pIH1 = pIH + 196608;
    const unsigned short* pHH0 = pHH;
    const unsigned short* pHH1 = pHH + 196608;
    const float* bih0 = b_ih;
    const float* bih1 = b_ih + G_;
    const float* bhh0 = b_hh;
    const float* bhh1 = b_hh + G_;

    int nc = T_ / chunk;
    int grid = 16 + 2 * chunk;
    void* args[] = {
        (void*)&nc, (void*)&chunk, (void*)&x,
        (void*)&pIH0, (void*)&pIH1, (void*)&pHH0, (void*)&pHH1,
        (void*)&bih0, (void*)&bhh0, (void*)&bih1, (void*)&bhh1,
        (void*)&xg0, (void*)&xg1, (void*)&hseq, (void*)&h2
    };
    hipLaunchCooperativeKernel((const void*)pipeline, dim3(grid), dim3(512),
                               args, 65536, stream);

    fc_out<<<128, 256, 0, stream>>>(h2, W_fc, b_fc, out);
}

// Round 21
// 1942.882 us; speedup vs baseline: 2.3918x; 1.0773x over previous
//
#include <hip/hip_runtime.h>
#include <stdint.h>

#define T_ 1024
#define H_ 256
#define G_ 768

typedef __attribute__((ext_vector_type(8))) short bf16x8;
typedef __attribute__((ext_vector_type(4))) float f32x4;

__device__ __forceinline__ unsigned short f2bf(float f) {
    union { float f; uint32_t u; } v; v.f = f;
    uint32_t u = v.u;
    return (unsigned short)((u + 0x7FFFu + ((u >> 16) & 1u)) >> 16);
}

__device__ __forceinline__ float sigm(float x) {
    return __builtin_amdgcn_rcpf(1.f + __expf(-x));
}
__device__ __forceinline__ float tanh_f(float x) {
    return __builtin_amdgcn_rcpf(1.f + __expf(-2.f * x)) * 2.f - 1.f;
}

// asm cvt_pk: recur-only (scalar float inputs) — CONDEMNED on gemm MFMA accs (K5..K10)
__device__ __forceinline__ unsigned long long pk4bf(float a, float b, float c, float d) {
    uint32_t lo, hi;
    asm("v_cvt_pk_bf16_f32 %0, %1, %2" : "=v"(lo) : "v"(a), "v"(b));
    asm("v_cvt_pk_bf16_f32 %0, %1, %2" : "=v"(hi) : "v"(c), "v"(d));
    return ((unsigned long long)hi << 32) | (unsigned long long)lo;
}

__device__ __forceinline__ unsigned long long pk4bf_sw(float a, float b, float c, float d) {
    return (unsigned long long)f2bf(a)
         | ((unsigned long long)f2bf(b) << 16)
         | ((unsigned long long)f2bf(c) << 32)
         | ((unsigned long long)f2bf(d) << 48);
}

__device__ __forceinline__ void unpk4(unsigned long long v, float* o) {
    uint32_t lo = (uint32_t)v, hi = (uint32_t)(v >> 32);
    union { uint32_t u; float f; } a, b, c, d;
    a.u = lo << 16; b.u = lo & 0xffff0000u;
    c.u = hi << 16; d.u = hi & 0xffff0000u;
    o[0] = a.f; o[1] = b.f; o[2] = c.f; o[3] = d.f;
}

__device__ __forceinline__ void gload_lds16(const void* g, void* l) {
    __builtin_amdgcn_global_load_lds((const __attribute__((address_space(1))) void*)g,
                                     (__attribute__((address_space(3))) void*)l,
                                     16, 0, 0);
}

// chunk-granularity dataflow sync: acquire-spin (invalidates caches -> fresh data
// reads after), release-add after __syncthreads() (all waves' stores drained).
__device__ __forceinline__ void spin_ge(int* p, int target) {
    while (__hip_atomic_load(p, __ATOMIC_ACQUIRE, __HIP_MEMORY_SCOPE_AGENT) < target)
        __builtin_amdgcn_s_sleep(16);
}
__device__ __forceinline__ void flag_add(int* p) {
    __hip_atomic_fetch_add(p, 1, __ATOMIC_RELEASE, __HIP_MEMORY_SCOPE_AGENT);
}

// Pack W (f32 [layer][768][256]) into per-wave MFMA A-fragment order (K2-proven):
// flat = ((((layer*8 + w)*6 + mt)*8 + kt)*64 + l)*8 + j
// gate = (mt>>1)*256 + w*32 + (mt&1)*16 + (l&15)
// k    = kt*32 + (j&3) + ((l>>4)<<2) + ((j>>2)<<4)
__global__ void pack_weights(const float* __restrict__ W_ih, const float* __restrict__ W_hh,
                             unsigned short* __restrict__ pIH, unsigned short* __restrict__ pHH)
{
    int idx = blockIdx.x * blockDim.x + threadIdx.x;
    if (idx >= 2 * 8 * 6 * 8 * 64 * 8) return;
    int pos = idx;
    int j = pos & 7;  pos >>= 3;
    int l = pos & 63; pos >>= 6;
    int kt = pos & 7; pos >>= 3;
    int mt = pos % 6; pos /= 6;
    int w = pos & 7;  pos >>= 3;
    int layer = pos;
    int gate = (mt >> 1) * 256 + w * 32 + (mt & 1) * 16 + (l & 15);
    int k = kt * 32 + (j & 3) + ((l >> 4) << 2) + ((j >> 2) << 4);
    size_t src = (size_t)layer * G_ * H_ + (size_t)gate * H_ + k;
    pIH[idx] = f2bf(W_ih[src]);
    pHH[idx] = f2bf(W_hh[src]);
}

// ---- persistent gemm role: weights loaded once; dataflow-flag driven ----
template<bool SRC_BF16>
__device__ void gemm_persist(char* smem, int gb,
                             const void* __restrict__ srcp,
                             const unsigned short* __restrict__ wpack,
                             const float* __restrict__ bih, const float* __restrict__ bhh,
                             unsigned long long* __restrict__ xgring, size_t slotU,
                             int nc, int chunk,
                             int* srcReady, int srcTarget,
                             int* ringFree, int ringTarget, int* doneCtr)
{
    unsigned short* Bt = (unsigned short*)smem; // [8][4096] shorts = 64KB
    const int tid = threadIdx.x;
    const int w = tid >> 6, l = tid & 63;
    const int bblk = gb & 7;
    const int tg = gb >> 3;
    const int b = l & 15, g = l >> 4;

    bf16x8 af[6][8];
    {
        const bf16x8* wp = (const bf16x8*)wpack;
        #pragma unroll
        for (int mt = 0; mt < 6; ++mt)
            #pragma unroll
            for (int kt = 0; kt < 8; ++kt)
                af[mt][kt] = wp[((w * 6 + mt) * 8 + kt) * 64 + l];
    }
    float bsum[6][4];
    #pragma unroll
    for (int mt = 0; mt < 6; ++mt)
        #pragma unroll
        for (int q = 0; q < 4; ++q) {
            int gate = (mt >> 1) * 256 + w * 32 + (mt & 1) * 16 + g * 4 + q;
            bsum[mt][q] = (gate < 512) ? (bih[gate] + bhh[gate]) : bih[gate];
        }

    for (int cc = 0; cc < nc; ++cc) {
        if (tid == 0) {
            if (srcReady) spin_ge(srcReady + cc * 16, srcTarget);
            if (cc >= 2) spin_ge(ringFree + (cc - 2) * 16, ringTarget);
        }
        __syncthreads();

        unsigned long long* xg = xgring + (size_t)(cc & 1) * slotU;
        const int tbase = cc * chunk + tg * 8;

        if (!SRC_BF16) {
            const float* x = (const float*)srcp;
            const int t_i = w;
            const int sb = (l >> 2) & 15;
            const int f0 = (l & 3) * 64;
            const float* row = x + ((size_t)(bblk * 16 + sb) * T_ + (tbase + t_i)) * H_ + f0;
            unsigned short* bt = Bt + t_i * 4096;
            #pragma unroll
            for (int i = 0; i < 64; i += 4) {
                f32x4 v = *(const f32x4*)(row + i);
                int f = f0 + i;
                bt[(f + 0) * 16 + sb] = f2bf(v[0]);
                bt[(f + 1) * 16 + sb] = f2bf(v[1]);
                bt[(f + 2) * 16 + sb] = f2bf(v[2]);
                bt[(f + 3) * 16 + sb] = f2bf(v[3]);
            }
        } else {
            const unsigned short* hs = (const unsigned short*)srcp;
            #pragma unroll
            for (int t_i = 0; t_i < 8; ++t_i) {
                const unsigned short* src = hs + ((size_t)bblk * T_ + (tbase + t_i)) * 4096
                                               + (size_t)(w * 64 + l) * 8;
                gload_lds16(src, Bt + t_i * 4096 + w * 512);
            }
        }
        __syncthreads();

        #pragma unroll 1
        for (int t_i = 0; t_i < 8; ++t_i) {
            const unsigned short* bt = Bt + t_i * 4096;
            f32x4 acc[6];
            #pragma unroll
            for (int mt = 0; mt < 6; ++mt) acc[mt] = (f32x4){0.f, 0.f, 0.f, 0.f};
            #pragma unroll
            for (int kt = 0; kt < 8; ++kt) {
                bf16x8 bf;
                if (SRC_BF16) {
                    bf = *(const bf16x8*)(bt + kt * 512 + l * 8);
                } else {
                    #pragma unroll
                    for (int j = 0; j < 8; ++j) {
                        int k = kt * 32 + (j & 3) + (g << 2) + ((j >> 2) << 4);
                        bf[j] = (short)bt[k * 16 + b];
                    }
                }
                #pragma unroll
                for (int mt = 0; mt < 6; ++mt)
                    acc[mt] = __builtin_amdgcn_mfma_f32_16x16x32_bf16(af[mt][kt], bf, acc[mt], 0, 0, 0);
            }
            unsigned long long* dst = xg + ((size_t)(tg * 8 + t_i) * 8 + bblk) * 3072 + (size_t)w * 384;
            #pragma unroll
            for (int mt = 0; mt < 6; ++mt)
                dst[mt * 64 + l] = pk4bf_sw(acc[mt][0] + bsum[mt][0], acc[mt][1] + bsum[mt][1],
                                            acc[mt][2] + bsum[mt][2], acc[mt][3] + bsum[mt][3]);
        }
        __syncthreads();   // drains all waves' xg stores
        if (tid == 0) flag_add(doneCtr + cc * 16);
    }
}

// ---- persistent recur role: weights + h state live for the whole run ----
__device__ void recur_persist(char* smem, int layer, int bblk,
                              const unsigned long long* __restrict__ xgring, size_t slotU,
                              const unsigned short* __restrict__ wpack,
                              const float* __restrict__ bhh,
                              unsigned short* __restrict__ hseq, float* __restrict__ h2last,
                              int nc, int chunk,
                              int* srcReady, int srcTarget, int* doneCtr)
{
    unsigned short* wlds  = (unsigned short*)smem;             // [8][6][512] u16 = 48KB (kt7)
    unsigned short* hfrag = (unsigned short*)(smem + 49152);   // [2][8][512] u16 = 16KB
    const int tid = threadIdx.x;
    const int w = tid >> 6, l = tid & 63;
    const int g = l >> 4, b = l & 15;

    bf16x8 af[6][7];
    {
        const bf16x8* wp = (const bf16x8*)wpack;
        #pragma unroll
        for (int mt = 0; mt < 6; ++mt)
            #pragma unroll
            for (int kt = 0; kt < 7; ++kt) {
                af[mt][kt] = wp[((w * 6 + mt) * 8 + kt) * 64 + l];
                asm volatile("" : "+v"(af[mt][kt]));
            }
    }
    #pragma unroll
    for (int mt = 0; mt < 6; ++mt)
        gload_lds16(wpack + ((((size_t)(w * 6 + mt)) * 8 + 7) * 64 + l) * 8,
                    wlds + (w * 6 + mt) * 512);

    float nbh[2][4];
    #pragma unroll
    for (int s = 0; s < 2; ++s)
        #pragma unroll
        for (int q = 0; q < 4; ++q)
            nbh[s][q] = bhh[512 + w * 32 + s * 16 + g * 4 + q];

    float hreg[2][4];
    #pragma unroll
    for (int s = 0; s < 2; ++s)
        #pragma unroll
        for (int q = 0; q < 4; ++q) hreg[s][q] = 0.f;
    *(unsigned long long*)(&hfrag[(size_t)w * 512 + l * 8])     = 0ull;
    *(unsigned long long*)(&hfrag[(size_t)w * 512 + l * 8 + 4]) = 0ull;
    __syncthreads();   // drains weight gload_lds + hfrag writes (once)

    for (int cc = 0; cc < nc; ++cc) {
        if (tid == 0) spin_ge(srcReady + cc * 16, srcTarget);
        __syncthreads();

        const unsigned long long* xg = xgring + (size_t)(cc & 1) * slotU;
        const int t0 = cc * chunk;

        unsigned long long xgA[6], xgB[6];
        {
            const unsigned long long* xv = xg + (size_t)bblk * 3072 + (size_t)w * 384;
            #pragma unroll
            for (int mt = 0; mt < 6; ++mt) xgA[mt] = xv[mt * 64 + l];
        }

        auto rstep = [&](int it, unsigned long long (&cur)[6], unsigned long long (&nxt)[6]) {
            const int pr = it & 1;   // chunk even -> parity continuous across chunks
            const unsigned short* hb = hfrag + (size_t)pr * 4096;
            f32x4 acc[6];
            #pragma unroll
            for (int mt = 0; mt < 6; ++mt) acc[mt] = (f32x4){0.f, 0.f, 0.f, 0.f};
            #pragma unroll
            for (int kp = 0; kp < 3; ++kp) {
                bf16x8 h0 = *(const bf16x8*)(hb + (2 * kp) * 512 + l * 8);
                bf16x8 h1 = *(const bf16x8*)(hb + (2 * kp + 1) * 512 + l * 8);
                #pragma unroll
                for (int mt = 0; mt < 6; ++mt)
                    acc[mt] = __builtin_amdgcn_mfma_f32_16x16x32_bf16(af[mt][2 * kp], h0, acc[mt], 0, 0, 0);
                #pragma unroll
                for (int mt = 0; mt < 6; ++mt)
                    acc[mt] = __builtin_amdgcn_mfma_f32_16x16x32_bf16(af[mt][2 * kp + 1], h1, acc[mt], 0, 0, 0);
            }
            {
                bf16x8 h0 = *(const bf16x8*)(hb + 6 * 512 + l * 8);
                bf16x8 h1 = *(const bf16x8*)(hb + 7 * 512 + l * 8);
                #pragma unroll
                for (int mt = 0; mt < 6; ++mt)
                    acc[mt] = __builtin_amdgcn_mfma_f32_16x16x32_bf16(af[mt][6], h0, acc[mt], 0, 0, 0);
                #pragma unroll
                for (int mt = 0; mt < 6; ++mt) {
                    bf16x8 a = *(const bf16x8*)(wlds + (w * 6 + mt) * 512 + l * 8);
                    acc[mt] = __builtin_amdgcn_mfma_f32_16x16x32_bf16(a, h1, acc[mt], 0, 0, 0);
                }
            }
            unsigned long long pks[2];
            #pragma unroll
            for (int ss = 0; ss < 2; ++ss) {
                float cx0[4], cx1[4], cx2[4];
                unpk4(cur[0 + ss], cx0);
                unpk4(cur[2 + ss], cx1);
                unpk4(cur[4 + ss], cx2);
                float hn4[4];
                #pragma unroll
                for (int q = 0; q < 4; ++q) {
                    float r = sigm(cx0[q] + acc[0 + ss][q]);
                    float z = sigm(cx1[q] + acc[2 + ss][q]);
                    float n = tanh_f(cx2[q] + r * (acc[4 + ss][q] + nbh[ss][q]));
                    float hn = n + z * (hreg[ss][q] - n);
                    hreg[ss][q] = hn;
                    hn4[q] = hn;
                }
                pks[ss] = pk4bf(hn4[0], hn4[1], hn4[2], hn4[3]);
            }
            *(unsigned long long*)(&hfrag[(size_t)(pr ^ 1) * 4096 + w * 512 + l * 8])     = pks[0];
            *(unsigned long long*)(&hfrag[(size_t)(pr ^ 1) * 4096 + w * 512 + l * 8 + 4]) = pks[1];
            if (layer == 0) {
                unsigned long long* dv = (unsigned long long*)(hseq
                    + ((size_t)bblk * T_ + (t0 + it)) * 4096 + (size_t)w * 512 + l * 8);
                dv[0] = pks[0];
                dv[1] = pks[1];
            }
            // prefetch next-step xg (within chunk); rides across the barrier
            {
                int itn = (it + 1 < chunk) ? (it + 1) : it;
                const unsigned long long* xv = xg + ((size_t)itn * 8 + bblk) * 3072 + (size_t)w * 384;
                #pragma unroll
                for (int mt = 0; mt < 6; ++mt) nxt[mt] = xv[mt * 64 + l];
            }
            asm volatile("s_waitcnt lgkmcnt(0)\n\ts_barrier" ::: "memory");
        };

        #pragma unroll 1
        for (int it2 = 0; it2 < chunk; it2 += 2) {
            rstep(it2,     xgA, xgB);
            rstep(it2 + 1, xgB, xgA);
        }

        __syncthreads();   // drains hseq stores (vmcnt) before signaling
        if (tid == 0) flag_add(doneCtr + cc * 16);
    }

    if (layer == 1) {
        #pragma unroll
        for (int s = 0; s < 2; ++s)
            #pragma unroll
            for (int q = 0; q < 4; ++q) {
                int hid = w * 32 + s * 16 + g * 4 + q;
                h2last[(size_t)(bblk * 16 + b) * H_ + hid] = hreg[s][q];
            }
    }
}

// One persistent launch (cooperative for co-residency; NO grid.sync — dataflow
// flags at chunk granularity drive the pipeline).
// flags layout (int, stride-16 per chunk): [0]=g0done [2048]=rdone0 [4096]=g1done [6144]=rdone1
__global__ __launch_bounds__(512, 2)
void pipeline(int nc, int chunk,
              const float* __restrict__ x,
              const unsigned short* __restrict__ pIH0, const unsigned short* __restrict__ pIH1,
              const unsigned short* __restrict__ pHH0, const unsigned short* __restrict__ pHH1,
              const float* __restrict__ bih0, const float* __restrict__ bhh0,
              const float* __restrict__ bih1, const float* __restrict__ bhh1,
              unsigned long long* __restrict__ xg0, unsigned long long* __restrict__ xg1,
              unsigned short* __restrict__ hseq, float* __restrict__ h2last,
              int* __restrict__ flags)
{
    extern __shared__ char smem[];
    const size_t slotU = (size_t)chunk * 24576;
    int* g0done = flags;
    int* rdone0 = flags + 2048;
    int* g1done = flags + 4096;
    int* rdone1 = flags + 6144;
    const int bid = blockIdx.x;
    if (bid < 8) {
        recur_persist(smem, 0, bid, xg0, slotU, pHH0, bhh0, hseq, nullptr,
                      nc, chunk, g0done, chunk, rdone0);
    } else if (bid < 16) {
        recur_persist(smem, 1, bid - 8, xg1, slotU, pHH1, bhh1, nullptr, h2last,
                      nc, chunk, g1done, chunk, rdone1);
    } else if (bid < 16 + chunk) {
        gemm_persist<true>(smem, bid - 16, hseq, pIH1, bih1, bhh1, xg1, slotU,
                           nc, chunk, rdone0, 8, rdone1, 8, g1done);
    } else {
        gemm_persist<false>(smem, bid - 16 - chunk, x, pIH0, bih0, bhh0, xg0, slotU,
                            nc, chunk, nullptr, 0, rdone0, 8, g0done);
    }
}

__global__ void fc_out(const float* __restrict__ h2, const float* __restrict__ W_fc,
                       const float* __restrict__ b_fc, float* __restrict__ out)
{
    __shared__ float hrow[256];
    const int bb = blockIdx.x, i = threadIdx.x;
    hrow[i] = h2[(size_t)bb * 256 + i];
    __syncthreads();
    float acc = b_fc[i];
    const float* wr = W_fc + (size_t)i * 256;
    #pragma unroll 8
    for (int k = 0; k < 256; ++k) acc += hrow[k] * wr[k];
    out[(size_t)bb * 256 + i] = sigm(acc);
}

extern "C" void kernel_launch(void* const* d_in, const int* in_sizes, int n_in,
                              void* d_out, int out_size, void* d_ws, size_t ws_size,
                              hipStream_t stream)
{
    const float* x    = (const float*)d_in[0];
    const float* W_ih = (const float*)d_in[1];
    const float* W_hh = (const float*)d_in[2];
    const float* b_ih = (const float*)d_in[3];
    const float* b_hh = (const float*)d_in[4];
    const float* W_fc = (const float*)d_in[5];
    const float* b_fc = (const float*)d_in[6];
    float* out = (float*)d_out;

    const size_t HSEQ_B = (size_t)8 * T_ * 4096 * 2;   // 64 MB
    const size_t PACK_B = 393216ull * 2;               // 768 KB each
    const size_t H2_B = 131072;
    const size_t FLG_B = 32768;                        // 4 x 2048 ints
    size_t fixed = HSEQ_B + 2 * PACK_B + H2_B + FLG_B;
    int chunk = 32;
    while (chunk > 8 && fixed + (size_t)chunk * 196608 * 4 > ws_size) chunk >>= 1;
    const size_t slotB = (size_t)chunk * 196608;

    char* ws = (char*)d_ws;
    unsigned long long* xg0 = (unsigned long long*)ws;
    unsigned long long* xg1 = (unsigned long long*)(ws + 2 * slotB);
    size_t off = 4 * slotB;
    unsigned short* hseq = (unsigned short*)(ws + off); off += HSEQ_B;
    unsigned short* pIH  = (unsigned short*)(ws + off); off += PACK_B;
    unsigned short* pHH  = (unsigned short*)(ws + off); off += PACK_B;
    float* h2     = (float*)(ws + off); off += H2_B;
    int* flags    = (int*)(ws + off);

    hipMemsetAsync(flags, 0, FLG_B, stream);
    pack_weights<<<1536, 256, 0, stream>>>(W_ih, W_hh, pIH, pHH);

    const unsigned short* pIH0 = pIH;
    const unsigned short* pIH1 = pIH + 196608;
    const unsigned short* pHH0 = pHH;
    const unsigned short* pHH1 = pHH + 196608;
    const float* bih0 = b_ih;
    const float* bih1 = b_ih + G_;
    const float* bhh0 = b_hh;
    const float* bhh1 = b_hh + G_;

    int nc = T_ / chunk;
    int grid = 16 + 2 * chunk;
    void* args[] = {
        (void*)&nc, (void*)&chunk, (void*)&x,
        (void*)&pIH0, (void*)&pIH1, (void*)&pHH0, (void*)&pHH1,
        (void*)&bih0, (void*)&bhh0, (void*)&bih1, (void*)&bhh1,
        (void*)&xg0, (void*)&xg1, (void*)&hseq, (void*)&h2, (void*)&flags
    };
    hipLaunchCooperativeKernel((const void*)pipeline, dim3(grid), dim3(512),
                               args, 65536, stream);

    fc_out<<<128, 256, 0, stream>>>(h2, W_fc, b_fc, out);
}

// Round 22
// 1823.741 us; speedup vs baseline: 2.5480x; 1.0653x over previous
//
#include <hip/hip_runtime.h>
#include <stdint.h>

#define T_ 1024
#define H_ 256
#define G_ 768

typedef __attribute__((ext_vector_type(8))) short bf16x8;
typedef __attribute__((ext_vector_type(4))) float f32x4;

__device__ __forceinline__ unsigned short f2bf(float f) {
    union { float f; uint32_t u; } v; v.f = f;
    uint32_t u = v.u;
    return (unsigned short)((u + 0x7FFFu + ((u >> 16) & 1u)) >> 16);
}

__device__ __forceinline__ float sigm(float x) {
    return __builtin_amdgcn_rcpf(1.f + __expf(-x));
}
__device__ __forceinline__ float tanh_f(float x) {
    return __builtin_amdgcn_rcpf(1.f + __expf(-2.f * x)) * 2.f - 1.f;
}

// asm cvt_pk: recur-only (scalar float inputs) — CONDEMNED on gemm MFMA accs (K5..K10)
__device__ __forceinline__ unsigned long long pk4bf(float a, float b, float c, float d) {
    uint32_t lo, hi;
    asm("v_cvt_pk_bf16_f32 %0, %1, %2" : "=v"(lo) : "v"(a), "v"(b));
    asm("v_cvt_pk_bf16_f32 %0, %1, %2" : "=v"(hi) : "v"(c), "v"(d));
    return ((unsigned long long)hi << 32) | (unsigned long long)lo;
}

__device__ __forceinline__ unsigned long long pk4bf_sw(float a, float b, float c, float d) {
    return (unsigned long long)f2bf(a)
         | ((unsigned long long)f2bf(b) << 16)
         | ((unsigned long long)f2bf(c) << 32)
         | ((unsigned long long)f2bf(d) << 48);
}

__device__ __forceinline__ void unpk4(unsigned long long v, float* o) {
    uint32_t lo = (uint32_t)v, hi = (uint32_t)(v >> 32);
    union { uint32_t u; float f; } a, b, c, d;
    a.u = lo << 16; b.u = lo & 0xffff0000u;
    c.u = hi << 16; d.u = hi & 0xffff0000u;
    o[0] = a.f; o[1] = b.f; o[2] = c.f; o[3] = d.f;
}

__device__ __forceinline__ void gload_lds16(const void* g, void* l) {
    __builtin_amdgcn_global_load_lds((const __attribute__((address_space(1))) void*)g,
                                     (__attribute__((address_space(3))) void*)l,
                                     16, 0, 0);
}

// chunk-granularity dataflow sync (K21-proven): acquire-spin / release-add
__device__ __forceinline__ void spin_ge(int* p, int target) {
    while (__hip_atomic_load(p, __ATOMIC_ACQUIRE, __HIP_MEMORY_SCOPE_AGENT) < target)
        __builtin_amdgcn_s_sleep(16);
}
__device__ __forceinline__ void flag_add(int* p) {
    __hip_atomic_fetch_add(p, 1, __ATOMIC_RELEASE, __HIP_MEMORY_SCOPE_AGENT);
}

// Pack W (f32 [layer][768][256]) into per-wave MFMA A-fragment order (K2-proven):
// flat = ((((layer*8 + w)*6 + mt)*8 + kt)*64 + l)*8 + j
// gate = (mt>>1)*256 + w*32 + (mt&1)*16 + (l&15)
// k    = kt*32 + (j&3) + ((l>>4)<<2) + ((j>>2)<<4)
__global__ void pack_weights(const float* __restrict__ W_ih, const float* __restrict__ W_hh,
                             unsigned short* __restrict__ pIH, unsigned short* __restrict__ pHH)
{
    int idx = blockIdx.x * blockDim.x + threadIdx.x;
    if (idx >= 2 * 8 * 6 * 8 * 64 * 8) return;
    int pos = idx;
    int j = pos & 7;  pos >>= 3;
    int l = pos & 63; pos >>= 6;
    int kt = pos & 7; pos >>= 3;
    int mt = pos % 6; pos /= 6;
    int w = pos & 7;  pos >>= 3;
    int layer = pos;
    int gate = (mt >> 1) * 256 + w * 32 + (mt & 1) * 16 + (l & 15);
    int k = kt * 32 + (j & 3) + ((l >> 4) << 2) + ((j >> 2) << 4);
    size_t src = (size_t)layer * G_ * H_ + (size_t)gate * H_ + k;
    pIH[idx] = f2bf(W_ih[src]);
    pHH[idx] = f2bf(W_hh[src]);
}

// ---- persistent gemm role: weights loaded once; dataflow-flag driven ----
template<bool SRC_BF16>
__device__ void gemm_persist(char* smem, int gb,
                             const void* __restrict__ srcp,
                             const unsigned short* __restrict__ wpack,
                             const float* __restrict__ bih, const float* __restrict__ bhh,
                             unsigned long long* __restrict__ xgring, size_t slotU,
                             int nc, int chunk,
                             int* srcReady, int srcTarget,
                             int* ringFree, int ringTarget, int* doneCtr)
{
    unsigned short* Bt = (unsigned short*)smem; // [8][4096] shorts = 64KB
    const int tid = threadIdx.x;
    const int w = tid >> 6, l = tid & 63;
    const int bblk = gb & 7;
    const int tg = gb >> 3;
    const int b = l & 15, g = l >> 4;

    bf16x8 af[6][8];
    {
        const bf16x8* wp = (const bf16x8*)wpack;
        #pragma unroll
        for (int mt = 0; mt < 6; ++mt)
            #pragma unroll
            for (int kt = 0; kt < 8; ++kt)
                af[mt][kt] = wp[((w * 6 + mt) * 8 + kt) * 64 + l];
    }
    float bsum[6][4];
    #pragma unroll
    for (int mt = 0; mt < 6; ++mt)
        #pragma unroll
        for (int q = 0; q < 4; ++q) {
            int gate = (mt >> 1) * 256 + w * 32 + (mt & 1) * 16 + g * 4 + q;
            bsum[mt][q] = (gate < 512) ? (bih[gate] + bhh[gate]) : bih[gate];
        }

    for (int cc = 0; cc < nc; ++cc) {
        if (tid == 0) {
            if (srcReady) spin_ge(srcReady + cc * 16, srcTarget);
            if (cc >= 2) spin_ge(ringFree + (cc - 2) * 16, ringTarget);
        }
        __syncthreads();

        unsigned long long* xg = xgring + (size_t)(cc & 1) * slotU;
        const int tbase = cc * chunk + tg * 8;

        if (!SRC_BF16) {
            const float* x = (const float*)srcp;
            const int t_i = w;
            const int sb = (l >> 2) & 15;
            const int f0 = (l & 3) * 64;
            const float* row = x + ((size_t)(bblk * 16 + sb) * T_ + (tbase + t_i)) * H_ + f0;
            unsigned short* bt = Bt + t_i * 4096;
            #pragma unroll
            for (int i = 0; i < 64; i += 4) {
                f32x4 v = *(const f32x4*)(row + i);
                int f = f0 + i;
                bt[(f + 0) * 16 + sb] = f2bf(v[0]);
                bt[(f + 1) * 16 + sb] = f2bf(v[1]);
                bt[(f + 2) * 16 + sb] = f2bf(v[2]);
                bt[(f + 3) * 16 + sb] = f2bf(v[3]);
            }
        } else {
            const unsigned short* hs = (const unsigned short*)srcp;
            #pragma unroll
            for (int t_i = 0; t_i < 8; ++t_i) {
                const unsigned short* src = hs + ((size_t)bblk * T_ + (tbase + t_i)) * 4096
                                               + (size_t)(w * 64 + l) * 8;
                gload_lds16(src, Bt + t_i * 4096 + w * 512);
            }
        }
        __syncthreads();

        #pragma unroll 1
        for (int t_i = 0; t_i < 8; ++t_i) {
            const unsigned short* bt = Bt + t_i * 4096;
            f32x4 acc[6];
            #pragma unroll
            for (int mt = 0; mt < 6; ++mt) acc[mt] = (f32x4){0.f, 0.f, 0.f, 0.f};
            #pragma unroll
            for (int kt = 0; kt < 8; ++kt) {
                bf16x8 bf;
                if (SRC_BF16) {
                    bf = *(const bf16x8*)(bt + kt * 512 + l * 8);
                } else {
                    #pragma unroll
                    for (int j = 0; j < 8; ++j) {
                        int k = kt * 32 + (j & 3) + (g << 2) + ((j >> 2) << 4);
                        bf[j] = (short)bt[k * 16 + b];
                    }
                }
                #pragma unroll
                for (int mt = 0; mt < 6; ++mt)
                    acc[mt] = __builtin_amdgcn_mfma_f32_16x16x32_bf16(af[mt][kt], bf, acc[mt], 0, 0, 0);
            }
            unsigned long long* dst = xg + ((size_t)(tg * 8 + t_i) * 8 + bblk) * 3072 + (size_t)w * 384;
            #pragma unroll
            for (int mt = 0; mt < 6; ++mt)
                dst[mt * 64 + l] = pk4bf_sw(acc[mt][0] + bsum[mt][0], acc[mt][1] + bsum[mt][1],
                                            acc[mt][2] + bsum[mt][2], acc[mt][3] + bsum[mt][3]);
        }
        __syncthreads();   // drains all waves' xg stores
        if (tid == 0) flag_add(doneCtr + cc * 16);
    }
}

// ---- persistent recur role (LAYER templated; strength-reduced pointers) ----
template<int LAYER>
__device__ void recur_persist(char* smem, int bblk,
                              const unsigned long long* __restrict__ xgring, size_t slotU,
                              const unsigned short* __restrict__ wpack,
                              const float* __restrict__ bhh,
                              unsigned short* __restrict__ hseq, float* __restrict__ h2last,
                              int nc, int chunk,
                              int* srcReady, int srcTarget, int* doneCtr)
{
    unsigned short* wlds  = (unsigned short*)smem;             // [8][6][512] u16 = 48KB (kt7)
    unsigned short* hfrag = (unsigned short*)(smem + 49152);   // [2][8][512] u16 = 16KB
    const int tid = threadIdx.x;
    const int w = tid >> 6, l = tid & 63;
    const int g = l >> 4, b = l & 15;

    bf16x8 af[6][7];
    {
        const bf16x8* wp = (const bf16x8*)wpack;
        #pragma unroll
        for (int mt = 0; mt < 6; ++mt)
            #pragma unroll
            for (int kt = 0; kt < 7; ++kt) {
                af[mt][kt] = wp[((w * 6 + mt) * 8 + kt) * 64 + l];
                asm volatile("" : "+v"(af[mt][kt]));
            }
    }
    #pragma unroll
    for (int mt = 0; mt < 6; ++mt)
        gload_lds16(wpack + ((((size_t)(w * 6 + mt)) * 8 + 7) * 64 + l) * 8,
                    wlds + (w * 6 + mt) * 512);

    float nbh[2][4];
    #pragma unroll
    for (int s = 0; s < 2; ++s)
        #pragma unroll
        for (int q = 0; q < 4; ++q)
            nbh[s][q] = bhh[512 + w * 32 + s * 16 + g * 4 + q];

    float hreg[2][4];
    #pragma unroll
    for (int s = 0; s < 2; ++s)
        #pragma unroll
        for (int q = 0; q < 4; ++q) hreg[s][q] = 0.f;
    *(unsigned long long*)(&hfrag[(size_t)w * 512 + l * 8])     = 0ull;
    *(unsigned long long*)(&hfrag[(size_t)w * 512 + l * 8 + 4]) = 0ull;
    __syncthreads();   // drains weight gload_lds + hfrag writes (once)

    // advancing hseq pointer (LAYER 0 only; stride 4096 u16 per step)
    unsigned short* hq = hseq + (size_t)bblk * T_ * 4096 + (size_t)w * 512 + l * 8;

    for (int cc = 0; cc < nc; ++cc) {
        if (tid == 0) spin_ge(srcReady + cc * 16, srcTarget);
        __syncthreads();

        const unsigned long long* xbase = xgring + (size_t)(cc & 1) * slotU
                                        + (size_t)bblk * 3072 + (size_t)w * 384 + l;
        unsigned long long xgA[6], xgB[6];
        #pragma unroll
        for (int mt = 0; mt < 6; ++mt) xgA[mt] = xbase[mt * 64];
        // prefetch pointer: it=1 onward; advances 24576/step. On the final step it
        // reads one stride past the slot (valid ws memory, value discarded).
        const unsigned long long* xp = xbase + 24576;

        auto rstep = [&](int pr, unsigned long long (&cur)[6], unsigned long long (&nxt)[6]) {
            const unsigned short* hb = hfrag + (size_t)pr * 4096;
            f32x4 acc[6];
            #pragma unroll
            for (int mt = 0; mt < 6; ++mt) acc[mt] = (f32x4){0.f, 0.f, 0.f, 0.f};
            #pragma unroll
            for (int kp = 0; kp < 3; ++kp) {
                bf16x8 h0 = *(const bf16x8*)(hb + (2 * kp) * 512 + l * 8);
                bf16x8 h1 = *(const bf16x8*)(hb + (2 * kp + 1) * 512 + l * 8);
                #pragma unroll
                for (int mt = 0; mt < 6; ++mt)
                    acc[mt] = __builtin_amdgcn_mfma_f32_16x16x32_bf16(af[mt][2 * kp], h0, acc[mt], 0, 0, 0);
                #pragma unroll
                for (int mt = 0; mt < 6; ++mt)
                    acc[mt] = __builtin_amdgcn_mfma_f32_16x16x32_bf16(af[mt][2 * kp + 1], h1, acc[mt], 0, 0, 0);
            }
            {
                bf16x8 h0 = *(const bf16x8*)(hb + 6 * 512 + l * 8);
                bf16x8 h1 = *(const bf16x8*)(hb + 7 * 512 + l * 8);
                #pragma unroll
                for (int mt = 0; mt < 6; ++mt)
                    acc[mt] = __builtin_amdgcn_mfma_f32_16x16x32_bf16(af[mt][6], h0, acc[mt], 0, 0, 0);
                #pragma unroll
                for (int mt = 0; mt < 6; ++mt) {
                    bf16x8 a = *(const bf16x8*)(wlds + (w * 6 + mt) * 512 + l * 8);
                    acc[mt] = __builtin_amdgcn_mfma_f32_16x16x32_bf16(a, h1, acc[mt], 0, 0, 0);
                }
            }
            unsigned long long pks[2];
            #pragma unroll
            for (int ss = 0; ss < 2; ++ss) {
                float cx0[4], cx1[4], cx2[4];
                unpk4(cur[0 + ss], cx0);
                unpk4(cur[2 + ss], cx1);
                unpk4(cur[4 + ss], cx2);
                float hn4[4];
                #pragma unroll
                for (int q = 0; q < 4; ++q) {
                    float r = sigm(cx0[q] + acc[0 + ss][q]);
                    float z = sigm(cx1[q] + acc[2 + ss][q]);
                    float n = tanh_f(cx2[q] + r * (acc[4 + ss][q] + nbh[ss][q]));
                    float hn = n + z * (hreg[ss][q] - n);
                    hreg[ss][q] = hn;
                    hn4[q] = hn;
                }
                pks[ss] = pk4bf(hn4[0], hn4[1], hn4[2], hn4[3]);
            }
            *(unsigned long long*)(&hfrag[(size_t)(pr ^ 1) * 4096 + w * 512 + l * 8])     = pks[0];
            *(unsigned long long*)(&hfrag[(size_t)(pr ^ 1) * 4096 + w * 512 + l * 8 + 4]) = pks[1];
            if (LAYER == 0) {
                *(unsigned long long*)hq       = pks[0];
                *(unsigned long long*)(hq + 4) = pks[1];
                hq += 4096;
            }
            // prefetch next-step xg; rides across the barrier
            #pragma unroll
            for (int mt = 0; mt < 6; ++mt) nxt[mt] = xp[mt * 64];
            xp += 24576;
            asm volatile("s_waitcnt lgkmcnt(0)\n\ts_barrier" ::: "memory");
        };

        #pragma unroll 1
        for (int it2 = 0; it2 < chunk; it2 += 2) {
            rstep(0, xgA, xgB);
            rstep(1, xgB, xgA);
        }

        __syncthreads();   // drains hseq stores before signaling
        if (tid == 0) flag_add(doneCtr + cc * 16);
    }

    if (LAYER == 1) {
        #pragma unroll
        for (int s = 0; s < 2; ++s)
            #pragma unroll
            for (int q = 0; q < 4; ++q) {
                int hid = w * 32 + s * 16 + g * 4 + q;
                h2last[(size_t)(bblk * 16 + b) * H_ + hid] = hreg[s][q];
            }
    }
}

// One persistent launch (cooperative for co-residency; NO grid.sync — dataflow
// flags at chunk granularity drive the pipeline).
// flags layout (int, stride-16 per chunk): [0]=g0done [2048]=rdone0 [4096]=g1done [6144]=rdone1
__global__ __launch_bounds__(512, 2)
void pipeline(int nc, int chunk,
              const float* __restrict__ x,
              const unsigned short* __restrict__ pIH0, const unsigned short* __restrict__ pIH1,
              const unsigned short* __restrict__ pHH0, const unsigned short* __restrict__ pHH1,
              const float* __restrict__ bih0, const float* __restrict__ bhh0,
              const float* __restrict__ bih1, const float* __restrict__ bhh1,
              unsigned long long* __restrict__ xg0, unsigned long long* __restrict__ xg1,
              unsigned short* __restrict__ hseq, float* __restrict__ h2last,
              int* __restrict__ flags)
{
    extern __shared__ char smem[];
    const size_t slotU = (size_t)chunk * 24576;
    int* g0done = flags;
    int* rdone0 = flags + 2048;
    int* g1done = flags + 4096;
    int* rdone1 = flags + 6144;
    const int bid = blockIdx.x;
    if (bid < 8) {
        recur_persist<0>(smem, bid, xg0, slotU, pHH0, bhh0, hseq, nullptr,
                         nc, chunk, g0done, chunk, rdone0);
    } else if (bid < 16) {
        recur_persist<1>(smem, bid - 8, xg1, slotU, pHH1, bhh1, nullptr, h2last,
                         nc, chunk, g1done, chunk, rdone1);
    } else if (bid < 16 + chunk) {
        gemm_persist<true>(smem, bid - 16, hseq, pIH1, bih1, bhh1, xg1, slotU,
                           nc, chunk, rdone0, 8, rdone1, 8, g1done);
    } else {
        gemm_persist<false>(smem, bid - 16 - chunk, x, pIH0, bih0, bhh0, xg0, slotU,
                            nc, chunk, nullptr, 0, rdone0, 8, g0done);
    }
}

__global__ void fc_out(const float* __restrict__ h2, const float* __restrict__ W_fc,
                       const float* __restrict__ b_fc, float* __restrict__ out)
{
    __shared__ float hrow[256];
    const int bb = blockIdx.x, i = threadIdx.x;
    hrow[i] = h2[(size_t)bb * 256 + i];
    __syncthreads();
    float acc = b_fc[i];
    const float* wr = W_fc + (size_t)i * 256;
    #pragma unroll 8
    for (int k = 0; k < 256; ++k) acc += hrow[k] * wr[k];
    out[(size_t)bb * 256 + i] = sigm(acc);
}

extern "C" void kernel_launch(void* const* d_in, const int* in_sizes, int n_in,
                              void* d_out, int out_size, void* d_ws, size_t ws_size,
                              hipStream_t stream)
{
    const float* x    = (const float*)d_in[0];
    const float* W_ih = (const float*)d_in[1];
    const float* W_hh = (const float*)d_in[2];
    const float* b_ih = (const float*)d_in[3];
    const float* b_hh = (const float*)d_in[4];
    const float* W_fc = (const float*)d_in[5];
    const float* b_fc = (const float*)d_in[6];
    float* out = (float*)d_out;

    const size_t HSEQ_B = (size_t)8 * T_ * 4096 * 2;   // 64 MB
    const size_t PACK_B = 393216ull * 2;               // 768 KB each
    const size_t H2_B = 131072;
    const size_t FLG_B = 32768;                        // 4 x 2048 ints
    size_t fixed = HSEQ_B + 2 * PACK_B + H2_B + FLG_B;
    int chunk = 32;
    while (chunk > 8 && fixed + (size_t)chunk * 196608 * 4 > ws_size) chunk >>= 1;
    const size_t slotB = (size_t)chunk * 196608;

    char* ws = (char*)d_ws;
    unsigned long long* xg0 = (unsigned long long*)ws;
    unsigned long long* xg1 = (unsigned long long*)(ws + 2 * slotB);
    size_t off = 4 * slotB;
    unsigned short* hseq = (unsigned short*)(ws + off); off += HSEQ_B;
    unsigned short* pIH  = (unsigned short*)(ws + off); off += PACK_B;
    unsigned short* pHH  = (unsigned short*)(ws + off); off += PACK_B;
    float* h2     = (float*)(ws + off); off += H2_B;
    int* flags    = (int*)(ws + off);

    hipMemsetAsync(flags, 0, FLG_B, stream);
    pack_weights<<<1536, 256, 0, stream>>>(W_ih, W_hh, pIH, pHH);

    const unsigned short* pIH0 = pIH;
    const unsigned short* pIH1 = pIH + 196608;
    const unsigned short* pHH0 = pHH;
    const unsigned short* pHH1 = pHH + 196608;
    const float* bih0 = b_ih;
    const float* bih1 = b_ih + G_;
    const float* bhh0 = b_hh;
    const float* bhh1 = b_hh + G_;

    int nc = T_ / chunk;
    int grid = 16 + 2 * chunk;
    void* args[] = {
        (void*)&nc, (void*)&chunk, (void*)&x,
        (void*)&pIH0, (void*)&pIH1, (void*)&pHH0, (void*)&pHH1,
        (void*)&bih0, (void*)&bhh0, (void*)&bih1, (void*)&bhh1,
        (void*)&xg0, (void*)&xg1, (void*)&hseq, (void*)&h2, (void*)&flags
    };
    hipLaunchCooperativeKernel((const void*)pipeline, dim3(grid), dim3(512),
                               args, 65536, stream);

    fc_out<<<128, 256, 0, stream>>>(h2, W_fc, b_fc, out);
}

// Round 23
// 1766.314 us; speedup vs baseline: 2.6309x; 1.0325x over previous
//
#include <hip/hip_runtime.h>
#include <stdint.h>

#define T_ 1024
#define H_ 256
#define G_ 768

typedef __attribute__((ext_vector_type(8))) short bf16x8;
typedef __attribute__((ext_vector_type(4))) float f32x4;

__device__ __forceinline__ unsigned short f2bf(float f) {
    union { float f; uint32_t u; } v; v.f = f;
    uint32_t u = v.u;
    return (unsigned short)((u + 0x7FFFu + ((u >> 16) & 1u)) >> 16);
}

__device__ __forceinline__ float sigm(float x) {
    return __builtin_amdgcn_rcpf(1.f + __expf(-x));
}
__device__ __forceinline__ float tanh_f(float x) {
    return __builtin_amdgcn_rcpf(1.f + __expf(-2.f * x)) * 2.f - 1.f;
}

// asm cvt_pk: recur-only (scalar float inputs) — CONDEMNED on gemm MFMA accs (K5..K10)
__device__ __forceinline__ unsigned long long pk4bf(float a, float b, float c, float d) {
    uint32_t lo, hi;
    asm("v_cvt_pk_bf16_f32 %0, %1, %2" : "=v"(lo) : "v"(a), "v"(b));
    asm("v_cvt_pk_bf16_f32 %0, %1, %2" : "=v"(hi) : "v"(c), "v"(d));
    return ((unsigned long long)hi << 32) | (unsigned long long)lo;
}

__device__ __forceinline__ unsigned long long pk4bf_sw(float a, float b, float c, float d) {
    return (unsigned long long)f2bf(a)
         | ((unsigned long long)f2bf(b) << 16)
         | ((unsigned long long)f2bf(c) << 32)
         | ((unsigned long long)f2bf(d) << 48);
}

__device__ __forceinline__ void unpk4(unsigned long long v, float* o) {
    uint32_t lo = (uint32_t)v, hi = (uint32_t)(v >> 32);
    union { uint32_t u; float f; } a, b, c, d;
    a.u = lo << 16; b.u = lo & 0xffff0000u;
    c.u = hi << 16; d.u = hi & 0xffff0000u;
    o[0] = a.f; o[1] = b.f; o[2] = c.f; o[3] = d.f;
}

__device__ __forceinline__ void gload_lds16(const void* g, void* l) {
    __builtin_amdgcn_global_load_lds((const __attribute__((address_space(1))) void*)g,
                                     (__attribute__((address_space(3))) void*)l,
                                     16, 0, 0);
}

// chunk-granularity dataflow sync (K21-proven): acquire-spin / release-add
__device__ __forceinline__ void spin_ge(int* p, int target) {
    while (__hip_atomic_load(p, __ATOMIC_ACQUIRE, __HIP_MEMORY_SCOPE_AGENT) < target)
        __builtin_amdgcn_s_sleep(8);
}
__device__ __forceinline__ void flag_add(int* p) {
    __hip_atomic_fetch_add(p, 1, __ATOMIC_RELEASE, __HIP_MEMORY_SCOPE_AGENT);
}

// Pack W (f32 [layer][768][256]) into per-wave MFMA A-fragment order (K2-proven):
// flat = ((((layer*8 + w)*6 + mt)*8 + kt)*64 + l)*8 + j
// gate = (mt>>1)*256 + w*32 + (mt&1)*16 + (l&15)
// k    = kt*32 + (j&3) + ((l>>4)<<2) + ((j>>2)<<4)
__global__ void pack_weights(const float* __restrict__ W_ih, const float* __restrict__ W_hh,
                             unsigned short* __restrict__ pIH, unsigned short* __restrict__ pHH)
{
    int idx = blockIdx.x * blockDim.x + threadIdx.x;
    if (idx >= 2 * 8 * 6 * 8 * 64 * 8) return;
    int pos = idx;
    int j = pos & 7;  pos >>= 3;
    int l = pos & 63; pos >>= 6;
    int kt = pos & 7; pos >>= 3;
    int mt = pos % 6; pos /= 6;
    int w = pos & 7;  pos >>= 3;
    int layer = pos;
    int gate = (mt >> 1) * 256 + w * 32 + (mt & 1) * 16 + (l & 15);
    int k = kt * 32 + (j & 3) + ((l >> 4) << 2) + ((j >> 2) << 4);
    size_t src = (size_t)layer * G_ * H_ + (size_t)gate * H_ + k;
    pIH[idx] = f2bf(W_ih[src]);
    pHH[idx] = f2bf(W_hh[src]);
}

// ---- persistent gemm role: weights loaded once; dataflow-flag driven ----
template<bool SRC_BF16>
__device__ void gemm_persist(char* smem, int gb,
                             const void* __restrict__ srcp,
                             const unsigned short* __restrict__ wpack,
                             const float* __restrict__ bih, const float* __restrict__ bhh,
                             unsigned long long* __restrict__ xgring, size_t slotU,
                             int nc, int chunk,
                             int* srcReady, int srcTarget,
                             int* ringFree, int ringTarget, int* doneCtr)
{
    unsigned short* Bt = (unsigned short*)smem; // [8][4096] shorts = 64KB
    const int tid = threadIdx.x;
    const int w = tid >> 6, l = tid & 63;
    const int bblk = gb & 7;
    const int tg = gb >> 3;
    const int b = l & 15, g = l >> 4;

    bf16x8 af[6][8];
    {
        const bf16x8* wp = (const bf16x8*)wpack;
        #pragma unroll
        for (int mt = 0; mt < 6; ++mt)
            #pragma unroll
            for (int kt = 0; kt < 8; ++kt)
                af[mt][kt] = wp[((w * 6 + mt) * 8 + kt) * 64 + l];
    }
    float bsum[6][4];
    #pragma unroll
    for (int mt = 0; mt < 6; ++mt)
        #pragma unroll
        for (int q = 0; q < 4; ++q) {
            int gate = (mt >> 1) * 256 + w * 32 + (mt & 1) * 16 + g * 4 + q;
            bsum[mt][q] = (gate < 512) ? (bih[gate] + bhh[gate]) : bih[gate];
        }

    for (int cc = 0; cc < nc; ++cc) {
        if (tid == 0) {
            if (srcReady) spin_ge(srcReady + cc * 16, srcTarget);
            if (cc >= 2) spin_ge(ringFree + (cc - 2) * 16, ringTarget);
        }
        __syncthreads();

        unsigned long long* xg = xgring + (size_t)(cc & 1) * slotU;
        const int tbase = cc * chunk + tg * 8;

        if (!SRC_BF16) {
            const float* x = (const float*)srcp;
            const int t_i = w;
            const int sb = (l >> 2) & 15;
            const int f0 = (l & 3) * 64;
            const float* row = x + ((size_t)(bblk * 16 + sb) * T_ + (tbase + t_i)) * H_ + f0;
            unsigned short* bt = Bt + t_i * 4096;
            #pragma unroll
            for (int i = 0; i < 64; i += 4) {
                f32x4 v = *(const f32x4*)(row + i);
                int f = f0 + i;
                bt[(f + 0) * 16 + sb] = f2bf(v[0]);
                bt[(f + 1) * 16 + sb] = f2bf(v[1]);
                bt[(f + 2) * 16 + sb] = f2bf(v[2]);
                bt[(f + 3) * 16 + sb] = f2bf(v[3]);
            }
        } else {
            const unsigned short* hs = (const unsigned short*)srcp;
            #pragma unroll
            for (int t_i = 0; t_i < 8; ++t_i) {
                const unsigned short* src = hs + ((size_t)bblk * T_ + (tbase + t_i)) * 4096
                                               + (size_t)(w * 64 + l) * 8;
                gload_lds16(src, Bt + t_i * 4096 + w * 512);
            }
        }
        __syncthreads();

        #pragma unroll 1
        for (int t_i = 0; t_i < 8; ++t_i) {
            const unsigned short* bt = Bt + t_i * 4096;
            f32x4 acc[6];
            #pragma unroll
            for (int mt = 0; mt < 6; ++mt) acc[mt] = (f32x4){0.f, 0.f, 0.f, 0.f};
            #pragma unroll
            for (int kt = 0; kt < 8; ++kt) {
                bf16x8 bf;
                if (SRC_BF16) {
                    bf = *(const bf16x8*)(bt + kt * 512 + l * 8);
                } else {
                    #pragma unroll
                    for (int j = 0; j < 8; ++j) {
                        int k = kt * 32 + (j & 3) + (g << 2) + ((j >> 2) << 4);
                        bf[j] = (short)bt[k * 16 + b];
                    }
                }
                #pragma unroll
                for (int mt = 0; mt < 6; ++mt)
                    acc[mt] = __builtin_amdgcn_mfma_f32_16x16x32_bf16(af[mt][kt], bf, acc[mt], 0, 0, 0);
            }
            unsigned long long* dst = xg + ((size_t)(tg * 8 + t_i) * 8 + bblk) * 3072 + (size_t)w * 384;
            #pragma unroll
            for (int mt = 0; mt < 6; ++mt)
                dst[mt * 64 + l] = pk4bf_sw(acc[mt][0] + bsum[mt][0], acc[mt][1] + bsum[mt][1],
                                            acc[mt][2] + bsum[mt][2], acc[mt][3] + bsum[mt][3]);
        }
        __syncthreads();   // drains all waves' xg stores
        if (tid == 0) flag_add(doneCtr + cc * 16);
    }
}

// ---- persistent recur role (LAYER templated; strength-reduced pointers) ----
template<int LAYER>
__device__ void recur_persist(char* smem, int bblk,
                              const unsigned long long* __restrict__ xgring, size_t slotU,
                              const unsigned short* __restrict__ wpack,
                              const float* __restrict__ bhh,
                              unsigned short* __restrict__ hseq, float* __restrict__ h2last,
                              int nc, int chunk,
                              int* srcReady, int srcTarget, int* doneCtr)
{
    unsigned short* wlds  = (unsigned short*)smem;             // [8][6][512] u16 = 48KB (kt7)
    unsigned short* hfrag = (unsigned short*)(smem + 49152);   // [2][8][512] u16 = 16KB
    const int tid = threadIdx.x;
    const int w = tid >> 6, l = tid & 63;
    const int g = l >> 4, b = l & 15;

    bf16x8 af[6][7];
    {
        const bf16x8* wp = (const bf16x8*)wpack;
        #pragma unroll
        for (int mt = 0; mt < 6; ++mt)
            #pragma unroll
            for (int kt = 0; kt < 7; ++kt) {
                af[mt][kt] = wp[((w * 6 + mt) * 8 + kt) * 64 + l];
                asm volatile("" : "+v"(af[mt][kt]));
            }
    }
    #pragma unroll
    for (int mt = 0; mt < 6; ++mt)
        gload_lds16(wpack + ((((size_t)(w * 6 + mt)) * 8 + 7) * 64 + l) * 8,
                    wlds + (w * 6 + mt) * 512);

    float nbh[2][4];
    #pragma unroll
    for (int s = 0; s < 2; ++s)
        #pragma unroll
        for (int q = 0; q < 4; ++q)
            nbh[s][q] = bhh[512 + w * 32 + s * 16 + g * 4 + q];

    float hreg[2][4];
    #pragma unroll
    for (int s = 0; s < 2; ++s)
        #pragma unroll
        for (int q = 0; q < 4; ++q) hreg[s][q] = 0.f;
    *(unsigned long long*)(&hfrag[(size_t)w * 512 + l * 8])     = 0ull;
    *(unsigned long long*)(&hfrag[(size_t)w * 512 + l * 8 + 4]) = 0ull;
    __syncthreads();   // drains weight gload_lds + hfrag writes (once)

    // advancing hseq pointer (LAYER 0 only; stride 4096 u16 per step)
    unsigned short* hq = hseq + (size_t)bblk * T_ * 4096 + (size_t)w * 512 + l * 8;

    for (int cc = 0; cc < nc; ++cc) {
        if (tid == 0) spin_ge(srcReady + cc * 16, srcTarget);
        __syncthreads();

        const unsigned long long* xbase = xgring + (size_t)(cc & 1) * slotU
                                        + (size_t)bblk * 3072 + (size_t)w * 384 + l;
        unsigned long long xgA[6], xgB[6];
        #pragma unroll
        for (int mt = 0; mt < 6; ++mt) xgA[mt] = xbase[mt * 64];
        // prefetch pointer: it=1 onward; advances 24576/step. On the final step it
        // reads one stride past the slot (valid ws memory, value discarded).
        const unsigned long long* xp = xbase + 24576;

        auto rstep = [&](int pr, unsigned long long (&cur)[6], unsigned long long (&nxt)[6]) {
            const unsigned short* hb = hfrag + (size_t)pr * 4096;
            f32x4 acc[6];
            #pragma unroll
            for (int mt = 0; mt < 6; ++mt) acc[mt] = (f32x4){0.f, 0.f, 0.f, 0.f};
            #pragma unroll
            for (int kp = 0; kp < 3; ++kp) {
                bf16x8 h0 = *(const bf16x8*)(hb + (2 * kp) * 512 + l * 8);
                bf16x8 h1 = *(const bf16x8*)(hb + (2 * kp + 1) * 512 + l * 8);
                #pragma unroll
                for (int mt = 0; mt < 6; ++mt)
                    acc[mt] = __builtin_amdgcn_mfma_f32_16x16x32_bf16(af[mt][2 * kp], h0, acc[mt], 0, 0, 0);
                #pragma unroll
                for (int mt = 0; mt < 6; ++mt)
                    acc[mt] = __builtin_amdgcn_mfma_f32_16x16x32_bf16(af[mt][2 * kp + 1], h1, acc[mt], 0, 0, 0);
            }
            {
                bf16x8 h0 = *(const bf16x8*)(hb + 6 * 512 + l * 8);
                bf16x8 h1 = *(const bf16x8*)(hb + 7 * 512 + l * 8);
                #pragma unroll
                for (int mt = 0; mt < 6; ++mt)
                    acc[mt] = __builtin_amdgcn_mfma_f32_16x16x32_bf16(af[mt][6], h0, acc[mt], 0, 0, 0);
                #pragma unroll
                for (int mt = 0; mt < 6; ++mt) {
                    bf16x8 a = *(const bf16x8*)(wlds + (w * 6 + mt) * 512 + l * 8);
                    acc[mt] = __builtin_amdgcn_mfma_f32_16x16x32_bf16(a, h1, acc[mt], 0, 0, 0);
                }
            }
            unsigned long long pks[2];
            #pragma unroll
            for (int ss = 0; ss < 2; ++ss) {
                float cx0[4], cx1[4], cx2[4];
                unpk4(cur[0 + ss], cx0);
                unpk4(cur[2 + ss], cx1);
                unpk4(cur[4 + ss], cx2);
                float hn4[4];
                #pragma unroll
                for (int q = 0; q < 4; ++q) {
                    float r = sigm(cx0[q] + acc[0 + ss][q]);
                    float z = sigm(cx1[q] + acc[2 + ss][q]);
                    float n = tanh_f(cx2[q] + r * (acc[4 + ss][q] + nbh[ss][q]));
                    float hn = n + z * (hreg[ss][q] - n);
                    hreg[ss][q] = hn;
                    hn4[q] = hn;
                }
                pks[ss] = pk4bf(hn4[0], hn4[1], hn4[2], hn4[3]);
            }
            *(unsigned long long*)(&hfrag[(size_t)(pr ^ 1) * 4096 + w * 512 + l * 8])     = pks[0];
            *(unsigned long long*)(&hfrag[(size_t)(pr ^ 1) * 4096 + w * 512 + l * 8 + 4]) = pks[1];
            if (LAYER == 0) {
                *(unsigned long long*)hq       = pks[0];
                *(unsigned long long*)(hq + 4) = pks[1];
                hq += 4096;
            }
            // prefetch next-step xg; rides across the barrier
            #pragma unroll
            for (int mt = 0; mt < 6; ++mt) nxt[mt] = xp[mt * 64];
            xp += 24576;
            asm volatile("s_waitcnt lgkmcnt(0)\n\ts_barrier" ::: "memory");
        };

        #pragma unroll 1
        for (int it2 = 0; it2 < chunk; it2 += 2) {
            rstep(0, xgA, xgB);
            rstep(1, xgB, xgA);
        }

        __syncthreads();   // drains hseq stores before signaling
        if (tid == 0) flag_add(doneCtr + cc * 16);
    }

    if (LAYER == 1) {
        #pragma unroll
        for (int s = 0; s < 2; ++s)
            #pragma unroll
            for (int q = 0; q < 4; ++q) {
                int hid = w * 32 + s * 16 + g * 4 + q;
                h2last[(size_t)(bblk * 16 + b) * H_ + hid] = hreg[s][q];
            }
    }
}

// One persistent launch (cooperative for co-residency; NO grid.sync — dataflow
// flags at chunk granularity drive the pipeline).
// flags layout (int, stride-16 per chunk): [0]=g0done [2048]=rdone0 [4096]=g1done [6144]=rdone1
__global__ __launch_bounds__(512, 2)
void pipeline(int nc, int chunk,
              const float* __restrict__ x,
              const unsigned short* __restrict__ pIH0, const unsigned short* __restrict__ pIH1,
              const unsigned short* __restrict__ pHH0, const unsigned short* __restrict__ pHH1,
              const float* __restrict__ bih0, const float* __restrict__ bhh0,
              const float* __restrict__ bih1, const float* __restrict__ bhh1,
              unsigned long long* __restrict__ xg0, unsigned long long* __restrict__ xg1,
              unsigned short* __restrict__ hseq, float* __restrict__ h2last,
              int* __restrict__ flags)
{
    extern __shared__ char smem[];
    const size_t slotU = (size_t)chunk * 24576;
    int* g0done = flags;
    int* rdone0 = flags + 2048;
    int* g1done = flags + 4096;
    int* rdone1 = flags + 6144;
    const int bid = blockIdx.x;
    if (bid < 8) {
        recur_persist<0>(smem, bid, xg0, slotU, pHH0, bhh0, hseq, nullptr,
                         nc, chunk, g0done, chunk, rdone0);
    } else if (bid < 16) {
        recur_persist<1>(smem, bid - 8, xg1, slotU, pHH1, bhh1, nullptr, h2last,
                         nc, chunk, g1done, chunk, rdone1);
    } else if (bid < 16 + chunk) {
        gemm_persist<true>(smem, bid - 16, hseq, pIH1, bih1, bhh1, xg1, slotU,
                           nc, chunk, rdone0, 8, rdone1, 8, g1done);
    } else {
        gemm_persist<false>(smem, bid - 16 - chunk, x, pIH0, bih0, bhh0, xg0, slotU,
                            nc, chunk, nullptr, 0, rdone0, 8, g0done);
    }
}

__global__ void fc_out(const float* __restrict__ h2, const float* __restrict__ W_fc,
                       const float* __restrict__ b_fc, float* __restrict__ out)
{
    __shared__ float hrow[256];
    const int bb = blockIdx.x, i = threadIdx.x;
    hrow[i] = h2[(size_t)bb * 256 + i];
    __syncthreads();
    float acc = b_fc[i];
    const float* wr = W_fc + (size_t)i * 256;
    #pragma unroll 8
    for (int k = 0; k < 256; ++k) acc += hrow[k] * wr[k];
    out[(size_t)bb * 256 + i] = sigm(acc);
}

extern "C" void kernel_launch(void* const* d_in, const int* in_sizes, int n_in,
                              void* d_out, int out_size, void* d_ws, size_t ws_size,
                              hipStream_t stream)
{
    const float* x    = (const float*)d_in[0];
    const float* W_ih = (const float*)d_in[1];
    const float* W_hh = (const float*)d_in[2];
    const float* b_ih = (const float*)d_in[3];
    const float* b_hh = (const float*)d_in[4];
    const float* W_fc = (const float*)d_in[5];
    const float* b_fc = (const float*)d_in[6];
    float* out = (float*)d_out;

    const size_t HSEQ_B = (size_t)8 * T_ * 4096 * 2;   // 64 MB
    const size_t PACK_B = 393216ull * 2;               // 768 KB each
    const size_t H2_B = 131072;
    const size_t FLG_B = 32768;                        // 4 x 2048 ints
    size_t fixed = HSEQ_B + 2 * PACK_B + H2_B + FLG_B;
    int chunk = 16;
    while (chunk > 8 && fixed + (size_t)chunk * 196608 * 4 > ws_size) chunk >>= 1;
    const size_t slotB = (size_t)chunk * 196608;

    char* ws = (char*)d_ws;
    unsigned long long* xg0 = (unsigned long long*)ws;
    unsigned long long* xg1 = (unsigned long long*)(ws + 2 * slotB);
    size_t off = 4 * slotB;
    unsigned short* hseq = (unsigned short*)(ws + off); off += HSEQ_B;
    unsigned short* pIH  = (unsigned short*)(ws + off); off += PACK_B;
    unsigned short* pHH  = (unsigned short*)(ws + off); off += PACK_B;
    float* h2     = (float*)(ws + off); off += H2_B;
    int* flags    = (int*)(ws + off);

    hipMemsetAsync(flags, 0, FLG_B, stream);
    pack_weights<<<1536, 256, 0, stream>>>(W_ih, W_hh, pIH, pHH);

    const unsigned short* pIH0 = pIH;
    const unsigned short* pIH1 = pIH + 196608;
    const unsigned short* pHH0 = pHH;
    const unsigned short* pHH1 = pHH + 196608;
    const float* bih0 = b_ih;
    const float* bih1 = b_ih + G_;
    const float* bhh0 = b_hh;
    const float* bhh1 = b_hh + G_;

    int nc = T_ / chunk;
    int grid = 16 + 2 * chunk;
    void* args[] = {
        (void*)&nc, (void*)&chunk, (void*)&x,
        (void*)&pIH0, (void*)&pIH1, (void*)&pHH0, (void*)&pHH1,
        (void*)&bih0, (void*)&bhh0, (void*)&bih1, (void*)&bhh1,
        (void*)&xg0, (void*)&xg1, (void*)&hseq, (void*)&h2, (void*)&flags
    };
    hipLaunchCooperativeKernel((const void*)pipeline, dim3(grid), dim3(512),
                               args, 65536, stream);

    fc_out<<<128, 256, 0, stream>>>(h2, W_fc, b_fc, out);
}